// Round 6
// baseline (283.157 us; speedup 1.0000x reference)
//
#include <hip/hip_runtime.h>
#include <hip/hip_bf16.h>
#include <hip/hip_fp16.h>

#define NNODES 20000
#define NEDGES 320000
#define DIM    128
#define NH     4
#define ETOT   (NEDGES + NNODES)
#define LN_EPS 1e-5f

typedef unsigned short u16;
typedef unsigned int   u32;

typedef _Float16 f16x2 __attribute__((ext_vector_type(2)));
typedef _Float16 f16x8 __attribute__((ext_vector_type(8)));
typedef float    f32x2 __attribute__((ext_vector_type(2)));
typedef float    f32x4 __attribute__((ext_vector_type(4)));

__device__ inline u16 f2h(float f) {
    _Float16 h = (_Float16)f;
    union { _Float16 h; u16 u; } v; v.h = h; return v.u;
}
__device__ inline f16x2 u2h2(u32 u) { union { u32 u; f16x2 h; } v; v.u = u; return v.h; }
__device__ inline u32 h22u(f16x2 h) { union { f16x2 h; u32 u; } v; v.h = h; return v.u; }
__device__ inline f16x2 habs2(f16x2 h) { return u2h2(h22u(h) & 0x7FFF7FFFu); }

// ---------------- CSR build ----------------

__global__ void k_init_deg(int* __restrict__ deg) {
    int i = blockIdx.x * blockDim.x + threadIdx.x;
    if (i < NNODES) deg[i] = 1;   // self-loop
}

__global__ void k_hist(const int* __restrict__ dst, int* __restrict__ deg) {
    int i = blockIdx.x * blockDim.x + threadIdx.x;
    if (i < NEDGES) atomicAdd(&deg[dst[i]], 1);
}

__global__ __launch_bounds__(1024) void k_scan(const int* __restrict__ deg,
                                               int* __restrict__ row,
                                               int* __restrict__ cur) {
    __shared__ int part[1024];
    const int CH = (NNODES + 1023) / 1024;  // 20
    int t = threadIdx.x;
    int base = t * CH;
    int s = 0;
    for (int i = 0; i < CH; i++) { int idx = base + i; if (idx < NNODES) s += deg[idx]; }
    part[t] = s;
    __syncthreads();
    for (int off = 1; off < 1024; off <<= 1) {
        int v = (t >= off) ? part[t - off] : 0;
        __syncthreads();
        part[t] += v;
        __syncthreads();
    }
    int run = (t == 0) ? 0 : part[t - 1];
    for (int i = 0; i < CH; i++) {
        int idx = base + i;
        if (idx < NNODES) { row[idx] = run; cur[idx] = run; run += deg[idx]; }
    }
    if (t == 1023) row[NNODES] = part[1023];
}

__global__ void k_scatter(const int* __restrict__ src, const int* __restrict__ dst,
                          int* __restrict__ col, int* __restrict__ cur) {
    int i = blockIdx.x * blockDim.x + threadIdx.x;
    if (i < NEDGES) {
        int d = dst[i];
        int pos = atomicAdd(&cur[d], 1);
        col[pos] = src[i];
    } else if (i < ETOT) {
        int n = i - NEDGES;
        int pos = atomicAdd(&cur[n], 1);
        col[pos] = n;
    }
}

// ---------------- conversions (f32 -> fp16) ----------------

__global__ void k_cvt_x(const float* __restrict__ in, u16* __restrict__ out, int n4) {
    int i = blockIdx.x * blockDim.x + threadIdx.x;
    if (i < n4) {
        float4 v = ((const float4*)in)[i];
        ushort4 o;
        o.x = f2h(v.x); o.y = f2h(v.y); o.z = f2h(v.z); o.w = f2h(v.w);
        ((ushort4*)out)[i] = o;
    }
}

// Bt[n][k] = (n<512 ? Wl[k][n] : Wr[k][n-512]),  n in [0,1024), k in [0,128)
__global__ void k_cvt_w(const float* __restrict__ Wl, const float* __restrict__ Wr,
                        u16* __restrict__ Bt) {
    int idx = blockIdx.x * blockDim.x + threadIdx.x;
    if (idx < 1024 * 128) {
        int n = idx >> 7, k = idx & 127;
        float v = (n < 512) ? Wl[k * 512 + n] : Wr[k * 512 + (n - 512)];
        Bt[idx] = f2h(v);
    }
}

// ------------- fp16 MFMA GEMM: [XL|XR][M,512 each] = A[M,128] @ Bt^T -------------
// BM=32 (A staged ONCE per row), BN=1024 full width, 8 waves, wave = 32x128 (acc 64 VGPR).
// B (256KB) read from global per k-step -> L2-hot. Grid = M/32 = 625 exact.

__global__ __launch_bounds__(512, 4) void k_gemm_f16(const u16* __restrict__ A,
                                                     const u16* __restrict__ Bt,
                                                     u16* __restrict__ XL,
                                                     u16* __restrict__ XR) {
    __shared__ u16 smA[32 * 128];   // 8 KB, row-swizzled
    const int t  = threadIdx.x;
    const int bm = blockIdx.x * 32;

    {
        int row = t >> 4;            // 0..31
        int cb  = (t & 15) * 16;     // byte col 0..240
        uint4 va = *(const uint4*)(A + (size_t)(bm + row) * 128 + (cb >> 1));
        *(uint4*)((char*)smA + ((row * 256 + cb) ^ ((row & 7) << 4))) = va;
    }

    const int w   = t >> 6;             // wave 0..7
    const int l   = t & 63;
    const int wc  = w * 128;            // wave's 128-col slice of N=1024
    const int lr  = l & 15;
    const int lkb = (l >> 4) * 16;      // byte offset of lane's k-chunk
    const int lkh = (l >> 4) * 8;       // same in halves

    __syncthreads();

    f32x4 acc[2][8] = {};               // C^T fragments

#pragma unroll
    for (int ks = 0; ks < 4; ++ks) {
        f16x8 bfr[8];
#pragma unroll
        for (int ni = 0; ni < 8; ++ni)
            bfr[ni] = *(const f16x8*)(Bt + (size_t)(wc + ni * 16 + lr) * 128
                                         + ks * 32 + lkh);
        f16x8 af[2];
#pragma unroll
        for (int i = 0; i < 2; ++i) {
            int ra = i * 16 + lr;
            af[i]  = *(const f16x8*)((const char*)smA +
                        ((ra * 256 + ks * 64 + lkb) ^ ((ra & 7) << 4)));
        }
#pragma unroll
        for (int mi = 0; mi < 2; ++mi)
#pragma unroll
            for (int ni = 0; ni < 8; ++ni)
                acc[mi][ni] = __builtin_amdgcn_mfma_f32_16x16x32_f16(
                    bfr[ni], af[mi], acc[mi][ni], 0, 0, 0);
    }

    // epilogue: direct stores, route n<512 -> XL else XR
    const int n4 = (l >> 4) * 4;
#pragma unroll
    for (int mi = 0; mi < 2; ++mi) {
        int m = bm + mi * 16 + lr;
#pragma unroll
        for (int ni = 0; ni < 8; ++ni) {
            int n = wc + ni * 16 + n4;
            f32x4 v = acc[mi][ni];
            ushort4 o;
            o.x = f2h(v[0]); o.y = f2h(v[1]); o.z = f2h(v[2]); o.w = f2h(v[3]);
            u16* dst = (n < 512) ? (XL + (size_t)m * 512 + n)
                                 : (XR + (size_t)m * 512 + (n - 512));
            *(ushort4*)dst = o;
        }
    }
}

// ------------- fused GATv2 attention + head-mean + bias + LN + residual -------------
// TWO waves per node (no-max softmax => partials merge linearly via LDS).
// block = 4 waves = 2 nodes; wave: 4 heads x 16 lanes, 8 dims/lane; 2-edge unroll.

__global__ __launch_bounds__(256) void k_attn(const u16* __restrict__ XL,
                                              const u16* __restrict__ XR,
                                              const float* __restrict__ att,
                                              const float* __restrict__ bias,
                                              const float* __restrict__ gamma,
                                              const float* __restrict__ beta,
                                              const int* __restrict__ row,
                                              const int* __restrict__ col,
                                              const float* __restrict__ res,
                                              float* __restrict__ out,
                                              u16* __restrict__ out_h,
                                              int relu_flag) {
    const int tid  = threadIdx.x;
    const int wid  = tid >> 6;
    const int slot = wid >> 1;                      // node slot in block: 0/1
    const int half = wid & 1;                       // edge-list half: 0/1
    const int n    = blockIdx.x * 2 + slot;         // grid = NNODES/2 exactly
    const int l    = tid & 63;
    const int h    = l >> 4;                        // head 0..3
    const int e    = l & 15;                        // dim group: dims e*8..e*8+7

    const f16x2 C06 = {(_Float16)0.6f, (_Float16)0.6f};
    const f16x2 C04 = {(_Float16)0.4f, (_Float16)0.4f};

    const size_t lane_off = h * 128 + e * 8;

    uint4 xru = *(const uint4*)(XR + (size_t)n * 512 + lane_off);
    f16x2 xr0 = u2h2(xru.x), xr1 = u2h2(xru.y), xr2 = u2h2(xru.z), xr3 = u2h2(xru.w);

    const float* ap = att + h * 128 + e * 8;
    float4 af0 = *(const float4*)(ap);
    float4 af1 = *(const float4*)(ap + 4);
    f16x2 at0 = {(_Float16)af0.x, (_Float16)af0.y};
    f16x2 at1 = {(_Float16)af0.z, (_Float16)af0.w};
    f16x2 at2 = {(_Float16)af1.x, (_Float16)af1.y};
    f16x2 at3 = {(_Float16)af1.z, (_Float16)af1.w};

    float acc[8] = {0.f,0.f,0.f,0.f,0.f,0.f,0.f,0.f};
    float ssum = 0.f;

    const int beg = row[n], end = row[n + 1];
    const int mid = beg + ((end - beg + 1) >> 1);
    const int mb  = half ? mid : beg;
    const int me  = half ? end : mid;

    for (int i = mb; i < me; i += 2) {
        int s0 = col[i];
        bool has2 = (i + 1 < me);
        int s1 = has2 ? col[i + 1] : s0;
        uint4 a0 = *(const uint4*)(XL + (size_t)s0 * 512 + lane_off);
        uint4 a1 = *(const uint4*)(XL + (size_t)s1 * 512 + lane_off);

        float e0, e1;
        {
            f16x2 v0 = u2h2(a0.x) + xr0, v1 = u2h2(a0.y) + xr1;
            f16x2 v2 = u2h2(a0.z) + xr2, v3 = u2h2(a0.w) + xr3;
            f16x2 k0 = v0 * C06 + habs2(v0) * C04;
            f16x2 k1 = v1 * C06 + habs2(v1) * C04;
            f16x2 k2 = v2 * C06 + habs2(v2) * C04;
            f16x2 k3 = v3 * C06 + habs2(v3) * C04;
            e0 = __builtin_amdgcn_fdot2(k0, at0, 0.f, false);
            e0 = __builtin_amdgcn_fdot2(k1, at1, e0, false);
            e0 = __builtin_amdgcn_fdot2(k2, at2, e0, false);
            e0 = __builtin_amdgcn_fdot2(k3, at3, e0, false);
        }
        {
            f16x2 v0 = u2h2(a1.x) + xr0, v1 = u2h2(a1.y) + xr1;
            f16x2 v2 = u2h2(a1.z) + xr2, v3 = u2h2(a1.w) + xr3;
            f16x2 k0 = v0 * C06 + habs2(v0) * C04;
            f16x2 k1 = v1 * C06 + habs2(v1) * C04;
            f16x2 k2 = v2 * C06 + habs2(v2) * C04;
            f16x2 k3 = v3 * C06 + habs2(v3) * C04;
            e1 = __builtin_amdgcn_fdot2(k0, at0, 0.f, false);
            e1 = __builtin_amdgcn_fdot2(k1, at1, e1, false);
            e1 = __builtin_amdgcn_fdot2(k2, at2, e1, false);
            e1 = __builtin_amdgcn_fdot2(k3, at3, e1, false);
        }

#pragma unroll
        for (int m = 1; m < 16; m <<= 1) {
            e0 += __shfl_xor(e0, m, 64);
            e1 += __shfl_xor(e1, m, 64);
        }

        float p0 = __expf(e0);
        float p1 = has2 ? __expf(e1) : 0.f;
        ssum += p0 + p1;

        f32x2 f;
        f = __builtin_convertvector(u2h2(a0.x), f32x2); acc[0] += p0*f[0]; acc[1] += p0*f[1];
        f = __builtin_convertvector(u2h2(a0.y), f32x2); acc[2] += p0*f[0]; acc[3] += p0*f[1];
        f = __builtin_convertvector(u2h2(a0.z), f32x2); acc[4] += p0*f[0]; acc[5] += p0*f[1];
        f = __builtin_convertvector(u2h2(a0.w), f32x2); acc[6] += p0*f[0]; acc[7] += p0*f[1];
        f = __builtin_convertvector(u2h2(a1.x), f32x2); acc[0] += p1*f[0]; acc[1] += p1*f[1];
        f = __builtin_convertvector(u2h2(a1.y), f32x2); acc[2] += p1*f[0]; acc[3] += p1*f[1];
        f = __builtin_convertvector(u2h2(a1.z), f32x2); acc[4] += p1*f[0]; acc[5] += p1*f[1];
        f = __builtin_convertvector(u2h2(a1.w), f32x2); acc[6] += p1*f[0]; acc[7] += p1*f[1];
    }

    // merge the two half-partials (linear, thanks to no-max softmax)
    __shared__ float sh[2][64][9];
    if (half) {
#pragma unroll
        for (int j = 0; j < 8; ++j) sh[slot][l][j] = acc[j];
        sh[slot][l][8] = ssum;
    }
    __syncthreads();
    if (half) return;

#pragma unroll
    for (int j = 0; j < 8; ++j) acc[j] += sh[slot][l][j];
    ssum += sh[slot][l][8];

    // normalize per head, then mean over heads via butterfly across 16/32
    float inv = 1.f / (ssum + 1e-16f);
#pragma unroll
    for (int j = 0; j < 8; ++j) acc[j] *= inv;
#pragma unroll
    for (int j = 0; j < 8; ++j) acc[j] += __shfl_xor(acc[j], 16, 64);
#pragma unroll
    for (int j = 0; j < 8; ++j) acc[j] += __shfl_xor(acc[j], 32, 64);

    if (h == 0) {
        const int dd = e * 8;
        float4 b40 = *(const float4*)(bias + dd);
        float4 b41 = *(const float4*)(bias + dd + 4);
        float y[8];
        y[0] = acc[0]*0.25f + b40.x; y[1] = acc[1]*0.25f + b40.y;
        y[2] = acc[2]*0.25f + b40.z; y[3] = acc[3]*0.25f + b40.w;
        y[4] = acc[4]*0.25f + b41.x; y[5] = acc[5]*0.25f + b41.y;
        y[6] = acc[6]*0.25f + b41.z; y[7] = acc[7]*0.25f + b41.w;

        float s1 = 0.f, s2 = 0.f;
#pragma unroll
        for (int j = 0; j < 8; ++j) { s1 += y[j]; s2 += y[j]*y[j]; }
#pragma unroll
        for (int m = 1; m < 16; m <<= 1) {
            s1 += __shfl_xor(s1, m, 64);
            s2 += __shfl_xor(s2, m, 64);
        }
        float mu = s1 * (1.f / 128.f);
        float var = s2 * (1.f / 128.f) - mu * mu;
        float rstd = rsqrtf(var + LN_EPS);

        float4 g40 = *(const float4*)(gamma + dd);
        float4 g41 = *(const float4*)(gamma + dd + 4);
        float4 e40 = *(const float4*)(beta + dd);
        float4 e41 = *(const float4*)(beta + dd + 4);
        float4 r40 = *(const float4*)(res + (size_t)n * 128 + dd);
        float4 r41 = *(const float4*)(res + (size_t)n * 128 + dd + 4);
        float g[8] = {g40.x,g40.y,g40.z,g40.w,g41.x,g41.y,g41.z,g41.w};
        float be[8] = {e40.x,e40.y,e40.z,e40.w,e41.x,e41.y,e41.z,e41.w};
        float r[8] = {r40.x,r40.y,r40.z,r40.w,r41.x,r41.y,r41.z,r41.w};
#pragma unroll
        for (int j = 0; j < 8; ++j) {
            y[j] = (y[j] - mu) * rstd * g[j] + be[j] + r[j];
            if (relu_flag) y[j] = fmaxf(y[j], 0.f);
        }
        float4 o0 = {y[0],y[1],y[2],y[3]};
        float4 o1 = {y[4],y[5],y[6],y[7]};
        *(float4*)(out + (size_t)n * 128 + dd)     = o0;
        *(float4*)(out + (size_t)n * 128 + dd + 4) = o1;
        if (out_h) {
            ushort4 oh0, oh1;
            oh0.x = f2h(y[0]); oh0.y = f2h(y[1]); oh0.z = f2h(y[2]); oh0.w = f2h(y[3]);
            oh1.x = f2h(y[4]); oh1.y = f2h(y[5]); oh1.z = f2h(y[6]); oh1.w = f2h(y[7]);
            *(ushort4*)(out_h + (size_t)n * 128 + dd)     = oh0;
            *(ushort4*)(out_h + (size_t)n * 128 + dd + 4) = oh1;
        }
    }
}

// ---------------- launch ----------------

extern "C" void kernel_launch(void* const* d_in, const int* in_sizes, int n_in,
                              void* d_out, int out_size, void* d_ws, size_t ws_size,
                              hipStream_t stream) {
    const float* x    = (const float*)d_in[0];
    const int*   src  = (const int*)d_in[1];
    const int*   dst  = (const int*)d_in[2];
    const float* Wl1  = (const float*)d_in[3];
    const float* Wr1  = (const float*)d_in[4];
    const float* att1 = (const float*)d_in[5];
    const float* b1   = (const float*)d_in[6];
    const float* g1   = (const float*)d_in[7];
    const float* be1  = (const float*)d_in[8];
    const float* Wl2  = (const float*)d_in[9];
    const float* Wr2  = (const float*)d_in[10];
    const float* att2 = (const float*)d_in[11];
    const float* b2   = (const float*)d_in[12];
    const float* g2   = (const float*)d_in[13];
    const float* be2  = (const float*)d_in[14];
    float* out = (float*)d_out;

    char* ws = (char*)d_ws;
    size_t off = 0;
    u16*   xlb  = (u16*)(ws + off);   off += (size_t)NNODES * 512 * 2;    // 20.5 MB
    u16*   xrb  = (u16*)(ws + off);   off += (size_t)NNODES * 512 * 2;    // 20.5 MB
    u16*   xb   = (u16*)(ws + off);   off += (size_t)NNODES * 128 * 2;    // 5.1 MB
    float* hbuf = (float*)(ws + off); off += (size_t)NNODES * 128 * 4;    // 10.2 MB
    u16*   Bt1  = (u16*)(ws + off);   off += (size_t)1024 * 128 * 2;
    u16*   Bt2  = (u16*)(ws + off);   off += (size_t)1024 * 128 * 2;
    int*   deg  = (int*)(ws + off);   off += (size_t)NNODES * 4;
    int*   rowp = (int*)(ws + off);   off += (size_t)(NNODES + 1) * 4;
    int*   cur  = (int*)(ws + off);   off += (size_t)NNODES * 4;
    int*   col  = (int*)(ws + off);   off += (size_t)ETOT * 4;

    // CSR build (same graph both layers)
    k_init_deg<<<(NNODES + 255) / 256, 256, 0, stream>>>(deg);
    k_hist<<<(NEDGES + 255) / 256, 256, 0, stream>>>(dst, deg);
    k_scan<<<1, 1024, 0, stream>>>(deg, rowp, cur);
    k_scatter<<<(ETOT + 255) / 256, 256, 0, stream>>>(src, dst, col, cur);

    // conversions
    k_cvt_x<<<(NNODES * 128 / 4 + 255) / 256, 256, 0, stream>>>(x, xb, NNODES * 128 / 4);
    k_cvt_w<<<(1024 * 128 + 255) / 256, 256, 0, stream>>>(Wl1, Wr1, Bt1);
    k_cvt_w<<<(1024 * 128 + 255) / 256, 256, 0, stream>>>(Wl2, Wr2, Bt2);

    // layer 1
    k_gemm_f16<<<NNODES / 32, 512, 0, stream>>>(xb, Bt1, xlb, xrb);
    k_attn<<<NNODES / 2, 256, 0, stream>>>(xlb, xrb, att1, b1, g1, be1, rowp, col,
                                           x, hbuf, xb /*fp16 out for layer2*/, 1);
    // layer 2
    k_gemm_f16<<<NNODES / 32, 512, 0, stream>>>(xb, Bt2, xlb, xrb);
    k_attn<<<NNODES / 2, 256, 0, stream>>>(xlb, xrb, att2, b2, g2, be2, rowp, col,
                                           hbuf, out, (u16*)nullptr, 0);
}

// Round 7
// 240.460 us; speedup vs baseline: 1.1776x; 1.1776x over previous
//
#include <hip/hip_runtime.h>
#include <hip/hip_bf16.h>
#include <hip/hip_fp16.h>

#define NNODES 20000
#define MPAD   20096              // 157 * 128, no M-guards anywhere
#define NEDGES 320000
#define DIM    128
#define NH     4
#define ETOT   (NEDGES + NNODES)
#define LN_EPS 1e-5f

typedef unsigned short u16;
typedef unsigned int   u32;

typedef _Float16 f16x2 __attribute__((ext_vector_type(2)));
typedef _Float16 f16x8 __attribute__((ext_vector_type(8)));
typedef float    f32x2 __attribute__((ext_vector_type(2)));
typedef float    f32x4 __attribute__((ext_vector_type(4)));

__device__ inline u16 f2h(float f) {
    _Float16 h = (_Float16)f;
    union { _Float16 h; u16 u; } v; v.h = h; return v.u;
}
__device__ inline f16x2 u2h2(u32 u) { union { u32 u; f16x2 h; } v; v.u = u; return v.h; }
__device__ inline u32 h22u(f16x2 h) { union { f16x2 h; u32 u; } v; v.h = h; return v.u; }
__device__ inline f16x2 habs2(f16x2 h) { return u2h2(h22u(h) & 0x7FFF7FFFu); }

// ---------------- CSR build ----------------

__global__ void k_init_deg(int* __restrict__ deg) {
    int i = blockIdx.x * blockDim.x + threadIdx.x;
    if (i < NNODES) deg[i] = 1;   // self-loop
}

__global__ void k_hist(const int* __restrict__ dst, int* __restrict__ deg) {
    int i = blockIdx.x * blockDim.x + threadIdx.x;
    if (i < NEDGES) atomicAdd(&deg[dst[i]], 1);
}

__global__ __launch_bounds__(1024) void k_scan(const int* __restrict__ deg,
                                               int* __restrict__ row,
                                               int* __restrict__ cur) {
    __shared__ int part[1024];
    const int CH = (NNODES + 1023) / 1024;  // 20
    int t = threadIdx.x;
    int base = t * CH;
    int s = 0;
    for (int i = 0; i < CH; i++) { int idx = base + i; if (idx < NNODES) s += deg[idx]; }
    part[t] = s;
    __syncthreads();
    for (int off = 1; off < 1024; off <<= 1) {
        int v = (t >= off) ? part[t - off] : 0;
        __syncthreads();
        part[t] += v;
        __syncthreads();
    }
    int run = (t == 0) ? 0 : part[t - 1];
    for (int i = 0; i < CH; i++) {
        int idx = base + i;
        if (idx < NNODES) { row[idx] = run; cur[idx] = run; run += deg[idx]; }
    }
    if (t == 1023) row[NNODES] = part[1023];
}

__global__ void k_scatter(const int* __restrict__ src, const int* __restrict__ dst,
                          int* __restrict__ col, int* __restrict__ cur) {
    int i = blockIdx.x * blockDim.x + threadIdx.x;
    if (i < NEDGES) {
        int d = dst[i];
        int pos = atomicAdd(&cur[d], 1);
        col[pos] = src[i];
    } else if (i < ETOT) {
        int n = i - NEDGES;
        int pos = atomicAdd(&cur[n], 1);
        col[pos] = n;
    }
}

// ---------------- conversions (f32 -> fp16) ----------------

__global__ void k_cvt_x(const float* __restrict__ in, u16* __restrict__ out, int n4) {
    int i = blockIdx.x * blockDim.x + threadIdx.x;
    if (i < n4) {
        float4 v = ((const float4*)in)[i];
        ushort4 o;
        o.x = f2h(v.x); o.y = f2h(v.y); o.z = f2h(v.z); o.w = f2h(v.w);
        ((ushort4*)out)[i] = o;
    }
}

// Bt[n][k] = (n<512 ? Wl[k][n] : Wr[k][n-512]),  n in [0,1024), k in [0,128)
__global__ void k_cvt_w(const float* __restrict__ Wl, const float* __restrict__ Wr,
                        u16* __restrict__ Bt) {
    int idx = blockIdx.x * blockDim.x + threadIdx.x;
    if (idx < 1024 * 128) {
        int n = idx >> 7, k = idx & 127;
        float v = (n < 512) ? Wl[k * 512 + n] : Wr[k * 512 + (n - 512)];
        Bt[idx] = f2h(v);
    }
}

// ------------- fp16 MFMA GEMM: [XL|XR][M,512 each] = A[M,128] @ Bt^T -------------
// 128x128 tile, K=128 single shot, 4 waves (2x2 of 64x64), operand-swapped MFMA.
// A staged in 32KB swizzled LDS; B direct from global (256KB, L2-hot);
// C stored directly from acc. M padded to MPAD: NO guards.

__global__ __launch_bounds__(256, 4) void k_gemm_f16(const u16* __restrict__ A,
                                                     const u16* __restrict__ Bt,
                                                     u16* __restrict__ XL,
                                                     u16* __restrict__ XR) {
    __shared__ u16 smA[128 * 128];   // 32 KB
    const int t  = threadIdx.x;
    const int bm = blockIdx.y * 128;
    const int bn = blockIdx.x * 128;

    // stage A tile, XOR-swizzled rows (byte ^= (row&7)<<4)
    {
        int r  = t >> 4;           // 0..15
        int cb = (t & 15) * 16;    // byte col 0..240
#pragma unroll
        for (int p = 0; p < 8; ++p) {
            int row = p * 16 + r;
            uint4 va = *(const uint4*)(A + (size_t)(bm + row) * 128 + (cb >> 1));
            *(uint4*)((char*)smA + ((row * 256 + cb) ^ ((row & 7) << 4))) = va;
        }
    }

    const int w   = t >> 6;             // wave 0..3
    const int l   = t & 63;
    const int wr  = (w >> 1) * 64;      // M offset of wave subtile
    const int wc  = (w & 1) * 64;       // N offset
    const int lr  = l & 15;
    const int lkb = (l >> 4) * 16;      // byte offset of lane's k-chunk
    const int lkh = (l >> 4) * 8;       // same in halves

    __syncthreads();

    f32x4 acc[4][4] = {};               // [mi][ni], C^T fragments

#pragma unroll
    for (int ks = 0; ks < 4; ++ks) {
        f16x8 bfr[4];
#pragma unroll
        for (int ni = 0; ni < 4; ++ni)
            bfr[ni] = *(const f16x8*)(Bt + (size_t)(bn + wc + ni * 16 + lr) * 128
                                         + ks * 32 + lkh);
        f16x8 af[4];
#pragma unroll
        for (int i = 0; i < 4; ++i) {
            int ra = wr + i * 16 + lr;
            af[i]  = *(const f16x8*)((const char*)smA +
                        ((ra * 256 + ks * 64 + lkb) ^ ((ra & 7) << 4)));
        }
#pragma unroll
        for (int mi = 0; mi < 4; ++mi)
#pragma unroll
            for (int ni = 0; ni < 4; ++ni)
                acc[mi][ni] = __builtin_amdgcn_mfma_f32_16x16x32_f16(
                    bfr[ni], af[mi], acc[mi][ni], 0, 0, 0);
    }

    // epilogue: direct stores, route n<512 -> XL else XR (bn is 0..7; halves at 4)
    const int n4 = (l >> 4) * 4;
#pragma unroll
    for (int mi = 0; mi < 4; ++mi) {
        int m = bm + wr + mi * 16 + lr;
#pragma unroll
        for (int ni = 0; ni < 4; ++ni) {
            int n = bn + wc + ni * 16 + n4;
            f32x4 v = acc[mi][ni];
            ushort4 o;
            o.x = f2h(v[0]); o.y = f2h(v[1]); o.z = f2h(v[2]); o.w = f2h(v[3]);
            u16* dst = (n < 512) ? (XL + (size_t)m * 512 + n)
                                 : (XR + (size_t)m * 512 + (n - 512));
            *(ushort4*)dst = o;
        }
    }
}

// ------------- fused GATv2 attention + head-mean + bias + LN + residual -------------
// ONE wave per node (4 heads x 16 lanes, 8 dims/lane), block = 4 waves = 4 nodes.
// No-max softmax; packed-f16 accumulation (v_pk_fma_f16); 2-edge unroll.

__global__ __launch_bounds__(256) void k_attn(const u16* __restrict__ XL,
                                              const u16* __restrict__ XR,
                                              const float* __restrict__ att,
                                              const float* __restrict__ bias,
                                              const float* __restrict__ gamma,
                                              const float* __restrict__ beta,
                                              const int* __restrict__ row,
                                              const int* __restrict__ col,
                                              const float* __restrict__ res,
                                              float* __restrict__ out,
                                              u16* __restrict__ out_h,
                                              int relu_flag) {
    const int wid = __builtin_amdgcn_readfirstlane(threadIdx.x >> 6);
    const int n   = blockIdx.x * 4 + wid;          // grid = NNODES/4 exactly
    const int l   = threadIdx.x & 63;
    const int h   = l >> 4;                         // head 0..3
    const int e   = l & 15;                         // dim group: dims e*8..e*8+7

    const f16x2 C06 = {(_Float16)0.6f, (_Float16)0.6f};
    const f16x2 C04 = {(_Float16)0.4f, (_Float16)0.4f};

    const size_t lane_off = h * 128 + e * 8;

    uint4 xru = *(const uint4*)(XR + (size_t)n * 512 + lane_off);
    f16x2 xr0 = u2h2(xru.x), xr1 = u2h2(xru.y), xr2 = u2h2(xru.z), xr3 = u2h2(xru.w);

    const float* ap = att + h * 128 + e * 8;
    float4 af0 = *(const float4*)(ap);
    float4 af1 = *(const float4*)(ap + 4);
    f16x2 at0 = {(_Float16)af0.x, (_Float16)af0.y};
    f16x2 at1 = {(_Float16)af0.z, (_Float16)af0.w};
    f16x2 at2 = {(_Float16)af1.x, (_Float16)af1.y};
    f16x2 at3 = {(_Float16)af1.z, (_Float16)af1.w};

    f16x2 acch[4] = {};     // packed f16 accumulators (8 dims)
    float ssum = 0.f;

    const int beg = row[n], end = row[n + 1];

    for (int i = beg; i < end; i += 2) {
        int s0 = col[i];
        bool has2 = (i + 1 < end);
        int s1 = has2 ? col[i + 1] : s0;
        uint4 a0 = *(const uint4*)(XL + (size_t)s0 * 512 + lane_off);
        uint4 a1 = *(const uint4*)(XL + (size_t)s1 * 512 + lane_off);

        float e0, e1;
        {
            f16x2 v0 = u2h2(a0.x) + xr0, v1 = u2h2(a0.y) + xr1;
            f16x2 v2 = u2h2(a0.z) + xr2, v3 = u2h2(a0.w) + xr3;
            f16x2 k0 = v0 * C06 + habs2(v0) * C04;
            f16x2 k1 = v1 * C06 + habs2(v1) * C04;
            f16x2 k2 = v2 * C06 + habs2(v2) * C04;
            f16x2 k3 = v3 * C06 + habs2(v3) * C04;
            e0 = __builtin_amdgcn_fdot2(k0, at0, 0.f, false);
            e0 = __builtin_amdgcn_fdot2(k1, at1, e0, false);
            e0 = __builtin_amdgcn_fdot2(k2, at2, e0, false);
            e0 = __builtin_amdgcn_fdot2(k3, at3, e0, false);
        }
        {
            f16x2 v0 = u2h2(a1.x) + xr0, v1 = u2h2(a1.y) + xr1;
            f16x2 v2 = u2h2(a1.z) + xr2, v3 = u2h2(a1.w) + xr3;
            f16x2 k0 = v0 * C06 + habs2(v0) * C04;
            f16x2 k1 = v1 * C06 + habs2(v1) * C04;
            f16x2 k2 = v2 * C06 + habs2(v2) * C04;
            f16x2 k3 = v3 * C06 + habs2(v3) * C04;
            e1 = __builtin_amdgcn_fdot2(k0, at0, 0.f, false);
            e1 = __builtin_amdgcn_fdot2(k1, at1, e1, false);
            e1 = __builtin_amdgcn_fdot2(k2, at2, e1, false);
            e1 = __builtin_amdgcn_fdot2(k3, at3, e1, false);
        }

#pragma unroll
        for (int m = 1; m < 16; m <<= 1) {
            e0 += __shfl_xor(e0, m, 64);
            e1 += __shfl_xor(e1, m, 64);
        }

        float p0 = __expf(e0);
        float p1 = has2 ? __expf(e1) : 0.f;
        ssum += p0 + p1;

        _Float16 ph0s = (_Float16)p0, ph1s = (_Float16)p1;
        f16x2 ph0 = {ph0s, ph0s};
        f16x2 ph1 = {ph1s, ph1s};
        acch[0] = acch[0] + ph0 * u2h2(a0.x) + ph1 * u2h2(a1.x);
        acch[1] = acch[1] + ph0 * u2h2(a0.y) + ph1 * u2h2(a1.y);
        acch[2] = acch[2] + ph0 * u2h2(a0.z) + ph1 * u2h2(a1.z);
        acch[3] = acch[3] + ph0 * u2h2(a0.w) + ph1 * u2h2(a1.w);
    }

    // unpack to f32, normalize per head, mean over heads via butterfly
    float acc[8];
    {
        f32x2 c;
        c = __builtin_convertvector(acch[0], f32x2); acc[0] = c[0]; acc[1] = c[1];
        c = __builtin_convertvector(acch[1], f32x2); acc[2] = c[0]; acc[3] = c[1];
        c = __builtin_convertvector(acch[2], f32x2); acc[4] = c[0]; acc[5] = c[1];
        c = __builtin_convertvector(acch[3], f32x2); acc[6] = c[0]; acc[7] = c[1];
    }
    float inv = 1.f / (ssum + 1e-16f);
#pragma unroll
    for (int j = 0; j < 8; ++j) acc[j] *= inv;
#pragma unroll
    for (int j = 0; j < 8; ++j) acc[j] += __shfl_xor(acc[j], 16, 64);
#pragma unroll
    for (int j = 0; j < 8; ++j) acc[j] += __shfl_xor(acc[j], 32, 64);

    if (h == 0) {
        const int dd = e * 8;
        float4 b40 = *(const float4*)(bias + dd);
        float4 b41 = *(const float4*)(bias + dd + 4);
        float y[8];
        y[0] = acc[0]*0.25f + b40.x; y[1] = acc[1]*0.25f + b40.y;
        y[2] = acc[2]*0.25f + b40.z; y[3] = acc[3]*0.25f + b40.w;
        y[4] = acc[4]*0.25f + b41.x; y[5] = acc[5]*0.25f + b41.y;
        y[6] = acc[6]*0.25f + b41.z; y[7] = acc[7]*0.25f + b41.w;

        float s1 = 0.f, s2 = 0.f;
#pragma unroll
        for (int j = 0; j < 8; ++j) { s1 += y[j]; s2 += y[j]*y[j]; }
#pragma unroll
        for (int m = 1; m < 16; m <<= 1) {
            s1 += __shfl_xor(s1, m, 64);
            s2 += __shfl_xor(s2, m, 64);
        }
        float mu = s1 * (1.f / 128.f);
        float var = s2 * (1.f / 128.f) - mu * mu;
        float rstd = rsqrtf(var + LN_EPS);

        float4 g40 = *(const float4*)(gamma + dd);
        float4 g41 = *(const float4*)(gamma + dd + 4);
        float4 e40 = *(const float4*)(beta + dd);
        float4 e41 = *(const float4*)(beta + dd + 4);
        float4 r40 = *(const float4*)(res + (size_t)n * 128 + dd);
        float4 r41 = *(const float4*)(res + (size_t)n * 128 + dd + 4);
        float g[8] = {g40.x,g40.y,g40.z,g40.w,g41.x,g41.y,g41.z,g41.w};
        float be[8] = {e40.x,e40.y,e40.z,e40.w,e41.x,e41.y,e41.z,e41.w};
        float r[8] = {r40.x,r40.y,r40.z,r40.w,r41.x,r41.y,r41.z,r41.w};
#pragma unroll
        for (int j = 0; j < 8; ++j) {
            y[j] = (y[j] - mu) * rstd * g[j] + be[j] + r[j];
            if (relu_flag) y[j] = fmaxf(y[j], 0.f);
        }
        float4 o0 = {y[0],y[1],y[2],y[3]};
        float4 o1 = {y[4],y[5],y[6],y[7]};
        *(float4*)(out + (size_t)n * 128 + dd)     = o0;
        *(float4*)(out + (size_t)n * 128 + dd + 4) = o1;
        if (out_h) {
            ushort4 oh0, oh1;
            oh0.x = f2h(y[0]); oh0.y = f2h(y[1]); oh0.z = f2h(y[2]); oh0.w = f2h(y[3]);
            oh1.x = f2h(y[4]); oh1.y = f2h(y[5]); oh1.z = f2h(y[6]); oh1.w = f2h(y[7]);
            *(ushort4*)(out_h + (size_t)n * 128 + dd)     = oh0;
            *(ushort4*)(out_h + (size_t)n * 128 + dd + 4) = oh1;
        }
    }
}

// ---------------- launch ----------------

extern "C" void kernel_launch(void* const* d_in, const int* in_sizes, int n_in,
                              void* d_out, int out_size, void* d_ws, size_t ws_size,
                              hipStream_t stream) {
    const float* x    = (const float*)d_in[0];
    const int*   src  = (const int*)d_in[1];
    const int*   dst  = (const int*)d_in[2];
    const float* Wl1  = (const float*)d_in[3];
    const float* Wr1  = (const float*)d_in[4];
    const float* att1 = (const float*)d_in[5];
    const float* b1   = (const float*)d_in[6];
    const float* g1   = (const float*)d_in[7];
    const float* be1  = (const float*)d_in[8];
    const float* Wl2  = (const float*)d_in[9];
    const float* Wr2  = (const float*)d_in[10];
    const float* att2 = (const float*)d_in[11];
    const float* b2   = (const float*)d_in[12];
    const float* g2   = (const float*)d_in[13];
    const float* be2  = (const float*)d_in[14];
    float* out = (float*)d_out;

    char* ws = (char*)d_ws;
    size_t off = 0;
    u16*   xlb  = (u16*)(ws + off);   off += (size_t)MPAD * 512 * 2;      // padded
    u16*   xrb  = (u16*)(ws + off);   off += (size_t)MPAD * 512 * 2;      // padded
    u16*   xb   = (u16*)(ws + off);   off += (size_t)MPAD * 128 * 2;      // padded
    float* hbuf = (float*)(ws + off); off += (size_t)NNODES * 128 * 4;
    u16*   Bt1  = (u16*)(ws + off);   off += (size_t)1024 * 128 * 2;
    u16*   Bt2  = (u16*)(ws + off);   off += (size_t)1024 * 128 * 2;
    int*   deg  = (int*)(ws + off);   off += (size_t)NNODES * 4;
    int*   rowp = (int*)(ws + off);   off += (size_t)(NNODES + 1) * 4;
    int*   cur  = (int*)(ws + off);   off += (size_t)NNODES * 4;
    int*   col  = (int*)(ws + off);   off += (size_t)ETOT * 4;

    // CSR build (same graph both layers)
    k_init_deg<<<(NNODES + 255) / 256, 256, 0, stream>>>(deg);
    k_hist<<<(NEDGES + 255) / 256, 256, 0, stream>>>(dst, deg);
    k_scan<<<1, 1024, 0, stream>>>(deg, rowp, cur);
    k_scatter<<<(ETOT + 255) / 256, 256, 0, stream>>>(src, dst, col, cur);

    // conversions
    k_cvt_x<<<(NNODES * 128 / 4 + 255) / 256, 256, 0, stream>>>(x, xb, NNODES * 128 / 4);
    k_cvt_w<<<(1024 * 128 + 255) / 256, 256, 0, stream>>>(Wl1, Wr1, Bt1);
    k_cvt_w<<<(1024 * 128 + 255) / 256, 256, 0, stream>>>(Wl2, Wr2, Bt2);

    dim3 ggrid(8, MPAD / 128);   // 8 x 157, no guards

    // layer 1
    k_gemm_f16<<<ggrid, 256, 0, stream>>>(xb, Bt1, xlb, xrb);
    k_attn<<<NNODES / 4, 256, 0, stream>>>(xlb, xrb, att1, b1, g1, be1, rowp, col,
                                           x, hbuf, xb /*fp16 out for layer2*/, 1);
    // layer 2
    k_gemm_f16<<<ggrid, 256, 0, stream>>>(xb, Bt2, xlb, xrb);
    k_attn<<<NNODES / 4, 256, 0, stream>>>(xlb, xrb, att2, b2, g2, be2, rowp, col,
                                           hbuf, out, (u16*)nullptr, 0);
}

// Round 9
// 227.925 us; speedup vs baseline: 1.2423x; 1.0550x over previous
//
#include <hip/hip_runtime.h>
#include <hip/hip_bf16.h>
#include <hip/hip_fp16.h>

#define NNODES 20000
#define MPAD   20096              // 157 * 128, no M-guards anywhere
#define NEDGES 320000
#define DIM    128
#define NH     4
#define ETOT   (NEDGES + NNODES)
#define LN_EPS 1e-5f

typedef unsigned char  u8;
typedef unsigned short u16;
typedef unsigned int   u32;

typedef _Float16 f16x2 __attribute__((ext_vector_type(2)));
typedef _Float16 f16x8 __attribute__((ext_vector_type(8)));
typedef float    f32x2 __attribute__((ext_vector_type(2)));
typedef float    f32x4 __attribute__((ext_vector_type(4)));

__device__ inline u16 f2h(float f) {
    _Float16 h = (_Float16)f;
    union { _Float16 h; u16 u; } v; v.h = h; return v.u;
}
__device__ inline f16x2 u2h2(u32 u) { union { u32 u; f16x2 h; } v; v.u = u; return v.h; }
__device__ inline u32 h22u(f16x2 h) { union { f16x2 h; u32 u; } v; v.h = h; return v.u; }
__device__ inline f16x2 habs2(f16x2 h) { return u2h2(h22u(h) & 0x7FFF7FFFu); }

// async global->LDS, 16B per lane, linear LDS dest (wave-uniform base + lane*16)
#define GLDS16(g, l) __builtin_amdgcn_global_load_lds(                         \
    (const __attribute__((address_space(1))) void*)(g),                        \
    (__attribute__((address_space(3))) void*)(l), 16, 0, 0)

// ---------------- fused prep: deg init + x->f16 + W->Bt f16 ----------------

__global__ void k_prep(const float* __restrict__ x, u16* __restrict__ xb,
                       const float* __restrict__ Wl1, const float* __restrict__ Wr1,
                       u16* __restrict__ Bt1,
                       const float* __restrict__ Wl2, const float* __restrict__ Wr2,
                       u16* __restrict__ Bt2,
                       int* __restrict__ deg) {
    int i = blockIdx.x * blockDim.x + threadIdx.x;
    int stride = gridDim.x * blockDim.x;
    if (i < NNODES) deg[i] = 1;   // self-loop
    for (int j = i; j < NNODES * 32; j += stride) {
        float4 v = ((const float4*)x)[j];
        ushort4 o;
        o.x = f2h(v.x); o.y = f2h(v.y); o.z = f2h(v.z); o.w = f2h(v.w);
        ((ushort4*)xb)[j] = o;
    }
    for (int j = i; j < 1024 * 128; j += stride) {
        int n = j >> 7, k = j & 127;
        Bt1[j] = f2h((n < 512) ? Wl1[k * 512 + n] : Wr1[k * 512 + (n - 512)]);
        Bt2[j] = f2h((n < 512) ? Wl2[k * 512 + n] : Wr2[k * 512 + (n - 512)]);
    }
}

// ---------------- CSR build ----------------

__global__ void k_hist(const int* __restrict__ dst, int* __restrict__ deg) {
    int i = blockIdx.x * blockDim.x + threadIdx.x;
    if (i < NEDGES) atomicAdd(&deg[dst[i]], 1);
}

__global__ __launch_bounds__(1024) void k_scan(const int* __restrict__ deg,
                                               int* __restrict__ row,
                                               int* __restrict__ cur) {
    __shared__ int part[1024];
    const int CH = (NNODES + 1023) / 1024;  // 20
    int t = threadIdx.x;
    int base = t * CH;
    int s = 0;
    for (int i = 0; i < CH; i++) { int idx = base + i; if (idx < NNODES) s += deg[idx]; }
    part[t] = s;
    __syncthreads();
    for (int off = 1; off < 1024; off <<= 1) {
        int v = (t >= off) ? part[t - off] : 0;
        __syncthreads();
        part[t] += v;
        __syncthreads();
    }
    int run = (t == 0) ? 0 : part[t - 1];
    for (int i = 0; i < CH; i++) {
        int idx = base + i;
        if (idx < NNODES) { row[idx] = run; cur[idx] = run; run += deg[idx]; }
    }
    if (t == 1023) row[NNODES] = part[1023];
}

__global__ void k_scatter(const int* __restrict__ src, const int* __restrict__ dst,
                          int* __restrict__ col, int* __restrict__ cur) {
    int i = blockIdx.x * blockDim.x + threadIdx.x;
    if (i < NEDGES) {
        int d = dst[i];
        int pos = atomicAdd(&cur[d], 1);
        col[pos] = src[i];
    } else if (i < ETOT) {
        int n = i - NEDGES;
        int pos = atomicAdd(&cur[n], 1);
        col[pos] = n;
    }
}

// ------------- fp16 MFMA GEMM: [XL|XR][M,512 each] = A[M,128] @ Bt^T -------------
// m97 pattern: BOTH tiles staged via global_load_lds width=16, pre-swizzled global
// source (linear LDS dest == XOR-swizzled tile), K=128 single shot, ONE barrier,
// direct C stores. 64KB LDS -> 2 blocks/CU.

__global__ __launch_bounds__(256, 2) void k_gemm_f16(const u16* __restrict__ A,
                                                     const u16* __restrict__ Bt,
                                                     u16* __restrict__ XL,
                                                     u16* __restrict__ XR) {
    __shared__ u16 smA[128 * 128];   // 32 KB
    __shared__ u16 smB[128 * 128];   // 32 KB
    const int t  = threadIdx.x;
    const int w  = t >> 6;              // wave 0..3
    const int l  = t & 63;
    const int bm = blockIdx.y * 128;
    const int bn = blockIdx.x * 128;

    // stage: wave w covers rows [w*32, w*32+32); 8 chunks of 4 rows (1KB) each.
    // swizzled layout: data of (row, 16B-slot j) lives at slot j^(row&7);
    // lane i (linear dest slot s=i&15, row+=i>>4) loads global slot s^(row&7).
    {
        char* smAb = (char*)smA;
        char* smBb = (char*)smB;
#pragma unroll
        for (int p = 0; p < 8; ++p) {
            int rbase = w * 32 + p * 4;
            int row   = rbase + (l >> 4);
            int j     = (l & 15) ^ (row & 7);
            const u16* ga = A  + (size_t)(bm + row) * 128 + j * 8;
            const u16* gb = Bt + (size_t)(bn + row) * 128 + j * 8;
            GLDS16(ga, smAb + rbase * 256);
            GLDS16(gb, smBb + rbase * 256);
        }
    }
    __syncthreads();   // drains vmcnt (compiler emits full waitcnt before barrier)

    const int wr  = (w >> 1) * 64;      // M offset of wave subtile
    const int wc  = (w & 1) * 64;       // N offset
    const int lr  = l & 15;
    const int lkb = (l >> 4) * 16;      // byte offset of lane's k-chunk

    f32x4 acc[4][4] = {};               // [mi][ni], C^T fragments

#pragma unroll
    for (int ks = 0; ks < 4; ++ks) {
        f16x8 af[4], bfr[4];
#pragma unroll
        for (int i = 0; i < 4; ++i) {
            int ra = wr + i * 16 + lr;
            af[i]  = *(const f16x8*)((const char*)smA +
                        ((ra * 256 + ks * 64 + lkb) ^ ((ra & 7) << 4)));
            int rb = wc + i * 16 + lr;
            bfr[i] = *(const f16x8*)((const char*)smB +
                        ((rb * 256 + ks * 64 + lkb) ^ ((rb & 7) << 4)));
        }
#pragma unroll
        for (int mi = 0; mi < 4; ++mi)
#pragma unroll
            for (int ni = 0; ni < 4; ++ni)
                acc[mi][ni] = __builtin_amdgcn_mfma_f32_16x16x32_f16(
                    bfr[ni], af[mi], acc[mi][ni], 0, 0, 0);
    }

    // epilogue: direct stores, route n<512 -> XL else XR (uniform per block)
    const int n4 = (l >> 4) * 4;
#pragma unroll
    for (int mi = 0; mi < 4; ++mi) {
        int m = bm + wr + mi * 16 + lr;
#pragma unroll
        for (int ni = 0; ni < 4; ++ni) {
            int n = bn + wc + ni * 16 + n4;
            f32x4 v = acc[mi][ni];
            ushort4 o;
            o.x = f2h(v[0]); o.y = f2h(v[1]); o.z = f2h(v[2]); o.w = f2h(v[3]);
            u16* dst = (n < 512) ? (XL + (size_t)m * 512 + n)
                                 : (XR + (size_t)m * 512 + (n - 512));
            *(ushort4*)dst = o;
        }
    }
}

// ------------- fused GATv2 attention + head-mean + bias + LN + residual -------------
// ONE wave per node (4 heads x 16 lanes, 8 dims/lane), block = 4 waves = 4 nodes.
// No-max softmax; packed-f16 accumulation; 2-edge unroll. (R7 structure, fp16 XL.)

__global__ __launch_bounds__(256) void k_attn(const u16* __restrict__ XL,
                                              const u16* __restrict__ XR,
                                              const float* __restrict__ att,
                                              const float* __restrict__ bias,
                                              const float* __restrict__ gamma,
                                              const float* __restrict__ beta,
                                              const int* __restrict__ row,
                                              const int* __restrict__ col,
                                              const float* __restrict__ res,
                                              float* __restrict__ out,
                                              u16* __restrict__ out_h,
                                              int relu_flag) {
    const int wid = __builtin_amdgcn_readfirstlane(threadIdx.x >> 6);
    const int n   = blockIdx.x * 4 + wid;          // grid = NNODES/4 exactly
    const int l   = threadIdx.x & 63;
    const int h   = l >> 4;                         // head 0..3
    const int e   = l & 15;                         // dim group: dims e*8..e*8+7

    const f16x2 C06 = {(_Float16)0.6f, (_Float16)0.6f};
    const f16x2 C04 = {(_Float16)0.4f, (_Float16)0.4f};

    const size_t lane_off = h * 128 + e * 8;

    uint4 xru = *(const uint4*)(XR + (size_t)n * 512 + lane_off);
    f16x2 xr0 = u2h2(xru.x), xr1 = u2h2(xru.y), xr2 = u2h2(xru.z), xr3 = u2h2(xru.w);

    const float* ap = att + lane_off;
    float4 af0 = *(const float4*)(ap);
    float4 af1 = *(const float4*)(ap + 4);
    f16x2 at0 = {(_Float16)af0.x, (_Float16)af0.y};
    f16x2 at1 = {(_Float16)af0.z, (_Float16)af0.w};
    f16x2 at2 = {(_Float16)af1.x, (_Float16)af1.y};
    f16x2 at3 = {(_Float16)af1.z, (_Float16)af1.w};

    f16x2 acch[4] = {};     // packed f16 accumulators (8 dims)
    float ssum = 0.f;

    const int beg = row[n], end = row[n + 1];

    for (int i = beg; i < end; i += 2) {
        int s0 = col[i];
        bool has2 = (i + 1 < end);
        int s1 = has2 ? col[i + 1] : s0;
        uint4 a0 = *(const uint4*)(XL + (size_t)s0 * 512 + lane_off);
        uint4 a1 = *(const uint4*)(XL + (size_t)s1 * 512 + lane_off);

        float e0, e1;
        {
            f16x2 v0 = u2h2(a0.x) + xr0, v1 = u2h2(a0.y) + xr1;
            f16x2 v2 = u2h2(a0.z) + xr2, v3 = u2h2(a0.w) + xr3;
            f16x2 k0 = v0 * C06 + habs2(v0) * C04;
            f16x2 k1 = v1 * C06 + habs2(v1) * C04;
            f16x2 k2 = v2 * C06 + habs2(v2) * C04;
            f16x2 k3 = v3 * C06 + habs2(v3) * C04;
            e0 = __builtin_amdgcn_fdot2(k0, at0, 0.f, false);
            e0 = __builtin_amdgcn_fdot2(k1, at1, e0, false);
            e0 = __builtin_amdgcn_fdot2(k2, at2, e0, false);
            e0 = __builtin_amdgcn_fdot2(k3, at3, e0, false);
        }
        {
            f16x2 v0 = u2h2(a1.x) + xr0, v1 = u2h2(a1.y) + xr1;
            f16x2 v2 = u2h2(a1.z) + xr2, v3 = u2h2(a1.w) + xr3;
            f16x2 k0 = v0 * C06 + habs2(v0) * C04;
            f16x2 k1 = v1 * C06 + habs2(v1) * C04;
            f16x2 k2 = v2 * C06 + habs2(v2) * C04;
            f16x2 k3 = v3 * C06 + habs2(v3) * C04;
            e1 = __builtin_amdgcn_fdot2(k0, at0, 0.f, false);
            e1 = __builtin_amdgcn_fdot2(k1, at1, e1, false);
            e1 = __builtin_amdgcn_fdot2(k2, at2, e1, false);
            e1 = __builtin_amdgcn_fdot2(k3, at3, e1, false);
        }

#pragma unroll
        for (int m = 1; m < 16; m <<= 1) {
            e0 += __shfl_xor(e0, m, 64);
            e1 += __shfl_xor(e1, m, 64);
        }

        float p0 = __expf(e0);
        float p1 = has2 ? __expf(e1) : 0.f;
        ssum += p0 + p1;

        _Float16 ph0s = (_Float16)p0, ph1s = (_Float16)p1;
        f16x2 ph0 = {ph0s, ph0s};
        f16x2 ph1 = {ph1s, ph1s};
        acch[0] = acch[0] + ph0 * u2h2(a0.x) + ph1 * u2h2(a1.x);
        acch[1] = acch[1] + ph0 * u2h2(a0.y) + ph1 * u2h2(a1.y);
        acch[2] = acch[2] + ph0 * u2h2(a0.z) + ph1 * u2h2(a1.z);
        acch[3] = acch[3] + ph0 * u2h2(a0.w) + ph1 * u2h2(a1.w);
    }

    // unpack to f32, normalize per head, mean over heads via butterfly
    float acc[8];
    {
        f32x2 c;
        c = __builtin_convertvector(acch[0], f32x2); acc[0] = c[0]; acc[1] = c[1];
        c = __builtin_convertvector(acch[1], f32x2); acc[2] = c[0]; acc[3] = c[1];
        c = __builtin_convertvector(acch[2], f32x2); acc[4] = c[0]; acc[5] = c[1];
        c = __builtin_convertvector(acch[3], f32x2); acc[6] = c[0]; acc[7] = c[1];
    }
    float inv = 1.f / (ssum + 1e-16f);
#pragma unroll
    for (int j = 0; j < 8; ++j) acc[j] *= inv;
#pragma unroll
    for (int j = 0; j < 8; ++j) acc[j] += __shfl_xor(acc[j], 16, 64);
#pragma unroll
    for (int j = 0; j < 8; ++j) acc[j] += __shfl_xor(acc[j], 32, 64);

    if (h == 0) {
        const int dd = e * 8;
        float4 b40 = *(const float4*)(bias + dd);
        float4 b41 = *(const float4*)(bias + dd + 4);
        float y[8];
        y[0] = acc[0]*0.25f + b40.x; y[1] = acc[1]*0.25f + b40.y;
        y[2] = acc[2]*0.25f + b40.z; y[3] = acc[3]*0.25f + b40.w;
        y[4] = acc[4]*0.25f + b41.x; y[5] = acc[5]*0.25f + b41.y;
        y[6] = acc[6]*0.25f + b41.z; y[7] = acc[7]*0.25f + b41.w;

        float s1 = 0.f, s2 = 0.f;
#pragma unroll
        for (int j = 0; j < 8; ++j) { s1 += y[j]; s2 += y[j]*y[j]; }
#pragma unroll
        for (int m = 1; m < 16; m <<= 1) {
            s1 += __shfl_xor(s1, m, 64);
            s2 += __shfl_xor(s2, m, 64);
        }
        float mu = s1 * (1.f / 128.f);
        float var = s2 * (1.f / 128.f) - mu * mu;
        float rstd = rsqrtf(var + LN_EPS);

        float4 g40 = *(const float4*)(gamma + dd);
        float4 g41 = *(const float4*)(gamma + dd + 4);
        float4 e40 = *(const float4*)(beta + dd);
        float4 e41 = *(const float4*)(beta + dd + 4);
        float4 r40 = *(const float4*)(res + (size_t)n * 128 + dd);
        float4 r41 = *(const float4*)(res + (size_t)n * 128 + dd + 4);
        float g[8] = {g40.x,g40.y,g40.z,g40.w,g41.x,g41.y,g41.z,g41.w};
        float be[8] = {e40.x,e40.y,e40.z,e40.w,e41.x,e41.y,e41.z,e41.w};
        float r[8] = {r40.x,r40.y,r40.z,r40.w,r41.x,r41.y,r41.z,r41.w};
#pragma unroll
        for (int j = 0; j < 8; ++j) {
            y[j] = (y[j] - mu) * rstd * g[j] + be[j] + r[j];
            if (relu_flag) y[j] = fmaxf(y[j], 0.f);
        }
        float4 o0 = {y[0],y[1],y[2],y[3]};
        float4 o1 = {y[4],y[5],y[6],y[7]};
        *(float4*)(out + (size_t)n * 128 + dd)     = o0;
        *(float4*)(out + (size_t)n * 128 + dd + 4) = o1;
        if (out_h) {
            ushort4 oh0, oh1;
            oh0.x = f2h(y[0]); oh0.y = f2h(y[1]); oh0.z = f2h(y[2]); oh0.w = f2h(y[3]);
            oh1.x = f2h(y[4]); oh1.y = f2h(y[5]); oh1.z = f2h(y[6]); oh1.w = f2h(y[7]);
            *(ushort4*)(out_h + (size_t)n * 128 + dd)     = oh0;
            *(ushort4*)(out_h + (size_t)n * 128 + dd + 4) = oh1;
        }
    }
}

// ---------------- launch ----------------

extern "C" void kernel_launch(void* const* d_in, const int* in_sizes, int n_in,
                              void* d_out, int out_size, void* d_ws, size_t ws_size,
                              hipStream_t stream) {
    const float* x    = (const float*)d_in[0];
    const int*   src  = (const int*)d_in[1];
    const int*   dst  = (const int*)d_in[2];
    const float* Wl1  = (const float*)d_in[3];
    const float* Wr1  = (const float*)d_in[4];
    const float* att1 = (const float*)d_in[5];
    const float* b1   = (const float*)d_in[6];
    const float* g1   = (const float*)d_in[7];
    const float* be1  = (const float*)d_in[8];
    const float* Wl2  = (const float*)d_in[9];
    const float* Wr2  = (const float*)d_in[10];
    const float* att2 = (const float*)d_in[11];
    const float* b2   = (const float*)d_in[12];
    const float* g2   = (const float*)d_in[13];
    const float* be2  = (const float*)d_in[14];
    float* out = (float*)d_out;

    char* ws = (char*)d_ws;
    size_t off = 0;
    u16*   xlb  = (u16*)(ws + off);   off += (size_t)MPAD * 512 * 2;      // f16
    u16*   xrb  = (u16*)(ws + off);   off += (size_t)MPAD * 512 * 2;      // f16
    u16*   xb   = (u16*)(ws + off);   off += (size_t)MPAD * 128 * 2;      // f16 A input
    float* hbuf = (float*)(ws + off); off += (size_t)NNODES * 128 * 4;
    u16*   Bt1  = (u16*)(ws + off);   off += (size_t)1024 * 128 * 2;
    u16*   Bt2  = (u16*)(ws + off);   off += (size_t)1024 * 128 * 2;
    int*   deg  = (int*)(ws + off);   off += (size_t)NNODES * 4;
    int*   rowp = (int*)(ws + off);   off += (size_t)(NNODES + 1) * 4;
    int*   cur  = (int*)(ws + off);   off += (size_t)NNODES * 4;
    int*   col  = (int*)(ws + off);   off += (size_t)ETOT * 4;

    // fused prep (deg init + cvt_x + both cvt_w), then CSR build
    k_prep<<<1024, 256, 0, stream>>>(x, xb, Wl1, Wr1, Bt1, Wl2, Wr2, Bt2, deg);
    k_hist<<<(NEDGES + 255) / 256, 256, 0, stream>>>(dst, deg);
    k_scan<<<1, 1024, 0, stream>>>(deg, rowp, cur);
    k_scatter<<<(ETOT + 255) / 256, 256, 0, stream>>>(src, dst, col, cur);

    dim3 ggrid(8, MPAD / 128);   // 8 x 157, no guards

    // layer 1
    k_gemm_f16<<<ggrid, 256, 0, stream>>>(xb, Bt1, xlb, xrb);
    k_attn<<<NNODES / 4, 256, 0, stream>>>(xlb, xrb, att1, b1, g1, be1, rowp, col,
                                           x, hbuf, xb /*fp16 out for layer2*/, 1);
    // layer 2
    k_gemm_f16<<<ggrid, 256, 0, stream>>>(xb, Bt2, xlb, xrb);
    k_attn<<<NNODES / 4, 256, 0, stream>>>(xlb, xrb, att2, b2, g2, be2, rowp, col,
                                           hbuf, out, (u16*)nullptr, 0);
}

// Round 10
// 220.536 us; speedup vs baseline: 1.2839x; 1.0335x over previous
//
#include <hip/hip_runtime.h>
#include <hip/hip_bf16.h>
#include <hip/hip_fp16.h>

#define NNODES 20000
#define MPAD   20480              // 160 * 128 row-tiles, no M-guards anywhere
#define NEDGES 320000
#define DIM    128
#define NH     4
#define ETOT   (NEDGES + NNODES)
#define LN_EPS 1e-5f

typedef unsigned char  u8;
typedef unsigned short u16;
typedef unsigned int   u32;

typedef _Float16 f16x2 __attribute__((ext_vector_type(2)));
typedef _Float16 f16x8 __attribute__((ext_vector_type(8)));
typedef float    f32x2 __attribute__((ext_vector_type(2)));
typedef float    f32x4 __attribute__((ext_vector_type(4)));

__device__ inline u16 f2h(float f) {
    _Float16 h = (_Float16)f;
    union { _Float16 h; u16 u; } v; v.h = h; return v.u;
}
__device__ inline f16x2 u2h2(u32 u) { union { u32 u; f16x2 h; } v; v.u = u; return v.h; }
__device__ inline u32 h22u(f16x2 h) { union { f16x2 h; u32 u; } v; v.h = h; return v.u; }
__device__ inline f16x2 habs2(f16x2 h) { return u2h2(h22u(h) & 0x7FFF7FFFu); }

// async global->LDS, 16B per lane, linear LDS dest (wave-uniform base + lane*16)
#define GLDS16(g, l) __builtin_amdgcn_global_load_lds(                         \
    (const __attribute__((address_space(1))) void*)(g),                        \
    (__attribute__((address_space(3))) void*)(l), 16, 0, 0)

// ---------------- fused prep: deg init + x->f16 + W->Bt f16 ----------------

__global__ void k_prep(const float* __restrict__ x, u16* __restrict__ xb,
                       const float* __restrict__ Wl1, const float* __restrict__ Wr1,
                       u16* __restrict__ Bt1,
                       const float* __restrict__ Wl2, const float* __restrict__ Wr2,
                       u16* __restrict__ Bt2,
                       int* __restrict__ deg) {
    int i = blockIdx.x * blockDim.x + threadIdx.x;
    int stride = gridDim.x * blockDim.x;
    if (i < NNODES) deg[i] = 1;   // self-loop
    for (int j = i; j < NNODES * 32; j += stride) {
        float4 v = ((const float4*)x)[j];
        ushort4 o;
        o.x = f2h(v.x); o.y = f2h(v.y); o.z = f2h(v.z); o.w = f2h(v.w);
        ((ushort4*)xb)[j] = o;
    }
    for (int j = i; j < 1024 * 128; j += stride) {
        int n = j >> 7, k = j & 127;
        Bt1[j] = f2h((n < 512) ? Wl1[k * 512 + n] : Wr1[k * 512 + (n - 512)]);
        Bt2[j] = f2h((n < 512) ? Wl2[k * 512 + n] : Wr2[k * 512 + (n - 512)]);
    }
}

// ---------------- CSR build ----------------

__global__ void k_hist(const int* __restrict__ dst, int* __restrict__ deg) {
    int i = blockIdx.x * blockDim.x + threadIdx.x;
    if (i < NEDGES) atomicAdd(&deg[dst[i]], 1);
}

__global__ __launch_bounds__(1024) void k_scan(const int* __restrict__ deg,
                                               int* __restrict__ row,
                                               int* __restrict__ cur) {
    __shared__ int part[1024];
    const int CH = (NNODES + 1023) / 1024;  // 20
    int t = threadIdx.x;
    int base = t * CH;
    int s = 0;
    for (int i = 0; i < CH; i++) { int idx = base + i; if (idx < NNODES) s += deg[idx]; }
    part[t] = s;
    __syncthreads();
    for (int off = 1; off < 1024; off <<= 1) {
        int v = (t >= off) ? part[t - off] : 0;
        __syncthreads();
        part[t] += v;
        __syncthreads();
    }
    int run = (t == 0) ? 0 : part[t - 1];
    for (int i = 0; i < CH; i++) {
        int idx = base + i;
        if (idx < NNODES) { row[idx] = run; cur[idx] = run; run += deg[idx]; }
    }
    if (t == 1023) row[NNODES] = part[1023];
}

__global__ void k_scatter(const int* __restrict__ src, const int* __restrict__ dst,
                          int* __restrict__ col, int* __restrict__ cur) {
    int i = blockIdx.x * blockDim.x + threadIdx.x;
    if (i < NEDGES) {
        int d = dst[i];
        int pos = atomicAdd(&cur[d], 1);
        col[pos] = src[i];
    } else if (i < ETOT) {
        int n = i - NEDGES;
        int pos = atomicAdd(&cur[n], 1);
        col[pos] = n;
    }
}

// ------------- fp16 MFMA GEMM: [XL|XR][M,512 each] = A[M,128] @ Bt^T -------------
// m97 pattern + XCD-locality: 1D grid 1280 = 8 XCD x (20 by x 8 bx); each XCD owns
// 20 contiguous A row-tiles -> A staged from HBM once, L2-resident for bx re-reads.
// Both tiles via global_load_lds w=16 with pre-swizzled source; one barrier; direct C.

__global__ __launch_bounds__(256, 2) void k_gemm_f16(const u16* __restrict__ A,
                                                     const u16* __restrict__ Bt,
                                                     u16* __restrict__ XL,
                                                     u16* __restrict__ XR) {
    __shared__ u16 smA[128 * 128];   // 32 KB
    __shared__ u16 smB[128 * 128];   // 32 KB
    const int L   = blockIdx.x;         // 0..1279
    const int xcd = L & 7;
    const int w9  = L >> 3;             // 0..159
    const int bm  = (xcd * 20 + (w9 % 20)) * 128;   // by in [20*xcd, 20*xcd+20)
    const int bn  = (w9 / 20) * 128;                // bx 0..7
    const int t  = threadIdx.x;
    const int w  = t >> 6;              // wave 0..3
    const int l  = t & 63;

    // stage: wave w covers rows [w*32, w*32+32); 8 chunks of 4 rows (1KB) each.
    {
        char* smAb = (char*)smA;
        char* smBb = (char*)smB;
#pragma unroll
        for (int p = 0; p < 8; ++p) {
            int rbase = w * 32 + p * 4;
            int row   = rbase + (l >> 4);
            int j     = (l & 15) ^ (row & 7);
            const u16* ga = A  + (size_t)(bm + row) * 128 + j * 8;
            const u16* gb = Bt + (size_t)(bn + row) * 128 + j * 8;
            GLDS16(ga, smAb + rbase * 256);
            GLDS16(gb, smBb + rbase * 256);
        }
    }
    __syncthreads();

    const int wr  = (w >> 1) * 64;      // M offset of wave subtile
    const int wc  = (w & 1) * 64;       // N offset
    const int lr  = l & 15;
    const int lkb = (l >> 4) * 16;      // byte offset of lane's k-chunk

    f32x4 acc[4][4] = {};               // [mi][ni], C^T fragments

#pragma unroll
    for (int ks = 0; ks < 4; ++ks) {
        f16x8 af[4], bfr[4];
#pragma unroll
        for (int i = 0; i < 4; ++i) {
            int ra = wr + i * 16 + lr;
            af[i]  = *(const f16x8*)((const char*)smA +
                        ((ra * 256 + ks * 64 + lkb) ^ ((ra & 7) << 4)));
            int rb = wc + i * 16 + lr;
            bfr[i] = *(const f16x8*)((const char*)smB +
                        ((rb * 256 + ks * 64 + lkb) ^ ((rb & 7) << 4)));
        }
#pragma unroll
        for (int mi = 0; mi < 4; ++mi)
#pragma unroll
            for (int ni = 0; ni < 4; ++ni)
                acc[mi][ni] = __builtin_amdgcn_mfma_f32_16x16x32_f16(
                    bfr[ni], af[mi], acc[mi][ni], 0, 0, 0);
    }

    // epilogue: direct stores, route n<512 -> XL else XR (uniform per block)
    const int n4 = (l >> 4) * 4;
#pragma unroll
    for (int mi = 0; mi < 4; ++mi) {
        int m = bm + wr + mi * 16 + lr;
#pragma unroll
        for (int ni = 0; ni < 4; ++ni) {
            int n = bn + wc + ni * 16 + n4;
            f32x4 v = acc[mi][ni];
            ushort4 o;
            o.x = f2h(v[0]); o.y = f2h(v[1]); o.z = f2h(v[2]); o.w = f2h(v[3]);
            u16* dst = (n < 512) ? (XL + (size_t)m * 512 + n)
                                 : (XR + (size_t)m * 512 + (n - 512));
            *(ushort4*)dst = o;
        }
    }
}

// ------------- fused GATv2 attention + head-mean + bias + LN + residual -------------
// ONE wave per node (4 heads x 16 lanes, 8 dims/lane), block = 4 waves = 4 nodes.
// No-max softmax; packed-f16 accumulation; 2-edge pairs with EXPLICIT 2-deep
// software pipeline: gathers for pair+1 and col-reads for pair+2 issued before
// computing the current pair (hides L2 gather latency under the VALU chain).

__global__ __launch_bounds__(256) void k_attn(const u16* __restrict__ XL,
                                              const u16* __restrict__ XR,
                                              const float* __restrict__ att,
                                              const float* __restrict__ bias,
                                              const float* __restrict__ gamma,
                                              const float* __restrict__ beta,
                                              const int* __restrict__ row,
                                              const int* __restrict__ col,
                                              const float* __restrict__ res,
                                              float* __restrict__ out,
                                              u16* __restrict__ out_h,
                                              int relu_flag) {
    const int wid = __builtin_amdgcn_readfirstlane(threadIdx.x >> 6);
    const int n   = blockIdx.x * 4 + wid;          // grid = NNODES/4 exactly
    const int l   = threadIdx.x & 63;
    const int h   = l >> 4;                         // head 0..3
    const int e   = l & 15;                         // dim group: dims e*8..e*8+7

    const f16x2 C06 = {(_Float16)0.6f, (_Float16)0.6f};
    const f16x2 C04 = {(_Float16)0.4f, (_Float16)0.4f};

    const size_t lane_off = h * 128 + e * 8;

    uint4 xru = *(const uint4*)(XR + (size_t)n * 512 + lane_off);
    f16x2 xr0 = u2h2(xru.x), xr1 = u2h2(xru.y), xr2 = u2h2(xru.z), xr3 = u2h2(xru.w);

    const float* ap = att + lane_off;
    float4 af0 = *(const float4*)(ap);
    float4 af1 = *(const float4*)(ap + 4);
    f16x2 at0 = {(_Float16)af0.x, (_Float16)af0.y};
    f16x2 at1 = {(_Float16)af0.z, (_Float16)af0.w};
    f16x2 at2 = {(_Float16)af1.x, (_Float16)af1.y};
    f16x2 at3 = {(_Float16)af1.z, (_Float16)af1.w};

    f16x2 acch[4] = {};     // packed f16 accumulators (8 dims)
    float ssum = 0.f;

    const int beg = row[n], end = row[n + 1];

    // ---- pipeline prologue ----
    int i = beg;
    int j = i + 2;
    {
        int c0 = col[i];
        int c1 = (i + 1 < end) ? col[i + 1] : c0;
        uint4 a0 = *(const uint4*)(XL + (size_t)c0 * 512 + lane_off);
        uint4 a1 = *(const uint4*)(XL + (size_t)c1 * 512 + lane_off);
        bool morej = j < end;
        int d0 = 0, d1 = 0;
        if (morej) { d0 = col[j]; d1 = (j + 1 < end) ? col[j + 1] : d0; }

        while (true) {
            // issue next pair's gathers (no deps on compute below)
            uint4 b0, b1;
            if (morej) {
                b0 = *(const uint4*)(XL + (size_t)d0 * 512 + lane_off);
                b1 = *(const uint4*)(XL + (size_t)d1 * 512 + lane_off);
            }
            // prefetch next-next pair's col indices
            int k2 = j + 2;
            bool morek = morej && (k2 < end);
            int e0c = 0, e1c = 0;
            if (morek) { e0c = col[k2]; e1c = (k2 + 1 < end) ? col[k2 + 1] : e0c; }

            // ---- compute current pair (a0, a1) ----
            bool has2 = (i + 1 < end);
            float e0, e1;
            {
                f16x2 v0 = u2h2(a0.x) + xr0, v1 = u2h2(a0.y) + xr1;
                f16x2 v2 = u2h2(a0.z) + xr2, v3 = u2h2(a0.w) + xr3;
                f16x2 k0 = v0 * C06 + habs2(v0) * C04;
                f16x2 k1 = v1 * C06 + habs2(v1) * C04;
                f16x2 k2h = v2 * C06 + habs2(v2) * C04;
                f16x2 k3 = v3 * C06 + habs2(v3) * C04;
                e0 = __builtin_amdgcn_fdot2(k0, at0, 0.f, false);
                e0 = __builtin_amdgcn_fdot2(k1, at1, e0, false);
                e0 = __builtin_amdgcn_fdot2(k2h, at2, e0, false);
                e0 = __builtin_amdgcn_fdot2(k3, at3, e0, false);
            }
            {
                f16x2 v0 = u2h2(a1.x) + xr0, v1 = u2h2(a1.y) + xr1;
                f16x2 v2 = u2h2(a1.z) + xr2, v3 = u2h2(a1.w) + xr3;
                f16x2 k0 = v0 * C06 + habs2(v0) * C04;
                f16x2 k1 = v1 * C06 + habs2(v1) * C04;
                f16x2 k2h = v2 * C06 + habs2(v2) * C04;
                f16x2 k3 = v3 * C06 + habs2(v3) * C04;
                e1 = __builtin_amdgcn_fdot2(k0, at0, 0.f, false);
                e1 = __builtin_amdgcn_fdot2(k1, at1, e1, false);
                e1 = __builtin_amdgcn_fdot2(k2h, at2, e1, false);
                e1 = __builtin_amdgcn_fdot2(k3, at3, e1, false);
            }
#pragma unroll
            for (int m = 1; m < 16; m <<= 1) {
                e0 += __shfl_xor(e0, m, 64);
                e1 += __shfl_xor(e1, m, 64);
            }
            float p0 = __expf(e0);
            float p1 = has2 ? __expf(e1) : 0.f;
            ssum += p0 + p1;
            _Float16 ph0s = (_Float16)p0, ph1s = (_Float16)p1;
            f16x2 ph0 = {ph0s, ph0s};
            f16x2 ph1 = {ph1s, ph1s};
            acch[0] = acch[0] + ph0 * u2h2(a0.x) + ph1 * u2h2(a1.x);
            acch[1] = acch[1] + ph0 * u2h2(a0.y) + ph1 * u2h2(a1.y);
            acch[2] = acch[2] + ph0 * u2h2(a0.z) + ph1 * u2h2(a1.z);
            acch[3] = acch[3] + ph0 * u2h2(a0.w) + ph1 * u2h2(a1.w);

            // ---- advance pipeline ----
            if (!morej) break;
            a0 = b0; a1 = b1;
            i = j; j = k2;
            d0 = e0c; d1 = e1c;
            morej = morek;
        }
    }

    // unpack to f32, normalize per head, mean over heads via butterfly
    float acc[8];
    {
        f32x2 c;
        c = __builtin_convertvector(acch[0], f32x2); acc[0] = c[0]; acc[1] = c[1];
        c = __builtin_convertvector(acch[1], f32x2); acc[2] = c[0]; acc[3] = c[1];
        c = __builtin_convertvector(acch[2], f32x2); acc[4] = c[0]; acc[5] = c[1];
        c = __builtin_convertvector(acch[3], f32x2); acc[6] = c[0]; acc[7] = c[1];
    }
    float inv = 1.f / (ssum + 1e-16f);
#pragma unroll
    for (int jj = 0; jj < 8; ++jj) acc[jj] *= inv;
#pragma unroll
    for (int jj = 0; jj < 8; ++jj) acc[jj] += __shfl_xor(acc[jj], 16, 64);
#pragma unroll
    for (int jj = 0; jj < 8; ++jj) acc[jj] += __shfl_xor(acc[jj], 32, 64);

    if (h == 0) {
        const int dd = e * 8;
        float4 b40 = *(const float4*)(bias + dd);
        float4 b41 = *(const float4*)(bias + dd + 4);
        float y[8];
        y[0] = acc[0]*0.25f + b40.x; y[1] = acc[1]*0.25f + b40.y;
        y[2] = acc[2]*0.25f + b40.z; y[3] = acc[3]*0.25f + b40.w;
        y[4] = acc[4]*0.25f + b41.x; y[5] = acc[5]*0.25f + b41.y;
        y[6] = acc[6]*0.25f + b41.z; y[7] = acc[7]*0.25f + b41.w;

        float s1 = 0.f, s2 = 0.f;
#pragma unroll
        for (int jj = 0; jj < 8; ++jj) { s1 += y[jj]; s2 += y[jj]*y[jj]; }
#pragma unroll
        for (int m = 1; m < 16; m <<= 1) {
            s1 += __shfl_xor(s1, m, 64);
            s2 += __shfl_xor(s2, m, 64);
        }
        float mu = s1 * (1.f / 128.f);
        float var = s2 * (1.f / 128.f) - mu * mu;
        float rstd = rsqrtf(var + LN_EPS);

        float4 g40 = *(const float4*)(gamma + dd);
        float4 g41 = *(const float4*)(gamma + dd + 4);
        float4 e40 = *(const float4*)(beta + dd);
        float4 e41 = *(const float4*)(beta + dd + 4);
        float4 r40 = *(const float4*)(res + (size_t)n * 128 + dd);
        float4 r41 = *(const float4*)(res + (size_t)n * 128 + dd + 4);
        float g[8] = {g40.x,g40.y,g40.z,g40.w,g41.x,g41.y,g41.z,g41.w};
        float be[8] = {e40.x,e40.y,e40.z,e40.w,e41.x,e41.y,e41.z,e41.w};
        float r[8] = {r40.x,r40.y,r40.z,r40.w,r41.x,r41.y,r41.z,r41.w};
#pragma unroll
        for (int jj = 0; jj < 8; ++jj) {
            y[jj] = (y[jj] - mu) * rstd * g[jj] + be[jj] + r[jj];
            if (relu_flag) y[jj] = fmaxf(y[jj], 0.f);
        }
        float4 o0 = {y[0],y[1],y[2],y[3]};
        float4 o1 = {y[4],y[5],y[6],y[7]};
        *(float4*)(out + (size_t)n * 128 + dd)     = o0;
        *(float4*)(out + (size_t)n * 128 + dd + 4) = o1;
        if (out_h) {
            ushort4 oh0, oh1;
            oh0.x = f2h(y[0]); oh0.y = f2h(y[1]); oh0.z = f2h(y[2]); oh0.w = f2h(y[3]);
            oh1.x = f2h(y[4]); oh1.y = f2h(y[5]); oh1.z = f2h(y[6]); oh1.w = f2h(y[7]);
            *(ushort4*)(out_h + (size_t)n * 128 + dd)     = oh0;
            *(ushort4*)(out_h + (size_t)n * 128 + dd + 4) = oh1;
        }
    }
}

// ---------------- launch ----------------

extern "C" void kernel_launch(void* const* d_in, const int* in_sizes, int n_in,
                              void* d_out, int out_size, void* d_ws, size_t ws_size,
                              hipStream_t stream) {
    const float* x    = (const float*)d_in[0];
    const int*   src  = (const int*)d_in[1];
    const int*   dst  = (const int*)d_in[2];
    const float* Wl1  = (const float*)d_in[3];
    const float* Wr1  = (const float*)d_in[4];
    const float* att1 = (const float*)d_in[5];
    const float* b1   = (const float*)d_in[6];
    const float* g1   = (const float*)d_in[7];
    const float* be1  = (const float*)d_in[8];
    const float* Wl2  = (const float*)d_in[9];
    const float* Wr2  = (const float*)d_in[10];
    const float* att2 = (const float*)d_in[11];
    const float* b2   = (const float*)d_in[12];
    const float* g2   = (const float*)d_in[13];
    const float* be2  = (const float*)d_in[14];
    float* out = (float*)d_out;

    char* ws = (char*)d_ws;
    size_t off = 0;
    u16*   xlb  = (u16*)(ws + off);   off += (size_t)MPAD * 512 * 2;      // f16
    u16*   xrb  = (u16*)(ws + off);   off += (size_t)MPAD * 512 * 2;      // f16
    u16*   xb   = (u16*)(ws + off);   off += (size_t)MPAD * 128 * 2;      // f16 A input
    float* hbuf = (float*)(ws + off); off += (size_t)NNODES * 128 * 4;
    u16*   Bt1  = (u16*)(ws + off);   off += (size_t)1024 * 128 * 2;
    u16*   Bt2  = (u16*)(ws + off);   off += (size_t)1024 * 128 * 2;
    int*   deg  = (int*)(ws + off);   off += (size_t)NNODES * 4;
    int*   rowp = (int*)(ws + off);   off += (size_t)(NNODES + 1) * 4;
    int*   cur  = (int*)(ws + off);   off += (size_t)NNODES * 4;
    int*   col  = (int*)(ws + off);   off += (size_t)ETOT * 4;

    // fused prep (deg init + cvt_x + both cvt_w), then CSR build
    k_prep<<<1024, 256, 0, stream>>>(x, xb, Wl1, Wr1, Bt1, Wl2, Wr2, Bt2, deg);
    k_hist<<<(NEDGES + 255) / 256, 256, 0, stream>>>(dst, deg);
    k_scan<<<1, 1024, 0, stream>>>(deg, rowp, cur);
    k_scatter<<<(ETOT + 255) / 256, 256, 0, stream>>>(src, dst, col, cur);

    // layer 1
    k_gemm_f16<<<MPAD / 128 * 8, 256, 0, stream>>>(xb, Bt1, xlb, xrb);
    k_attn<<<NNODES / 4, 256, 0, stream>>>(xlb, xrb, att1, b1, g1, be1, rowp, col,
                                           x, hbuf, xb /*fp16 out for layer2*/, 1);
    // layer 2
    k_gemm_f16<<<MPAD / 128 * 8, 256, 0, stream>>>(xb, Bt2, xlb, xrb);
    k_attn<<<NNODES / 4, 256, 0, stream>>>(xlb, xrb, att2, b2, g2, be2, rowp, col,
                                           hbuf, out, (u16*)nullptr, 0);
}

// Round 11
// 213.313 us; speedup vs baseline: 1.3274x; 1.0339x over previous
//
#include <hip/hip_runtime.h>
#include <hip/hip_bf16.h>
#include <hip/hip_fp16.h>

#define NNODES 20000
#define MPAD   20480              // 160 * 128 row-tiles, no M-guards anywhere
#define NEDGES 320000
#define DIM    128
#define NH     4
#define ETOT   (NEDGES + NNODES)
#define LN_EPS 1e-5f

typedef unsigned char  u8;
typedef unsigned short u16;
typedef unsigned int   u32;

typedef _Float16 f16x2 __attribute__((ext_vector_type(2)));
typedef _Float16 f16x8 __attribute__((ext_vector_type(8)));
typedef float    f32x2 __attribute__((ext_vector_type(2)));
typedef float    f32x4 __attribute__((ext_vector_type(4)));

__device__ inline u16 f2h(float f) {
    _Float16 h = (_Float16)f;
    union { _Float16 h; u16 u; } v; v.h = h; return v.u;
}
__device__ inline f16x2 u2h2(u32 u) { union { u32 u; f16x2 h; } v; v.u = u; return v.h; }
__device__ inline u32 h22u(f16x2 h) { union { f16x2 h; u32 u; } v; v.h = h; return v.u; }
__device__ inline f16x2 habs2(f16x2 h) { return u2h2(h22u(h) & 0x7FFF7FFFu); }

// async global->LDS, 16B per lane, linear LDS dest (wave-uniform base + lane*16)
#define GLDS16(g, l) __builtin_amdgcn_global_load_lds(                         \
    (const __attribute__((address_space(1))) void*)(g),                        \
    (__attribute__((address_space(3))) void*)(l), 16, 0, 0)

// ---------------- fused prep: deg init + x->f16 + W->Bt f16 ----------------

__global__ void k_prep(const float* __restrict__ x, u16* __restrict__ xb,
                       const float* __restrict__ Wl1, const float* __restrict__ Wr1,
                       u16* __restrict__ Bt1,
                       const float* __restrict__ Wl2, const float* __restrict__ Wr2,
                       u16* __restrict__ Bt2,
                       int* __restrict__ deg) {
    int i = blockIdx.x * blockDim.x + threadIdx.x;
    int stride = gridDim.x * blockDim.x;
    if (i < NNODES) deg[i] = 1;   // self-loop
    for (int j = i; j < NNODES * 32; j += stride) {
        float4 v = ((const float4*)x)[j];
        ushort4 o;
        o.x = f2h(v.x); o.y = f2h(v.y); o.z = f2h(v.z); o.w = f2h(v.w);
        ((ushort4*)xb)[j] = o;
    }
    for (int j = i; j < 1024 * 128; j += stride) {
        int n = j >> 7, k = j & 127;
        Bt1[j] = f2h((n < 512) ? Wl1[k * 512 + n] : Wr1[k * 512 + (n - 512)]);
        Bt2[j] = f2h((n < 512) ? Wl2[k * 512 + n] : Wr2[k * 512 + (n - 512)]);
    }
}

// ---------------- CSR build ----------------

__global__ void k_hist(const int* __restrict__ dst, int* __restrict__ deg) {
    int i = blockIdx.x * blockDim.x + threadIdx.x;
    if (i < NEDGES) atomicAdd(&deg[dst[i]], 1);
}

__global__ __launch_bounds__(1024) void k_scan(const int* __restrict__ deg,
                                               int* __restrict__ row,
                                               int* __restrict__ cur) {
    __shared__ int part[1024];
    const int CH = (NNODES + 1023) / 1024;  // 20
    int t = threadIdx.x;
    int base = t * CH;
    int s = 0;
    for (int i = 0; i < CH; i++) { int idx = base + i; if (idx < NNODES) s += deg[idx]; }
    part[t] = s;
    __syncthreads();
    for (int off = 1; off < 1024; off <<= 1) {
        int v = (t >= off) ? part[t - off] : 0;
        __syncthreads();
        part[t] += v;
        __syncthreads();
    }
    int run = (t == 0) ? 0 : part[t - 1];
    for (int i = 0; i < CH; i++) {
        int idx = base + i;
        if (idx < NNODES) { row[idx] = run; cur[idx] = run; run += deg[idx]; }
    }
    if (t == 1023) row[NNODES] = part[1023];
}

__global__ void k_scatter(const int* __restrict__ src, const int* __restrict__ dst,
                          int* __restrict__ col, int* __restrict__ cur) {
    int i = blockIdx.x * blockDim.x + threadIdx.x;
    if (i < NEDGES) {
        int d = dst[i];
        int pos = atomicAdd(&cur[d], 1);
        col[pos] = src[i];
    } else if (i < ETOT) {
        int n = i - NEDGES;
        int pos = atomicAdd(&cur[n], 1);
        col[pos] = n;
    }
}

// ------------- fp16 MFMA GEMM: [XL|XR][M,512 each] = A[M,128] @ Bt^T -------------
// m97 pattern + XCD-locality (bn FASTEST: A-tile L2-resident across its 8 bn-blocks,
// A fetched from HBM once). Both tiles via global_load_lds w=16 with pre-swizzled
// source; one barrier; C staged through LDS for coalesced 256B-row writes.

__global__ __launch_bounds__(256, 2) void k_gemm_f16(const u16* __restrict__ A,
                                                     const u16* __restrict__ Bt,
                                                     u16* __restrict__ XL,
                                                     u16* __restrict__ XR) {
    __shared__ u16 smA[128 * 128];   // 32 KB
    __shared__ u16 smB[128 * 128];   // 32 KB
    const int L   = blockIdx.x;         // 0..1279
    const int xcd = L & 7;
    const int w9  = L >> 3;             // 0..159
    const int bm  = (xcd * 20 + (w9 >> 3)) * 128;   // 20 row-tiles per XCD
    const int bn  = (w9 & 7) * 128;                 // bn fastest -> A-tile reuse in L2
    const int t  = threadIdx.x;
    const int w  = t >> 6;              // wave 0..3
    const int l  = t & 63;

    // stage: wave w covers rows [w*32, w*32+32); 8 chunks of 4 rows (1KB) each.
    // swizzled layout: data of (row, 16B-slot j) lives at slot j^(row&7).
    {
        char* smAb = (char*)smA;
        char* smBb = (char*)smB;
#pragma unroll
        for (int p = 0; p < 8; ++p) {
            int rbase = w * 32 + p * 4;
            int row   = rbase + (l >> 4);
            int j     = (l & 15) ^ (row & 7);
            const u16* ga = A  + (size_t)(bm + row) * 128 + j * 8;
            const u16* gb = Bt + (size_t)(bn + row) * 128 + j * 8;
            GLDS16(ga, smAb + rbase * 256);
            GLDS16(gb, smBb + rbase * 256);
        }
    }
    __syncthreads();

    const int wr  = (w >> 1) * 64;      // M offset of wave subtile
    const int wc  = (w & 1) * 64;       // N offset
    const int lr  = l & 15;
    const int lkb = (l >> 4) * 16;      // byte offset of lane's k-chunk

    f32x4 acc[4][4] = {};               // [mi][ni], C^T fragments

#pragma unroll
    for (int ks = 0; ks < 4; ++ks) {
        f16x8 af[4], bfr[4];
#pragma unroll
        for (int i = 0; i < 4; ++i) {
            int ra = wr + i * 16 + lr;
            af[i]  = *(const f16x8*)((const char*)smA +
                        ((ra * 256 + ks * 64 + lkb) ^ ((ra & 7) << 4)));
            int rb = wc + i * 16 + lr;
            bfr[i] = *(const f16x8*)((const char*)smB +
                        ((rb * 256 + ks * 64 + lkb) ^ ((rb & 7) << 4)));
        }
#pragma unroll
        for (int mi = 0; mi < 4; ++mi)
#pragma unroll
            for (int ni = 0; ni < 4; ++ni)
                acc[mi][ni] = __builtin_amdgcn_mfma_f32_16x16x32_f16(
                    bfr[ni], af[mi], acc[mi][ni], 0, 0, 0);
    }

    // epilogue: acc -> LDS (swizzled, conflict-free) -> coalesced 256B-row writes
    __syncthreads();                     // all LDS reads done; reuse smA as C tile
    u16* smC = smA;
    {
        const int n4 = (l >> 4) * 4;
#pragma unroll
        for (int mi = 0; mi < 4; ++mi) {
            int m = wr + mi * 16 + lr;
#pragma unroll
            for (int ni = 0; ni < 4; ++ni) {
                int n = wc + ni * 16 + n4;
                f32x4 v = acc[mi][ni];
                ushort4 o;
                o.x = f2h(v[0]); o.y = f2h(v[1]); o.z = f2h(v[2]); o.w = f2h(v[3]);
                *(ushort4*)((char*)smC + (m * 256 + ((n * 2) ^ ((m & 7) << 4)))) = o;
            }
        }
    }
    __syncthreads();
    {
        int r  = t >> 4;                 // 0..15
        int cb = (t & 15) * 16;          // byte col 0..240
        const bool left = (bn < 512);
        u16* base = left ? (XL + bn) : (XR + (bn - 512));
#pragma unroll
        for (int p = 0; p < 8; ++p) {
            int row = p * 16 + r;
            uint4 v = *(const uint4*)((const char*)smC +
                        (row * 256 + (cb ^ ((row & 7) << 4))));
            *(uint4*)(base + (size_t)(bm + row) * 512 + (cb >> 1)) = v;
        }
    }
}

// ------------- fused GATv2 attention + head-mean + bias + LN + residual -------------
// ONE wave per node (4 heads x 16 lanes, 8 dims/lane), block = 4 waves = 4 nodes.
// No-max softmax; packed-f16 accumulation; 2-edge pairs with 2-deep pipeline.

__global__ __launch_bounds__(256) void k_attn(const u16* __restrict__ XL,
                                              const u16* __restrict__ XR,
                                              const float* __restrict__ att,
                                              const float* __restrict__ bias,
                                              const float* __restrict__ gamma,
                                              const float* __restrict__ beta,
                                              const int* __restrict__ row,
                                              const int* __restrict__ col,
                                              const float* __restrict__ res,
                                              float* __restrict__ out,
                                              u16* __restrict__ out_h,
                                              int relu_flag) {
    const int wid = __builtin_amdgcn_readfirstlane(threadIdx.x >> 6);
    const int n   = blockIdx.x * 4 + wid;          // grid = NNODES/4 exactly
    const int l   = threadIdx.x & 63;
    const int h   = l >> 4;                         // head 0..3
    const int e   = l & 15;                         // dim group: dims e*8..e*8+7

    const f16x2 C06 = {(_Float16)0.6f, (_Float16)0.6f};
    const f16x2 C04 = {(_Float16)0.4f, (_Float16)0.4f};

    const size_t lane_off = h * 128 + e * 8;

    uint4 xru = *(const uint4*)(XR + (size_t)n * 512 + lane_off);
    f16x2 xr0 = u2h2(xru.x), xr1 = u2h2(xru.y), xr2 = u2h2(xru.z), xr3 = u2h2(xru.w);

    const float* ap = att + lane_off;
    float4 af0 = *(const float4*)(ap);
    float4 af1 = *(const float4*)(ap + 4);
    f16x2 at0 = {(_Float16)af0.x, (_Float16)af0.y};
    f16x2 at1 = {(_Float16)af0.z, (_Float16)af0.w};
    f16x2 at2 = {(_Float16)af1.x, (_Float16)af1.y};
    f16x2 at3 = {(_Float16)af1.z, (_Float16)af1.w};

    f16x2 acch[4] = {};     // packed f16 accumulators (8 dims)
    float ssum = 0.f;

    const int beg = row[n], end = row[n + 1];

    int i = beg;
    int j = i + 2;
    {
        int c0 = col[i];
        int c1 = (i + 1 < end) ? col[i + 1] : c0;
        uint4 a0 = *(const uint4*)(XL + (size_t)c0 * 512 + lane_off);
        uint4 a1 = *(const uint4*)(XL + (size_t)c1 * 512 + lane_off);
        bool morej = j < end;
        int d0 = 0, d1 = 0;
        if (morej) { d0 = col[j]; d1 = (j + 1 < end) ? col[j + 1] : d0; }

        while (true) {
            uint4 b0, b1;
            if (morej) {
                b0 = *(const uint4*)(XL + (size_t)d0 * 512 + lane_off);
                b1 = *(const uint4*)(XL + (size_t)d1 * 512 + lane_off);
            }
            int k2 = j + 2;
            bool morek = morej && (k2 < end);
            int e0c = 0, e1c = 0;
            if (morek) { e0c = col[k2]; e1c = (k2 + 1 < end) ? col[k2 + 1] : e0c; }

            bool has2 = (i + 1 < end);
            float e0, e1;
            {
                f16x2 v0 = u2h2(a0.x) + xr0, v1 = u2h2(a0.y) + xr1;
                f16x2 v2 = u2h2(a0.z) + xr2, v3 = u2h2(a0.w) + xr3;
                f16x2 k0 = v0 * C06 + habs2(v0) * C04;
                f16x2 k1 = v1 * C06 + habs2(v1) * C04;
                f16x2 k2h = v2 * C06 + habs2(v2) * C04;
                f16x2 k3 = v3 * C06 + habs2(v3) * C04;
                e0 = __builtin_amdgcn_fdot2(k0, at0, 0.f, false);
                e0 = __builtin_amdgcn_fdot2(k1, at1, e0, false);
                e0 = __builtin_amdgcn_fdot2(k2h, at2, e0, false);
                e0 = __builtin_amdgcn_fdot2(k3, at3, e0, false);
            }
            {
                f16x2 v0 = u2h2(a1.x) + xr0, v1 = u2h2(a1.y) + xr1;
                f16x2 v2 = u2h2(a1.z) + xr2, v3 = u2h2(a1.w) + xr3;
                f16x2 k0 = v0 * C06 + habs2(v0) * C04;
                f16x2 k1 = v1 * C06 + habs2(v1) * C04;
                f16x2 k2h = v2 * C06 + habs2(v2) * C04;
                f16x2 k3 = v3 * C06 + habs2(v3) * C04;
                e1 = __builtin_amdgcn_fdot2(k0, at0, 0.f, false);
                e1 = __builtin_amdgcn_fdot2(k1, at1, e1, false);
                e1 = __builtin_amdgcn_fdot2(k2h, at2, e1, false);
                e1 = __builtin_amdgcn_fdot2(k3, at3, e1, false);
            }
#pragma unroll
            for (int m = 1; m < 16; m <<= 1) {
                e0 += __shfl_xor(e0, m, 64);
                e1 += __shfl_xor(e1, m, 64);
            }
            float p0 = __expf(e0);
            float p1 = has2 ? __expf(e1) : 0.f;
            ssum += p0 + p1;
            _Float16 ph0s = (_Float16)p0, ph1s = (_Float16)p1;
            f16x2 ph0 = {ph0s, ph0s};
            f16x2 ph1 = {ph1s, ph1s};
            acch[0] = acch[0] + ph0 * u2h2(a0.x) + ph1 * u2h2(a1.x);
            acch[1] = acch[1] + ph0 * u2h2(a0.y) + ph1 * u2h2(a1.y);
            acch[2] = acch[2] + ph0 * u2h2(a0.z) + ph1 * u2h2(a1.z);
            acch[3] = acch[3] + ph0 * u2h2(a0.w) + ph1 * u2h2(a1.w);

            if (!morej) break;
            a0 = b0; a1 = b1;
            i = j; j = k2;
            d0 = e0c; d1 = e1c;
            morej = morek;
        }
    }

    // unpack to f32, normalize per head, mean over heads via butterfly
    float acc[8];
    {
        f32x2 c;
        c = __builtin_convertvector(acch[0], f32x2); acc[0] = c[0]; acc[1] = c[1];
        c = __builtin_convertvector(acch[1], f32x2); acc[2] = c[0]; acc[3] = c[1];
        c = __builtin_convertvector(acch[2], f32x2); acc[4] = c[0]; acc[5] = c[1];
        c = __builtin_convertvector(acch[3], f32x2); acc[6] = c[0]; acc[7] = c[1];
    }
    float inv = 1.f / (ssum + 1e-16f);
#pragma unroll
    for (int jj = 0; jj < 8; ++jj) acc[jj] *= inv;
#pragma unroll
    for (int jj = 0; jj < 8; ++jj) acc[jj] += __shfl_xor(acc[jj], 16, 64);
#pragma unroll
    for (int jj = 0; jj < 8; ++jj) acc[jj] += __shfl_xor(acc[jj], 32, 64);

    if (h == 0) {
        const int dd = e * 8;
        float4 b40 = *(const float4*)(bias + dd);
        float4 b41 = *(const float4*)(bias + dd + 4);
        float y[8];
        y[0] = acc[0]*0.25f + b40.x; y[1] = acc[1]*0.25f + b40.y;
        y[2] = acc[2]*0.25f + b40.z; y[3] = acc[3]*0.25f + b40.w;
        y[4] = acc[4]*0.25f + b41.x; y[5] = acc[5]*0.25f + b41.y;
        y[6] = acc[6]*0.25f + b41.z; y[7] = acc[7]*0.25f + b41.w;

        float s1 = 0.f, s2 = 0.f;
#pragma unroll
        for (int jj = 0; jj < 8; ++jj) { s1 += y[jj]; s2 += y[jj]*y[jj]; }
#pragma unroll
        for (int m = 1; m < 16; m <<= 1) {
            s1 += __shfl_xor(s1, m, 64);
            s2 += __shfl_xor(s2, m, 64);
        }
        float mu = s1 * (1.f / 128.f);
        float var = s2 * (1.f / 128.f) - mu * mu;
        float rstd = rsqrtf(var + LN_EPS);

        float4 g40 = *(const float4*)(gamma + dd);
        float4 g41 = *(const float4*)(gamma + dd + 4);
        float4 e40 = *(const float4*)(beta + dd);
        float4 e41 = *(const float4*)(beta + dd + 4);
        float4 r40 = *(const float4*)(res + (size_t)n * 128 + dd);
        float4 r41 = *(const float4*)(res + (size_t)n * 128 + dd + 4);
        float g[8] = {g40.x,g40.y,g40.z,g40.w,g41.x,g41.y,g41.z,g41.w};
        float be[8] = {e40.x,e40.y,e40.z,e40.w,e41.x,e41.y,e41.z,e41.w};
        float r[8] = {r40.x,r40.y,r40.z,r40.w,r41.x,r41.y,r41.z,r41.w};
#pragma unroll
        for (int jj = 0; jj < 8; ++jj) {
            y[jj] = (y[jj] - mu) * rstd * g[jj] + be[jj] + r[jj];
            if (relu_flag) y[jj] = fmaxf(y[jj], 0.f);
        }
        float4 o0 = {y[0],y[1],y[2],y[3]};
        float4 o1 = {y[4],y[5],y[6],y[7]};
        *(float4*)(out + (size_t)n * 128 + dd)     = o0;
        *(float4*)(out + (size_t)n * 128 + dd + 4) = o1;
        if (out_h) {
            ushort4 oh0, oh1;
            oh0.x = f2h(y[0]); oh0.y = f2h(y[1]); oh0.z = f2h(y[2]); oh0.w = f2h(y[3]);
            oh1.x = f2h(y[4]); oh1.y = f2h(y[5]); oh1.z = f2h(y[6]); oh1.w = f2h(y[7]);
            *(ushort4*)(out_h + (size_t)n * 128 + dd)     = oh0;
            *(ushort4*)(out_h + (size_t)n * 128 + dd + 4) = oh1;
        }
    }
}

// ---------------- launch ----------------

extern "C" void kernel_launch(void* const* d_in, const int* in_sizes, int n_in,
                              void* d_out, int out_size, void* d_ws, size_t ws_size,
                              hipStream_t stream) {
    const float* x    = (const float*)d_in[0];
    const int*   src  = (const int*)d_in[1];
    const int*   dst  = (const int*)d_in[2];
    const float* Wl1  = (const float*)d_in[3];
    const float* Wr1  = (const float*)d_in[4];
    const float* att1 = (const float*)d_in[5];
    const float* b1   = (const float*)d_in[6];
    const float* g1   = (const float*)d_in[7];
    const float* be1  = (const float*)d_in[8];
    const float* Wl2  = (const float*)d_in[9];
    const float* Wr2  = (const float*)d_in[10];
    const float* att2 = (const float*)d_in[11];
    const float* b2   = (const float*)d_in[12];
    const float* g2   = (const float*)d_in[13];
    const float* be2  = (const float*)d_in[14];
    float* out = (float*)d_out;

    char* ws = (char*)d_ws;
    size_t off = 0;
    u16*   xlb  = (u16*)(ws + off);   off += (size_t)MPAD * 512 * 2;      // f16
    u16*   xrb  = (u16*)(ws + off);   off += (size_t)MPAD * 512 * 2;      // f16
    u16*   xb   = (u16*)(ws + off);   off += (size_t)MPAD * 128 * 2;      // f16 A input
    float* hbuf = (float*)(ws + off); off += (size_t)NNODES * 128 * 4;
    u16*   Bt1  = (u16*)(ws + off);   off += (size_t)1024 * 128 * 2;
    u16*   Bt2  = (u16*)(ws + off);   off += (size_t)1024 * 128 * 2;
    int*   deg  = (int*)(ws + off);   off += (size_t)NNODES * 4;
    int*   rowp = (int*)(ws + off);   off += (size_t)(NNODES + 1) * 4;
    int*   cur  = (int*)(ws + off);   off += (size_t)NNODES * 4;
    int*   col  = (int*)(ws + off);   off += (size_t)ETOT * 4;

    // fused prep (deg init + cvt_x + both cvt_w), then CSR build
    k_prep<<<1024, 256, 0, stream>>>(x, xb, Wl1, Wr1, Bt1, Wl2, Wr2, Bt2, deg);
    k_hist<<<(NEDGES + 255) / 256, 256, 0, stream>>>(dst, deg);
    k_scan<<<1, 1024, 0, stream>>>(deg, rowp, cur);
    k_scatter<<<(ETOT + 255) / 256, 256, 0, stream>>>(src, dst, col, cur);

    // layer 1
    k_gemm_f16<<<MPAD / 128 * 8, 256, 0, stream>>>(xb, Bt1, xlb, xrb);
    k_attn<<<NNODES / 4, 256, 0, stream>>>(xlb, xrb, att1, b1, g1, be1, rowp, col,
                                           x, hbuf, xb /*fp16 out for layer2*/, 1);
    // layer 2
    k_gemm_f16<<<MPAD / 128 * 8, 256, 0, stream>>>(xb, Bt2, xlb, xrb);
    k_attn<<<NNODES / 4, 256, 0, stream>>>(xlb, xrb, att2, b2, g2, be2, rowp, col,
                                           hbuf, out, (u16*)nullptr, 0);
}

// Round 12
// 202.760 us; speedup vs baseline: 1.3965x; 1.0521x over previous
//
#include <hip/hip_runtime.h>
#include <hip/hip_bf16.h>
#include <hip/hip_fp16.h>

#define NNODES 20000
#define MPAD   20480              // 160 * 128 row-tiles, no M-guards anywhere
#define NEDGES 320000
#define DIM    128
#define NH     4
#define ETOT   (NEDGES + NNODES)
#define LN_EPS 1e-5f

typedef unsigned char  u8;
typedef unsigned short u16;
typedef unsigned int   u32;

typedef _Float16 f16x2 __attribute__((ext_vector_type(2)));
typedef _Float16 f16x8 __attribute__((ext_vector_type(8)));
typedef float    f32x2 __attribute__((ext_vector_type(2)));
typedef float    f32x4 __attribute__((ext_vector_type(4)));

__device__ inline u16 f2h(float f) {
    _Float16 h = (_Float16)f;
    union { _Float16 h; u16 u; } v; v.h = h; return v.u;
}
__device__ inline f16x2 u2h2(u32 u) { union { u32 u; f16x2 h; } v; v.u = u; return v.h; }
__device__ inline u32 h22u(f16x2 h) { union { f16x2 h; u32 u; } v; v.h = h; return v.u; }
__device__ inline f16x2 habs2(f16x2 h) { return u2h2(h22u(h) & 0x7FFF7FFFu); }

// async global->LDS, 16B per lane, linear LDS dest (wave-uniform base + lane*16)
#define GLDS16(g, l) __builtin_amdgcn_global_load_lds(                         \
    (const __attribute__((address_space(1))) void*)(g),                        \
    (__attribute__((address_space(3))) void*)(l), 16, 0, 0)

// ---- fused prep: deg init + x->f16 + W->Bt via LDS transpose (coalesced both sides) ----
// grid MUST be 256 blocks x 256 threads.

__global__ __launch_bounds__(256) void k_prep(const float* __restrict__ x, u16* __restrict__ xb,
                       const float* __restrict__ Wl1, const float* __restrict__ Wr1,
                       u16* __restrict__ Bt1,
                       const float* __restrict__ Wl2, const float* __restrict__ Wr2,
                       u16* __restrict__ Bt2,
                       int* __restrict__ deg) {
    const int b = blockIdx.x, t = threadIdx.x;
    const int gid = b * 256 + t;
    if (gid < NNODES) deg[gid] = 1;   // self-loop

    // x -> fp16 (coalesced, grid-stride over 640k float4)
    for (int j = gid; j < NNODES * 32; j += 256 * 256) {
        float4 v = ((const float4*)x)[j];
        ushort4 o;
        o.x = f2h(v.x); o.y = f2h(v.y); o.z = f2h(v.z); o.w = f2h(v.w);
        ((ushort4*)xb)[j] = o;
    }

    // W transpose: 256 blocks = 4 matrices x 64 tiles (4 kt x 16 nt) of 32x32
    {
        const int m    = b >> 6;          // 0:Wl1 1:Wr1 2:Wl2 3:Wr2
        const int tile = b & 63;
        const int kt   = tile >> 4;       // 0..3
        const int nt   = tile & 15;       // 0..15
        const float* W = (m == 0) ? Wl1 : (m == 1) ? Wr1 : (m == 2) ? Wl2 : Wr2;
        u16* Bt        = (m < 2) ? Bt1 : Bt2;
        const int nbase = (m & 1) * 512 + nt * 32;

        __shared__ float lds[32][33];
        const int tx = t & 31, ty = t >> 5;   // 32 x 8
#pragma unroll
        for (int i = 0; i < 4; ++i) {
            int k = kt * 32 + ty + i * 8;
            lds[ty + i * 8][tx] = W[k * 512 + nt * 32 + tx];
        }
        __syncthreads();
#pragma unroll
        for (int i = 0; i < 4; ++i) {
            int nrow = nbase + ty + i * 8;
            Bt[nrow * 128 + kt * 32 + tx] = f2h(lds[tx][ty + i * 8]);
        }
    }
}

// ---------------- CSR build ----------------

__global__ void k_hist(const int* __restrict__ dst, int* __restrict__ deg) {
    int i = blockIdx.x * blockDim.x + threadIdx.x;
    if (i < NEDGES) atomicAdd(&deg[dst[i]], 1);
}

__global__ __launch_bounds__(1024) void k_scan(const int* __restrict__ deg,
                                               int* __restrict__ row,
                                               int* __restrict__ cur) {
    __shared__ int part[1024];
    const int CH = 20;                    // 20000 = 1000 * 20 exactly
    int t = threadIdx.x;
    int base = t * CH;
    int s = 0;
    int d[20];
    if (base < NNODES) {                  // threads 0..999 fully in range
#pragma unroll
        for (int q = 0; q < 5; ++q) {
            int4 v = ((const int4*)(deg + base))[q];
            d[q*4+0] = v.x; d[q*4+1] = v.y; d[q*4+2] = v.z; d[q*4+3] = v.w;
            s += v.x + v.y + v.z + v.w;
        }
    }
    part[t] = s;
    __syncthreads();
    for (int off = 1; off < 1024; off <<= 1) {
        int v = (t >= off) ? part[t - off] : 0;
        __syncthreads();
        part[t] += v;
        __syncthreads();
    }
    if (base < NNODES) {
        int run = (t == 0) ? 0 : part[t - 1];
#pragma unroll
        for (int i = 0; i < CH; i++) {
            row[base + i] = run; cur[base + i] = run; run += d[i];
        }
    }
    if (t == 1023) row[NNODES] = part[1023];
}

__global__ void k_scatter(const int* __restrict__ src, const int* __restrict__ dst,
                          int* __restrict__ col, int* __restrict__ cur) {
    int i = blockIdx.x * blockDim.x + threadIdx.x;
    if (i < NEDGES) {
        int d = dst[i];
        int pos = atomicAdd(&cur[d], 1);
        col[pos] = src[i];
    } else if (i < ETOT) {
        int n = i - NEDGES;
        int pos = atomicAdd(&cur[n], 1);
        col[pos] = n;
    }
}

// ------------- fp16 MFMA GEMM: [XL|XR][M,512 each] = A[M,128] @ Bt^T -------------
// m97 pattern + XCD-locality (bn fastest). global_load_lds w=16 pre-swizzled source;
// one barrier; C staged through LDS for coalesced 256B-row writes. (R11 version.)

__global__ __launch_bounds__(256, 2) void k_gemm_f16(const u16* __restrict__ A,
                                                     const u16* __restrict__ Bt,
                                                     u16* __restrict__ XL,
                                                     u16* __restrict__ XR) {
    __shared__ u16 smA[128 * 128];   // 32 KB
    __shared__ u16 smB[128 * 128];   // 32 KB
    const int L   = blockIdx.x;         // 0..1279
    const int xcd = L & 7;
    const int w9  = L >> 3;             // 0..159
    const int bm  = (xcd * 20 + (w9 >> 3)) * 128;
    const int bn  = (w9 & 7) * 128;
    const int t  = threadIdx.x;
    const int w  = t >> 6;
    const int l  = t & 63;

    {
        char* smAb = (char*)smA;
        char* smBb = (char*)smB;
#pragma unroll
        for (int p = 0; p < 8; ++p) {
            int rbase = w * 32 + p * 4;
            int row   = rbase + (l >> 4);
            int j     = (l & 15) ^ (row & 7);
            const u16* ga = A  + (size_t)(bm + row) * 128 + j * 8;
            const u16* gb = Bt + (size_t)(bn + row) * 128 + j * 8;
            GLDS16(ga, smAb + rbase * 256);
            GLDS16(gb, smBb + rbase * 256);
        }
    }
    __syncthreads();

    const int wr  = (w >> 1) * 64;
    const int wc  = (w & 1) * 64;
    const int lr  = l & 15;
    const int lkb = (l >> 4) * 16;

    f32x4 acc[4][4] = {};

#pragma unroll
    for (int ks = 0; ks < 4; ++ks) {
        f16x8 af[4], bfr[4];
#pragma unroll
        for (int i = 0; i < 4; ++i) {
            int ra = wr + i * 16 + lr;
            af[i]  = *(const f16x8*)((const char*)smA +
                        ((ra * 256 + ks * 64 + lkb) ^ ((ra & 7) << 4)));
            int rb = wc + i * 16 + lr;
            bfr[i] = *(const f16x8*)((const char*)smB +
                        ((rb * 256 + ks * 64 + lkb) ^ ((rb & 7) << 4)));
        }
#pragma unroll
        for (int mi = 0; mi < 4; ++mi)
#pragma unroll
            for (int ni = 0; ni < 4; ++ni)
                acc[mi][ni] = __builtin_amdgcn_mfma_f32_16x16x32_f16(
                    bfr[ni], af[mi], acc[mi][ni], 0, 0, 0);
    }

    __syncthreads();
    u16* smC = smA;
    {
        const int n4 = (l >> 4) * 4;
#pragma unroll
        for (int mi = 0; mi < 4; ++mi) {
            int m = wr + mi * 16 + lr;
#pragma unroll
            for (int ni = 0; ni < 4; ++ni) {
                int n = wc + ni * 16 + n4;
                f32x4 v = acc[mi][ni];
                ushort4 o;
                o.x = f2h(v[0]); o.y = f2h(v[1]); o.z = f2h(v[2]); o.w = f2h(v[3]);
                *(ushort4*)((char*)smC + (m * 256 + ((n * 2) ^ ((m & 7) << 4)))) = o;
            }
        }
    }
    __syncthreads();
    {
        int r  = t >> 4;
        int cb = (t & 15) * 16;
        const bool left = (bn < 512);
        u16* base = left ? (XL + bn) : (XR + (bn - 512));
#pragma unroll
        for (int p = 0; p < 8; ++p) {
            int row = p * 16 + r;
            uint4 v = *(const uint4*)((const char*)smC +
                        (row * 256 + (cb ^ ((row & 7) << 4))));
            *(uint4*)(base + (size_t)(bm + row) * 512 + (cb >> 1)) = v;
        }
    }
}

// ------------- fused GATv2 attention + head-mean + bias + LN + residual -------------
// ONE wave per node; block = 4 waves = 4 nodes; grid covers [n0, n0+NNODES/2).
// (Split into 2 dispatches per layer for profiler observability.)

__global__ __launch_bounds__(256) void k_attn(const u16* __restrict__ XL,
                                              const u16* __restrict__ XR,
                                              const float* __restrict__ att,
                                              const float* __restrict__ bias,
                                              const float* __restrict__ gamma,
                                              const float* __restrict__ beta,
                                              const int* __restrict__ row,
                                              const int* __restrict__ col,
                                              const float* __restrict__ res,
                                              float* __restrict__ out,
                                              u16* __restrict__ out_h,
                                              int relu_flag, int n0) {
    const int wid = __builtin_amdgcn_readfirstlane(threadIdx.x >> 6);
    const int n   = n0 + blockIdx.x * 4 + wid;
    const int l   = threadIdx.x & 63;
    const int h   = l >> 4;
    const int e   = l & 15;

    const f16x2 C06 = {(_Float16)0.6f, (_Float16)0.6f};
    const f16x2 C04 = {(_Float16)0.4f, (_Float16)0.4f};

    const size_t lane_off = h * 128 + e * 8;

    uint4 xru = *(const uint4*)(XR + (size_t)n * 512 + lane_off);
    f16x2 xr0 = u2h2(xru.x), xr1 = u2h2(xru.y), xr2 = u2h2(xru.z), xr3 = u2h2(xru.w);

    const float* ap = att + lane_off;
    float4 af0 = *(const float4*)(ap);
    float4 af1 = *(const float4*)(ap + 4);
    f16x2 at0 = {(_Float16)af0.x, (_Float16)af0.y};
    f16x2 at1 = {(_Float16)af0.z, (_Float16)af0.w};
    f16x2 at2 = {(_Float16)af1.x, (_Float16)af1.y};
    f16x2 at3 = {(_Float16)af1.z, (_Float16)af1.w};

    f16x2 acch[4] = {};
    float ssum = 0.f;

    const int beg = row[n], end = row[n + 1];

    int i = beg;
    int j = i + 2;
    {
        int c0 = col[i];
        int c1 = (i + 1 < end) ? col[i + 1] : c0;
        uint4 a0 = *(const uint4*)(XL + (size_t)c0 * 512 + lane_off);
        uint4 a1 = *(const uint4*)(XL + (size_t)c1 * 512 + lane_off);
        bool morej = j < end;
        int d0 = 0, d1 = 0;
        if (morej) { d0 = col[j]; d1 = (j + 1 < end) ? col[j + 1] : d0; }

        while (true) {
            uint4 b0, b1;
            if (morej) {
                b0 = *(const uint4*)(XL + (size_t)d0 * 512 + lane_off);
                b1 = *(const uint4*)(XL + (size_t)d1 * 512 + lane_off);
            }
            int k2 = j + 2;
            bool morek = morej && (k2 < end);
            int e0c = 0, e1c = 0;
            if (morek) { e0c = col[k2]; e1c = (k2 + 1 < end) ? col[k2 + 1] : e0c; }

            bool has2 = (i + 1 < end);
            float e0, e1;
            {
                f16x2 v0 = u2h2(a0.x) + xr0, v1 = u2h2(a0.y) + xr1;
                f16x2 v2 = u2h2(a0.z) + xr2, v3 = u2h2(a0.w) + xr3;
                f16x2 k0 = v0 * C06 + habs2(v0) * C04;
                f16x2 k1 = v1 * C06 + habs2(v1) * C04;
                f16x2 k2h = v2 * C06 + habs2(v2) * C04;
                f16x2 k3 = v3 * C06 + habs2(v3) * C04;
                e0 = __builtin_amdgcn_fdot2(k0, at0, 0.f, false);
                e0 = __builtin_amdgcn_fdot2(k1, at1, e0, false);
                e0 = __builtin_amdgcn_fdot2(k2h, at2, e0, false);
                e0 = __builtin_amdgcn_fdot2(k3, at3, e0, false);
            }
            {
                f16x2 v0 = u2h2(a1.x) + xr0, v1 = u2h2(a1.y) + xr1;
                f16x2 v2 = u2h2(a1.z) + xr2, v3 = u2h2(a1.w) + xr3;
                f16x2 k0 = v0 * C06 + habs2(v0) * C04;
                f16x2 k1 = v1 * C06 + habs2(v1) * C04;
                f16x2 k2h = v2 * C06 + habs2(v2) * C04;
                f16x2 k3 = v3 * C06 + habs2(v3) * C04;
                e1 = __builtin_amdgcn_fdot2(k0, at0, 0.f, false);
                e1 = __builtin_amdgcn_fdot2(k1, at1, e1, false);
                e1 = __builtin_amdgcn_fdot2(k2h, at2, e1, false);
                e1 = __builtin_amdgcn_fdot2(k3, at3, e1, false);
            }
#pragma unroll
            for (int m = 1; m < 16; m <<= 1) {
                e0 += __shfl_xor(e0, m, 64);
                e1 += __shfl_xor(e1, m, 64);
            }
            float p0 = __expf(e0);
            float p1 = has2 ? __expf(e1) : 0.f;
            ssum += p0 + p1;
            _Float16 ph0s = (_Float16)p0, ph1s = (_Float16)p1;
            f16x2 ph0 = {ph0s, ph0s};
            f16x2 ph1 = {ph1s, ph1s};
            acch[0] = acch[0] + ph0 * u2h2(a0.x) + ph1 * u2h2(a1.x);
            acch[1] = acch[1] + ph0 * u2h2(a0.y) + ph1 * u2h2(a1.y);
            acch[2] = acch[2] + ph0 * u2h2(a0.z) + ph1 * u2h2(a1.z);
            acch[3] = acch[3] + ph0 * u2h2(a0.w) + ph1 * u2h2(a1.w);

            if (!morej) break;
            a0 = b0; a1 = b1;
            i = j; j = k2;
            d0 = e0c; d1 = e1c;
            morej = morek;
        }
    }

    float acc[8];
    {
        f32x2 c;
        c = __builtin_convertvector(acch[0], f32x2); acc[0] = c[0]; acc[1] = c[1];
        c = __builtin_convertvector(acch[1], f32x2); acc[2] = c[0]; acc[3] = c[1];
        c = __builtin_convertvector(acch[2], f32x2); acc[4] = c[0]; acc[5] = c[1];
        c = __builtin_convertvector(acch[3], f32x2); acc[6] = c[0]; acc[7] = c[1];
    }
    float inv = 1.f / (ssum + 1e-16f);
#pragma unroll
    for (int jj = 0; jj < 8; ++jj) acc[jj] *= inv;
#pragma unroll
    for (int jj = 0; jj < 8; ++jj) acc[jj] += __shfl_xor(acc[jj], 16, 64);
#pragma unroll
    for (int jj = 0; jj < 8; ++jj) acc[jj] += __shfl_xor(acc[jj], 32, 64);

    if (h == 0) {
        const int dd = e * 8;
        float4 b40 = *(const float4*)(bias + dd);
        float4 b41 = *(const float4*)(bias + dd + 4);
        float y[8];
        y[0] = acc[0]*0.25f + b40.x; y[1] = acc[1]*0.25f + b40.y;
        y[2] = acc[2]*0.25f + b40.z; y[3] = acc[3]*0.25f + b40.w;
        y[4] = acc[4]*0.25f + b41.x; y[5] = acc[5]*0.25f + b41.y;
        y[6] = acc[6]*0.25f + b41.z; y[7] = acc[7]*0.25f + b41.w;

        float s1 = 0.f, s2 = 0.f;
#pragma unroll
        for (int jj = 0; jj < 8; ++jj) { s1 += y[jj]; s2 += y[jj]*y[jj]; }
#pragma unroll
        for (int m = 1; m < 16; m <<= 1) {
            s1 += __shfl_xor(s1, m, 64);
            s2 += __shfl_xor(s2, m, 64);
        }
        float mu = s1 * (1.f / 128.f);
        float var = s2 * (1.f / 128.f) - mu * mu;
        float rstd = rsqrtf(var + LN_EPS);

        float4 g40 = *(const float4*)(gamma + dd);
        float4 g41 = *(const float4*)(gamma + dd + 4);
        float4 e40 = *(const float4*)(beta + dd);
        float4 e41 = *(const float4*)(beta + dd + 4);
        float4 r40 = *(const float4*)(res + (size_t)n * 128 + dd);
        float4 r41 = *(const float4*)(res + (size_t)n * 128 + dd + 4);
        float g[8] = {g40.x,g40.y,g40.z,g40.w,g41.x,g41.y,g41.z,g41.w};
        float be[8] = {e40.x,e40.y,e40.z,e40.w,e41.x,e41.y,e41.z,e41.w};
        float r[8] = {r40.x,r40.y,r40.z,r40.w,r41.x,r41.y,r41.z,r41.w};
#pragma unroll
        for (int jj = 0; jj < 8; ++jj) {
            y[jj] = (y[jj] - mu) * rstd * g[jj] + be[jj] + r[jj];
            if (relu_flag) y[jj] = fmaxf(y[jj], 0.f);
        }
        float4 o0 = {y[0],y[1],y[2],y[3]};
        float4 o1 = {y[4],y[5],y[6],y[7]};
        *(float4*)(out + (size_t)n * 128 + dd)     = o0;
        *(float4*)(out + (size_t)n * 128 + dd + 4) = o1;
        if (out_h) {
            ushort4 oh0, oh1;
            oh0.x = f2h(y[0]); oh0.y = f2h(y[1]); oh0.z = f2h(y[2]); oh0.w = f2h(y[3]);
            oh1.x = f2h(y[4]); oh1.y = f2h(y[5]); oh1.z = f2h(y[6]); oh1.w = f2h(y[7]);
            *(ushort4*)(out_h + (size_t)n * 128 + dd)     = oh0;
            *(ushort4*)(out_h + (size_t)n * 128 + dd + 4) = oh1;
        }
    }
}

// ---------------- launch ----------------

extern "C" void kernel_launch(void* const* d_in, const int* in_sizes, int n_in,
                              void* d_out, int out_size, void* d_ws, size_t ws_size,
                              hipStream_t stream) {
    const float* x    = (const float*)d_in[0];
    const int*   src  = (const int*)d_in[1];
    const int*   dst  = (const int*)d_in[2];
    const float* Wl1  = (const float*)d_in[3];
    const float* Wr1  = (const float*)d_in[4];
    const float* att1 = (const float*)d_in[5];
    const float* b1   = (const float*)d_in[6];
    const float* g1   = (const float*)d_in[7];
    const float* be1  = (const float*)d_in[8];
    const float* Wl2  = (const float*)d_in[9];
    const float* Wr2  = (const float*)d_in[10];
    const float* att2 = (const float*)d_in[11];
    const float* b2   = (const float*)d_in[12];
    const float* g2   = (const float*)d_in[13];
    const float* be2  = (const float*)d_in[14];
    float* out = (float*)d_out;

    char* ws = (char*)d_ws;
    size_t off = 0;
    u16*   xlb  = (u16*)(ws + off);   off += (size_t)MPAD * 512 * 2;
    u16*   xrb  = (u16*)(ws + off);   off += (size_t)MPAD * 512 * 2;
    u16*   xb   = (u16*)(ws + off);   off += (size_t)MPAD * 128 * 2;
    float* hbuf = (float*)(ws + off); off += (size_t)NNODES * 128 * 4;
    u16*   Bt1  = (u16*)(ws + off);   off += (size_t)1024 * 128 * 2;
    u16*   Bt2  = (u16*)(ws + off);   off += (size_t)1024 * 128 * 2;
    int*   deg  = (int*)(ws + off);   off += (size_t)NNODES * 4;
    int*   rowp = (int*)(ws + off);   off += (size_t)(NNODES + 1) * 4;
    int*   cur  = (int*)(ws + off);   off += (size_t)NNODES * 4;
    int*   col  = (int*)(ws + off);   off += (size_t)ETOT * 4;

    k_prep<<<256, 256, 0, stream>>>(x, xb, Wl1, Wr1, Bt1, Wl2, Wr2, Bt2, deg);
    k_hist<<<(NEDGES + 255) / 256, 256, 0, stream>>>(dst, deg);
    k_scan<<<1, 1024, 0, stream>>>(deg, rowp, cur);
    k_scatter<<<(ETOT + 255) / 256, 256, 0, stream>>>(src, dst, col, cur);

    const int HALF = NNODES / 2;   // 10000

    // layer 1
    k_gemm_f16<<<MPAD / 128 * 8, 256, 0, stream>>>(xb, Bt1, xlb, xrb);
    k_attn<<<HALF / 4, 256, 0, stream>>>(xlb, xrb, att1, b1, g1, be1, rowp, col,
                                         x, hbuf, xb, 1, 0);
    k_attn<<<HALF / 4, 256, 0, stream>>>(xlb, xrb, att1, b1, g1, be1, rowp, col,
                                         x, hbuf, xb, 1, HALF);
    // layer 2
    k_gemm_f16<<<MPAD / 128 * 8, 256, 0, stream>>>(xb, Bt2, xlb, xrb);
    k_attn<<<HALF / 4, 256, 0, stream>>>(xlb, xrb, att2, b2, g2, be2, rowp, col,
                                         hbuf, out, (u16*)nullptr, 0, 0);
    k_attn<<<HALF / 4, 256, 0, stream>>>(xlb, xrb, att2, b2, g2, be2, rowp, col,
                                         hbuf, out, (u16*)nullptr, 0, HALF);
}

// Round 13
// 190.756 us; speedup vs baseline: 1.4844x; 1.0629x over previous
//
#include <hip/hip_runtime.h>
#include <hip/hip_bf16.h>
#include <hip/hip_fp16.h>

#define NNODES 20000
#define MPAD   20480              // 160 * 128 row-tiles, no M-guards anywhere
#define NEDGES 320000
#define DIM    128
#define NH     4
#define ETOT   (NEDGES + NNODES)
#define LN_EPS 1e-5f

typedef unsigned char  u8;
typedef unsigned short u16;
typedef unsigned int   u32;

typedef _Float16    f16x2 __attribute__((ext_vector_type(2)));
typedef _Float16    f16x8 __attribute__((ext_vector_type(8)));
typedef float       f32x2 __attribute__((ext_vector_type(2)));
typedef float       f32x4 __attribute__((ext_vector_type(4)));
typedef signed char i8x8  __attribute__((ext_vector_type(8)));

__device__ inline u16 f2h(float f) {
    _Float16 h = (_Float16)f;
    union { _Float16 h; u16 u; } v; v.h = h; return v.u;
}
__device__ inline _Float16 bits2h(u16 b) {
    union { u16 u; _Float16 h; } v; v.u = b; return v.h;
}
__device__ inline f16x2 u2h2(u32 u) { union { u32 u; f16x2 h; } v; v.u = u; return v.h; }
__device__ inline u32 h22u(f16x2 h) { union { f16x2 h; u32 u; } v; v.h = h; return v.u; }
__device__ inline f16x2 habs2(f16x2 h) { return u2h2(h22u(h) & 0x7FFF7FFFu); }

// async global->LDS, 16B per lane, linear LDS dest (wave-uniform base + lane*16)
#define GLDS16(g, l) __builtin_amdgcn_global_load_lds(                         \
    (const __attribute__((address_space(1))) void*)(g),                        \
    (__attribute__((address_space(3))) void*)(l), 16, 0, 0)

// ---- fused prep: deg init + x->f16 + W->Bt via LDS transpose (coalesced both sides) ----
// grid MUST be 256 blocks x 256 threads.

__global__ __launch_bounds__(256) void k_prep(const float* __restrict__ x, u16* __restrict__ xb,
                       const float* __restrict__ Wl1, const float* __restrict__ Wr1,
                       u16* __restrict__ Bt1,
                       const float* __restrict__ Wl2, const float* __restrict__ Wr2,
                       u16* __restrict__ Bt2,
                       int* __restrict__ deg) {
    const int b = blockIdx.x, t = threadIdx.x;
    const int gid = b * 256 + t;
    if (gid < NNODES) deg[gid] = 1;   // self-loop

    for (int j = gid; j < NNODES * 32; j += 256 * 256) {
        float4 v = ((const float4*)x)[j];
        ushort4 o;
        o.x = f2h(v.x); o.y = f2h(v.y); o.z = f2h(v.z); o.w = f2h(v.w);
        ((ushort4*)xb)[j] = o;
    }

    // W transpose: 256 blocks = 4 matrices x 64 tiles (4 kt x 16 nt) of 32x32
    {
        const int m    = b >> 6;
        const int tile = b & 63;
        const int kt   = tile >> 4;
        const int nt   = tile & 15;
        const float* W = (m == 0) ? Wl1 : (m == 1) ? Wr1 : (m == 2) ? Wl2 : Wr2;
        u16* Bt        = (m < 2) ? Bt1 : Bt2;
        const int nbase = (m & 1) * 512 + nt * 32;

        __shared__ float lds[32][33];
        const int tx = t & 31, ty = t >> 5;
#pragma unroll
        for (int i = 0; i < 4; ++i) {
            int k = kt * 32 + ty + i * 8;
            lds[ty + i * 8][tx] = W[k * 512 + nt * 32 + tx];
        }
        __syncthreads();
#pragma unroll
        for (int i = 0; i < 4; ++i) {
            int nrow = nbase + ty + i * 8;
            Bt[nrow * 128 + kt * 32 + tx] = f2h(lds[tx][ty + i * 8]);
        }
    }
}

// ---------------- CSR build ----------------

__global__ void k_hist(const int* __restrict__ dst, int* __restrict__ deg) {
    int i = blockIdx.x * blockDim.x + threadIdx.x;
    if (i < NEDGES) atomicAdd(&deg[dst[i]], 1);
}

__global__ __launch_bounds__(1024) void k_scan(const int* __restrict__ deg,
                                               int* __restrict__ row,
                                               int* __restrict__ cur) {
    __shared__ int part[1024];
    const int CH = 20;
    int t = threadIdx.x;
    int base = t * CH;
    int s = 0;
    int d[20];
    if (base < NNODES) {
#pragma unroll
        for (int q = 0; q < 5; ++q) {
            int4 v = ((const int4*)(deg + base))[q];
            d[q*4+0] = v.x; d[q*4+1] = v.y; d[q*4+2] = v.z; d[q*4+3] = v.w;
            s += v.x + v.y + v.z + v.w;
        }
    }
    part[t] = s;
    __syncthreads();
    for (int off = 1; off < 1024; off <<= 1) {
        int v = (t >= off) ? part[t - off] : 0;
        __syncthreads();
        part[t] += v;
        __syncthreads();
    }
    if (base < NNODES) {
        int run = (t == 0) ? 0 : part[t - 1];
#pragma unroll
        for (int i = 0; i < CH; i++) {
            row[base + i] = run; cur[base + i] = run; run += d[i];
        }
    }
    if (t == 1023) row[NNODES] = part[1023];
}

__global__ void k_scatter(const int* __restrict__ src, const int* __restrict__ dst,
                          int* __restrict__ col, int* __restrict__ cur) {
    int i = blockIdx.x * blockDim.x + threadIdx.x;
    if (i < NEDGES) {
        int d = dst[i];
        int pos = atomicAdd(&cur[d], 1);
        col[pos] = src[i];
    } else if (i < ETOT) {
        int n = i - NEDGES;
        int pos = atomicAdd(&cur[n], 1);
        col[pos] = n;
    }
}

// ------------- fp16 MFMA GEMM (R11 structure, unchanged) -------------

__global__ __launch_bounds__(256, 2) void k_gemm_f16(const u16* __restrict__ A,
                                                     const u16* __restrict__ Bt,
                                                     u16* __restrict__ XL,
                                                     u16* __restrict__ XR) {
    __shared__ u16 smA[128 * 128];
    __shared__ u16 smB[128 * 128];
    const int L   = blockIdx.x;
    const int xcd = L & 7;
    const int w9  = L >> 3;
    const int bm  = (xcd * 20 + (w9 >> 3)) * 128;
    const int bn  = (w9 & 7) * 128;
    const int t  = threadIdx.x;
    const int w  = t >> 6;
    const int l  = t & 63;

    {
        char* smAb = (char*)smA;
        char* smBb = (char*)smB;
#pragma unroll
        for (int p = 0; p < 8; ++p) {
            int rbase = w * 32 + p * 4;
            int row   = rbase + (l >> 4);
            int j     = (l & 15) ^ (row & 7);
            const u16* ga = A  + (size_t)(bm + row) * 128 + j * 8;
            const u16* gb = Bt + (size_t)(bn + row) * 128 + j * 8;
            GLDS16(ga, smAb + rbase * 256);
            GLDS16(gb, smBb + rbase * 256);
        }
    }
    __syncthreads();

    const int wr  = (w >> 1) * 64;
    const int wc  = (w & 1) * 64;
    const int lr  = l & 15;
    const int lkb = (l >> 4) * 16;

    f32x4 acc[4][4] = {};

#pragma unroll
    for (int ks = 0; ks < 4; ++ks) {
        f16x8 af[4], bfr[4];
#pragma unroll
        for (int i = 0; i < 4; ++i) {
            int ra = wr + i * 16 + lr;
            af[i]  = *(const f16x8*)((const char*)smA +
                        ((ra * 256 + ks * 64 + lkb) ^ ((ra & 7) << 4)));
            int rb = wc + i * 16 + lr;
            bfr[i] = *(const f16x8*)((const char*)smB +
                        ((rb * 256 + ks * 64 + lkb) ^ ((rb & 7) << 4)));
        }
#pragma unroll
        for (int mi = 0; mi < 4; ++mi)
#pragma unroll
            for (int ni = 0; ni < 4; ++ni)
                acc[mi][ni] = __builtin_amdgcn_mfma_f32_16x16x32_f16(
                    bfr[ni], af[mi], acc[mi][ni], 0, 0, 0);
    }

    __syncthreads();
    u16* smC = smA;
    {
        const int n4 = (l >> 4) * 4;
#pragma unroll
        for (int mi = 0; mi < 4; ++mi) {
            int m = wr + mi * 16 + lr;
#pragma unroll
            for (int ni = 0; ni < 4; ++ni) {
                int n = wc + ni * 16 + n4;
                f32x4 v = acc[mi][ni];
                ushort4 o;
                o.x = f2h(v[0]); o.y = f2h(v[1]); o.z = f2h(v[2]); o.w = f2h(v[3]);
                *(ushort4*)((char*)smC + (m * 256 + ((n * 2) ^ ((m & 7) << 4)))) = o;
            }
        }
    }
    __syncthreads();
    {
        int r  = t >> 4;
        int cb = (t & 15) * 16;
        const bool left = (bn < 512);
        u16* base = left ? (XL + bn) : (XR + (bn - 512));
#pragma unroll
        for (int p = 0; p < 8; ++p) {
            int row = p * 16 + r;
            uint4 v = *(const uint4*)((const char*)smC +
                        (row * 256 + (cb ^ ((row & 7) << 4))));
            *(uint4*)(base + (size_t)(bm + row) * 512 + (cb >> 1)) = v;
        }
    }
}

// ------------- quantize XL f16 -> int8 with per-node-per-head scale -------------
// one wave per row, 4 waves/block, grid = NNODES/4.

__global__ __launch_bounds__(256) void k_quant(const u16* __restrict__ XL,
                                               u8* __restrict__ XLq,
                                               u16* __restrict__ scales) {
    const int wid = threadIdx.x >> 6;
    const int n   = blockIdx.x * 4 + wid;
    const int l   = threadIdx.x & 63;
    const int h   = l >> 4, e = l & 15;

    uint4 v = *(const uint4*)(XL + (size_t)n * 512 + h * 128 + e * 8);
    float vf[8];
    {
        f32x2 c;
        c = __builtin_convertvector(u2h2(v.x), f32x2); vf[0] = c[0]; vf[1] = c[1];
        c = __builtin_convertvector(u2h2(v.y), f32x2); vf[2] = c[0]; vf[3] = c[1];
        c = __builtin_convertvector(u2h2(v.z), f32x2); vf[4] = c[0]; vf[5] = c[1];
        c = __builtin_convertvector(u2h2(v.w), f32x2); vf[6] = c[0]; vf[7] = c[1];
    }
    float m = 0.f;
#pragma unroll
    for (int k = 0; k < 8; ++k) m = fmaxf(m, fabsf(vf[k]));
#pragma unroll
    for (int off = 1; off < 16; off <<= 1) m = fmaxf(m, __shfl_xor(m, off, 64));

    float scale = m * (1.f / 127.f);
    float inv   = (m > 0.f) ? (127.f / m) : 0.f;

    int q[8];
#pragma unroll
    for (int k = 0; k < 8; ++k) {
        int qi = (int)__builtin_rintf(vf[k] * inv);
        qi = qi > 127 ? 127 : (qi < -127 ? -127 : qi);
        q[k] = qi;
    }
    u32 lo = (q[0] & 255) | ((q[1] & 255) << 8) | ((q[2] & 255) << 16) | ((q[3] & 255) << 24);
    u32 hi = (q[4] & 255) | ((q[5] & 255) << 8) | ((q[6] & 255) << 16) | ((q[7] & 255) << 24);
    uint2 o; o.x = lo; o.y = hi;
    *(uint2*)(XLq + (size_t)n * 512 + h * 128 + e * 8) = o;
    if (e == 0) scales[n * 4 + h] = f2h(scale);
}

// ------------- fused GATv2 attention + head-mean + bias + LN + residual -------------
// ONE wave per node; int8 XLq gather (8 B/lane/edge) + per-node-per-head f16 scale
// (160 KB, L2-resident). No-max softmax; exact factoring acc += (p*s)*q.

__global__ __launch_bounds__(256) void k_attn(const u8*  __restrict__ XLq,
                                              const u16* __restrict__ scales,
                                              const u16* __restrict__ XR,
                                              const float* __restrict__ att,
                                              const float* __restrict__ bias,
                                              const float* __restrict__ gamma,
                                              const float* __restrict__ beta,
                                              const int* __restrict__ row,
                                              const int* __restrict__ col,
                                              const float* __restrict__ res,
                                              float* __restrict__ out,
                                              u16* __restrict__ out_h,
                                              int relu_flag) {
    const int wid = __builtin_amdgcn_readfirstlane(threadIdx.x >> 6);
    const int n   = blockIdx.x * 4 + wid;          // grid = NNODES/4 exactly
    const int l   = threadIdx.x & 63;
    const int h   = l >> 4;
    const int e   = l & 15;

    const f16x2 C06 = {(_Float16)0.6f, (_Float16)0.6f};
    const f16x2 C04 = {(_Float16)0.4f, (_Float16)0.4f};

    const int lane_off = h * 128 + e * 8;           // bytes into 512B int8 row / halves into f16 row

    uint4 xru = *(const uint4*)(XR + (size_t)n * 512 + lane_off);
    f16x2 xr0 = u2h2(xru.x), xr1 = u2h2(xru.y), xr2 = u2h2(xru.z), xr3 = u2h2(xru.w);

    const float* ap = att + lane_off;
    float4 af0 = *(const float4*)(ap);
    float4 af1 = *(const float4*)(ap + 4);
    f16x2 at0 = {(_Float16)af0.x, (_Float16)af0.y};
    f16x2 at1 = {(_Float16)af0.z, (_Float16)af0.w};
    f16x2 at2 = {(_Float16)af1.x, (_Float16)af1.y};
    f16x2 at3 = {(_Float16)af1.z, (_Float16)af1.w};

    f16x2 acch[4] = {};
    float ssum = 0.f;

    const int beg = row[n], end = row[n + 1];

    for (int i = beg; i < end; i += 2) {
        int s0 = col[i];
        bool has2 = (i + 1 < end);
        int s1 = has2 ? col[i + 1] : s0;

        uint2 a0 = *(const uint2*)(XLq + (size_t)s0 * 512 + lane_off);
        uint2 a1 = *(const uint2*)(XLq + (size_t)s1 * 512 + lane_off);
        _Float16 sh0 = bits2h(scales[s0 * 4 + h]);
        _Float16 sh1 = bits2h(scales[s1 * 4 + h]);
        f16x2 s0h2 = {sh0, sh0};
        f16x2 s1h2 = {sh1, sh1};

        // decode int8 -> f16 (exact)
        f16x8 q0, q1;
        {
            union { uint2 u; i8x8 c; } uc;
            uc.u = a0; q0 = __builtin_convertvector(uc.c, f16x8);
            uc.u = a1; q1 = __builtin_convertvector(uc.c, f16x8);
        }
        f16x2 q00 = __builtin_shufflevector(q0, q0, 0, 1);
        f16x2 q01 = __builtin_shufflevector(q0, q0, 2, 3);
        f16x2 q02 = __builtin_shufflevector(q0, q0, 4, 5);
        f16x2 q03 = __builtin_shufflevector(q0, q0, 6, 7);
        f16x2 q10 = __builtin_shufflevector(q1, q1, 0, 1);
        f16x2 q11 = __builtin_shufflevector(q1, q1, 2, 3);
        f16x2 q12 = __builtin_shufflevector(q1, q1, 4, 5);
        f16x2 q13 = __builtin_shufflevector(q1, q1, 6, 7);

        float e0, e1;
        {
            f16x2 v0 = q00 * s0h2 + xr0, v1 = q01 * s0h2 + xr1;
            f16x2 v2 = q02 * s0h2 + xr2, v3 = q03 * s0h2 + xr3;
            f16x2 k0 = v0 * C06 + habs2(v0) * C04;
            f16x2 k1 = v1 * C06 + habs2(v1) * C04;
            f16x2 k2 = v2 * C06 + habs2(v2) * C04;
            f16x2 k3 = v3 * C06 + habs2(v3) * C04;
            e0 = __builtin_amdgcn_fdot2(k0, at0, 0.f, false);
            e0 = __builtin_amdgcn_fdot2(k1, at1, e0, false);
            e0 = __builtin_amdgcn_fdot2(k2, at2, e0, false);
            e0 = __builtin_amdgcn_fdot2(k3, at3, e0, false);
        }
        {
            f16x2 v0 = q10 * s1h2 + xr0, v1 = q11 * s1h2 + xr1;
            f16x2 v2 = q12 * s1h2 + xr2, v3 = q13 * s1h2 + xr3;
            f16x2 k0 = v0 * C06 + habs2(v0) * C04;
            f16x2 k1 = v1 * C06 + habs2(v1) * C04;
            f16x2 k2 = v2 * C06 + habs2(v2) * C04;
            f16x2 k3 = v3 * C06 + habs2(v3) * C04;
            e1 = __builtin_amdgcn_fdot2(k0, at0, 0.f, false);
            e1 = __builtin_amdgcn_fdot2(k1, at1, e1, false);
            e1 = __builtin_amdgcn_fdot2(k2, at2, e1, false);
            e1 = __builtin_amdgcn_fdot2(k3, at3, e1, false);
        }

#pragma unroll
        for (int m = 1; m < 16; m <<= 1) {
            e0 += __shfl_xor(e0, m, 64);
            e1 += __shfl_xor(e1, m, 64);
        }

        float p0 = __expf(e0);
        float p1 = has2 ? __expf(e1) : 0.f;
        ssum += p0 + p1;

        _Float16 ph0s = (_Float16)(p0 * (float)sh0);
        _Float16 ph1s = (_Float16)(p1 * (float)sh1);
        f16x2 ph0 = {ph0s, ph0s};
        f16x2 ph1 = {ph1s, ph1s};
        acch[0] = acch[0] + ph0 * q00 + ph1 * q10;
        acch[1] = acch[1] + ph0 * q01 + ph1 * q11;
        acch[2] = acch[2] + ph0 * q02 + ph1 * q12;
        acch[3] = acch[3] + ph0 * q03 + ph1 * q13;
    }

    float acc[8];
    {
        f32x2 c;
        c = __builtin_convertvector(acch[0], f32x2); acc[0] = c[0]; acc[1] = c[1];
        c = __builtin_convertvector(acch[1], f32x2); acc[2] = c[0]; acc[3] = c[1];
        c = __builtin_convertvector(acch[2], f32x2); acc[4] = c[0]; acc[5] = c[1];
        c = __builtin_convertvector(acch[3], f32x2); acc[6] = c[0]; acc[7] = c[1];
    }
    float inv = 1.f / (ssum + 1e-16f);
#pragma unroll
    for (int jj = 0; jj < 8; ++jj) acc[jj] *= inv;
#pragma unroll
    for (int jj = 0; jj < 8; ++jj) acc[jj] += __shfl_xor(acc[jj], 16, 64);
#pragma unroll
    for (int jj = 0; jj < 8; ++jj) acc[jj] += __shfl_xor(acc[jj], 32, 64);

    if (h == 0) {
        const int dd = e * 8;
        float4 b40 = *(const float4*)(bias + dd);
        float4 b41 = *(const float4*)(bias + dd + 4);
        float y[8];
        y[0] = acc[0]*0.25f + b40.x; y[1] = acc[1]*0.25f + b40.y;
        y[2] = acc[2]*0.25f + b40.z; y[3] = acc[3]*0.25f + b40.w;
        y[4] = acc[4]*0.25f + b41.x; y[5] = acc[5]*0.25f + b41.y;
        y[6] = acc[6]*0.25f + b41.z; y[7] = acc[7]*0.25f + b41.w;

        float s1 = 0.f, s2 = 0.f;
#pragma unroll
        for (int jj = 0; jj < 8; ++jj) { s1 += y[jj]; s2 += y[jj]*y[jj]; }
#pragma unroll
        for (int m = 1; m < 16; m <<= 1) {
            s1 += __shfl_xor(s1, m, 64);
            s2 += __shfl_xor(s2, m, 64);
        }
        float mu = s1 * (1.f / 128.f);
        float var = s2 * (1.f / 128.f) - mu * mu;
        float rstd = rsqrtf(var + LN_EPS);

        float4 g40 = *(const float4*)(gamma + dd);
        float4 g41 = *(const float4*)(gamma + dd + 4);
        float4 e40 = *(const float4*)(beta + dd);
        float4 e41 = *(const float4*)(beta + dd + 4);
        float4 r40 = *(const float4*)(res + (size_t)n * 128 + dd);
        float4 r41 = *(const float4*)(res + (size_t)n * 128 + dd + 4);
        float g[8] = {g40.x,g40.y,g40.z,g40.w,g41.x,g41.y,g41.z,g41.w};
        float be[8] = {e40.x,e40.y,e40.z,e40.w,e41.x,e41.y,e41.z,e41.w};
        float r[8] = {r40.x,r40.y,r40.z,r40.w,r41.x,r41.y,r41.z,r41.w};
#pragma unroll
        for (int jj = 0; jj < 8; ++jj) {
            y[jj] = (y[jj] - mu) * rstd * g[jj] + be[jj] + r[jj];
            if (relu_flag) y[jj] = fmaxf(y[jj], 0.f);
        }
        float4 o0 = {y[0],y[1],y[2],y[3]};
        float4 o1 = {y[4],y[5],y[6],y[7]};
        *(float4*)(out + (size_t)n * 128 + dd)     = o0;
        *(float4*)(out + (size_t)n * 128 + dd + 4) = o1;
        if (out_h) {
            ushort4 oh0, oh1;
            oh0.x = f2h(y[0]); oh0.y = f2h(y[1]); oh0.z = f2h(y[2]); oh0.w = f2h(y[3]);
            oh1.x = f2h(y[4]); oh1.y = f2h(y[5]); oh1.z = f2h(y[6]); oh1.w = f2h(y[7]);
            *(ushort4*)(out_h + (size_t)n * 128 + dd)     = oh0;
            *(ushort4*)(out_h + (size_t)n * 128 + dd + 4) = oh1;
        }
    }
}

// ---------------- launch ----------------

extern "C" void kernel_launch(void* const* d_in, const int* in_sizes, int n_in,
                              void* d_out, int out_size, void* d_ws, size_t ws_size,
                              hipStream_t stream) {
    const float* x    = (const float*)d_in[0];
    const int*   src  = (const int*)d_in[1];
    const int*   dst  = (const int*)d_in[2];
    const float* Wl1  = (const float*)d_in[3];
    const float* Wr1  = (const float*)d_in[4];
    const float* att1 = (const float*)d_in[5];
    const float* b1   = (const float*)d_in[6];
    const float* g1   = (const float*)d_in[7];
    const float* be1  = (const float*)d_in[8];
    const float* Wl2  = (const float*)d_in[9];
    const float* Wr2  = (const float*)d_in[10];
    const float* att2 = (const float*)d_in[11];
    const float* b2   = (const float*)d_in[12];
    const float* g2   = (const float*)d_in[13];
    const float* be2  = (const float*)d_in[14];
    float* out = (float*)d_out;

    char* ws = (char*)d_ws;
    size_t off = 0;
    u16*   xlb  = (u16*)(ws + off);   off += (size_t)MPAD * 512 * 2;      // f16 XL
    u16*   xrb  = (u16*)(ws + off);   off += (size_t)MPAD * 512 * 2;      // f16 XR
    u8*    xlq  = (u8*)(ws + off);    off += (size_t)NNODES * 512;        // int8 XL
    u16*   scl  = (u16*)(ws + off);   off += (size_t)NNODES * 4 * 2;      // f16 scales
    u16*   xb   = (u16*)(ws + off);   off += (size_t)MPAD * 128 * 2;      // f16 A input
    float* hbuf = (float*)(ws + off); off += (size_t)NNODES * 128 * 4;
    u16*   Bt1  = (u16*)(ws + off);   off += (size_t)1024 * 128 * 2;
    u16*   Bt2  = (u16*)(ws + off);   off += (size_t)1024 * 128 * 2;
    int*   deg  = (int*)(ws + off);   off += (size_t)NNODES * 4;
    int*   rowp = (int*)(ws + off);   off += (size_t)(NNODES + 1) * 4;
    int*   cur  = (int*)(ws + off);   off += (size_t)NNODES * 4;
    int*   col  = (int*)(ws + off);   off += (size_t)ETOT * 4;

    k_prep<<<256, 256, 0, stream>>>(x, xb, Wl1, Wr1, Bt1, Wl2, Wr2, Bt2, deg);
    k_hist<<<(NEDGES + 255) / 256, 256, 0, stream>>>(dst, deg);
    k_scan<<<1, 1024, 0, stream>>>(deg, rowp, cur);
    k_scatter<<<(ETOT + 255) / 256, 256, 0, stream>>>(src, dst, col, cur);

    // layer 1
    k_gemm_f16<<<MPAD / 128 * 8, 256, 0, stream>>>(xb, Bt1, xlb, xrb);
    k_quant<<<NNODES / 4, 256, 0, stream>>>(xlb, xlq, scl);
    k_attn<<<NNODES / 4, 256, 0, stream>>>(xlq, scl, xrb, att1, b1, g1, be1, rowp, col,
                                           x, hbuf, xb, 1);
    // layer 2
    k_gemm_f16<<<MPAD / 128 * 8, 256, 0, stream>>>(xb, Bt2, xlb, xrb);
    k_quant<<<NNODES / 4, 256, 0, stream>>>(xlb, xlq, scl);
    k_attn<<<NNODES / 4, 256, 0, stream>>>(xlq, scl, xrb, att2, b2, g2, be2, rowp, col,
                                           hbuf, out, (u16*)nullptr, 0);
}

// Round 14
// 180.379 us; speedup vs baseline: 1.5698x; 1.0575x over previous
//
#include <hip/hip_runtime.h>
#include <hip/hip_bf16.h>
#include <hip/hip_fp16.h>

#define NNODES 20000
#define MPAD   20480              // 160 * 128 row-tiles, no M-guards anywhere
#define NEDGES 320000
#define DIM    128
#define NH     4
#define ETOT   (NEDGES + NNODES)
#define LN_EPS 1e-5f

typedef unsigned char  u8;
typedef unsigned short u16;
typedef unsigned int   u32;

typedef _Float16    f16x2 __attribute__((ext_vector_type(2)));
typedef _Float16    f16x8 __attribute__((ext_vector_type(8)));
typedef float       f32x2 __attribute__((ext_vector_type(2)));
typedef float       f32x4 __attribute__((ext_vector_type(4)));

__device__ inline u16 f2h(float f) {
    _Float16 h = (_Float16)f;
    union { _Float16 h; u16 u; } v; v.h = h; return v.u;
}
__device__ inline _Float16 bits2h(u16 b) {
    union { u16 u; _Float16 h; } v; v.u = b; return v.h;
}
__device__ inline f16x2 u2h2(u32 u) { union { u32 u; f16x2 h; } v; v.u = u; return v.h; }
__device__ inline u32 h22u(f16x2 h) { union { f16x2 h; u32 u; } v; v.h = h; return v.u; }
__device__ inline f16x2 habs2(f16x2 h) { return u2h2(h22u(h) & 0x7FFF7FFFu); }

// async global->LDS, 16B per lane, linear LDS dest (wave-uniform base + lane*16)
#define GLDS16(g, l) __builtin_amdgcn_global_load_lds(                         \
    (const __attribute__((address_space(1))) void*)(g),                        \
    (__attribute__((address_space(3))) void*)(l), 16, 0, 0)

// ---- fused prep: deg init + x->f16 + W->Bt via LDS transpose ----

__global__ __launch_bounds__(256) void k_prep(const float* __restrict__ x, u16* __restrict__ xb,
                       const float* __restrict__ Wl1, const float* __restrict__ Wr1,
                       u16* __restrict__ Bt1,
                       const float* __restrict__ Wl2, const float* __restrict__ Wr2,
                       u16* __restrict__ Bt2,
                       int* __restrict__ deg) {
    const int b = blockIdx.x, t = threadIdx.x;
    const int gid = b * 256 + t;
    if (gid < NNODES) deg[gid] = 1;   // self-loop

    for (int j = gid; j < NNODES * 32; j += 256 * 256) {
        float4 v = ((const float4*)x)[j];
        ushort4 o;
        o.x = f2h(v.x); o.y = f2h(v.y); o.z = f2h(v.z); o.w = f2h(v.w);
        ((ushort4*)xb)[j] = o;
    }

    {
        const int m    = b >> 6;
        const int tile = b & 63;
        const int kt   = tile >> 4;
        const int nt   = tile & 15;
        const float* W = (m == 0) ? Wl1 : (m == 1) ? Wr1 : (m == 2) ? Wl2 : Wr2;
        u16* Bt        = (m < 2) ? Bt1 : Bt2;
        const int nbase = (m & 1) * 512 + nt * 32;

        __shared__ float lds[32][33];
        const int tx = t & 31, ty = t >> 5;
#pragma unroll
        for (int i = 0; i < 4; ++i) {
            int k = kt * 32 + ty + i * 8;
            lds[ty + i * 8][tx] = W[k * 512 + nt * 32 + tx];
        }
        __syncthreads();
#pragma unroll
        for (int i = 0; i < 4; ++i) {
            int nrow = nbase + ty + i * 8;
            Bt[nrow * 128 + kt * 32 + tx] = f2h(lds[tx][ty + i * 8]);
        }
    }
}

// ---------------- CSR build ----------------

__global__ void k_hist(const int* __restrict__ dst, int* __restrict__ deg) {
    int i = blockIdx.x * blockDim.x + threadIdx.x;
    if (i < NEDGES) atomicAdd(&deg[dst[i]], 1);
}

__global__ __launch_bounds__(1024) void k_scan(const int* __restrict__ deg,
                                               int* __restrict__ row,
                                               int* __restrict__ cur) {
    __shared__ int part[1024];
    const int CH = 20;
    int t = threadIdx.x;
    int base = t * CH;
    int s = 0;
    int d[20];
    if (base < NNODES) {
#pragma unroll
        for (int q = 0; q < 5; ++q) {
            int4 v = ((const int4*)(deg + base))[q];
            d[q*4+0] = v.x; d[q*4+1] = v.y; d[q*4+2] = v.z; d[q*4+3] = v.w;
            s += v.x + v.y + v.z + v.w;
        }
    }
    part[t] = s;
    __syncthreads();
    for (int off = 1; off < 1024; off <<= 1) {
        int v = (t >= off) ? part[t - off] : 0;
        __syncthreads();
        part[t] += v;
        __syncthreads();
    }
    if (base < NNODES) {
        int run = (t == 0) ? 0 : part[t - 1];
#pragma unroll
        for (int i = 0; i < CH; i++) {
            row[base + i] = run; cur[base + i] = run; run += d[i];
        }
    }
    if (t == 1023) row[NNODES] = part[1023];
}

__global__ void k_scatter(const int* __restrict__ src, const int* __restrict__ dst,
                          int* __restrict__ col, int* __restrict__ cur) {
    int i = blockIdx.x * blockDim.x + threadIdx.x;
    if (i < NEDGES) {
        int d = dst[i];
        int pos = atomicAdd(&cur[d], 1);
        col[pos] = src[i];
    } else if (i < ETOT) {
        int n = i - NEDGES;
        int pos = atomicAdd(&cur[n], 1);
        col[pos] = n;
    }
}

// ------------- fp16 MFMA GEMM with FUSED int8 quantization for the XL half -------------
// m97 pattern + XCD-locality (bn fastest). For bn<512 (one head x 128 nodes per block):
// per-row absmax from smC -> int8 XLq + f16 scale, no f16 XL buffer at all.
// For bn>=512: f16 XR written via coalesced 256B rows as before.

__global__ __launch_bounds__(256, 2) void k_gemm_f16(const u16* __restrict__ A,
                                                     const u16* __restrict__ Bt,
                                                     u8*  __restrict__ XLq,
                                                     u16* __restrict__ scales,
                                                     u16* __restrict__ XR) {
    __shared__ u16 smA[128 * 128];
    __shared__ u16 smB[128 * 128];
    const int L   = blockIdx.x;
    const int xcd = L & 7;
    const int w9  = L >> 3;
    const int bm  = (xcd * 20 + (w9 >> 3)) * 128;
    const int bn  = (w9 & 7) * 128;
    const int t  = threadIdx.x;
    const int w  = t >> 6;
    const int l  = t & 63;

    {
        char* smAb = (char*)smA;
        char* smBb = (char*)smB;
#pragma unroll
        for (int p = 0; p < 8; ++p) {
            int rbase = w * 32 + p * 4;
            int row   = rbase + (l >> 4);
            int j     = (l & 15) ^ (row & 7);
            const u16* ga = A  + (size_t)(bm + row) * 128 + j * 8;
            const u16* gb = Bt + (size_t)(bn + row) * 128 + j * 8;
            GLDS16(ga, smAb + rbase * 256);
            GLDS16(gb, smBb + rbase * 256);
        }
    }
    __syncthreads();

    const int wr  = (w >> 1) * 64;
    const int wc  = (w & 1) * 64;
    const int lr  = l & 15;
    const int lkb = (l >> 4) * 16;

    f32x4 acc[4][4] = {};

#pragma unroll
    for (int ks = 0; ks < 4; ++ks) {
        f16x8 af[4], bfr[4];
#pragma unroll
        for (int i = 0; i < 4; ++i) {
            int ra = wr + i * 16 + lr;
            af[i]  = *(const f16x8*)((const char*)smA +
                        ((ra * 256 + ks * 64 + lkb) ^ ((ra & 7) << 4)));
            int rb = wc + i * 16 + lr;
            bfr[i] = *(const f16x8*)((const char*)smB +
                        ((rb * 256 + ks * 64 + lkb) ^ ((rb & 7) << 4)));
        }
#pragma unroll
        for (int mi = 0; mi < 4; ++mi)
#pragma unroll
            for (int ni = 0; ni < 4; ++ni)
                acc[mi][ni] = __builtin_amdgcn_mfma_f32_16x16x32_f16(
                    bfr[ni], af[mi], acc[mi][ni], 0, 0, 0);
    }

    __syncthreads();
    u16* smC = smA;
    {
        const int n4 = (l >> 4) * 4;
#pragma unroll
        for (int mi = 0; mi < 4; ++mi) {
            int m = wr + mi * 16 + lr;
#pragma unroll
            for (int ni = 0; ni < 4; ++ni) {
                int n = wc + ni * 16 + n4;
                f32x4 v = acc[mi][ni];
                ushort4 o;
                o.x = f2h(v[0]); o.y = f2h(v[1]); o.z = f2h(v[2]); o.w = f2h(v[3]);
                *(ushort4*)((char*)smC + (m * 256 + ((n * 2) ^ ((m & 7) << 4)))) = o;
            }
        }
    }
    __syncthreads();

    if (bn < 512) {
        // fused quantization: one head (bn>>7), rows = nodes bm..bm+127.
        // 16 lanes x 8 f16 cover the 128-col row; 4 rows in flight per wave.
        const int head = bn >> 7;
        const int lr16 = l & 15;
        const int rg   = l >> 4;
#pragma unroll
        for (int p = 0; p < 8; ++p) {
            int r = w * 32 + p * 4 + rg;
            uint4 vv = *(const uint4*)((const char*)smC +
                        (r * 256 + ((lr16 * 16) ^ ((r & 7) << 4))));
            f32x2 c0 = __builtin_convertvector(u2h2(vv.x), f32x2);
            f32x2 c1 = __builtin_convertvector(u2h2(vv.y), f32x2);
            f32x2 c2 = __builtin_convertvector(u2h2(vv.z), f32x2);
            f32x2 c3 = __builtin_convertvector(u2h2(vv.w), f32x2);
            float f[8] = {c0[0],c0[1],c1[0],c1[1],c2[0],c2[1],c3[0],c3[1]};
            float m = 0.f;
#pragma unroll
            for (int k = 0; k < 8; ++k) m = fmaxf(m, fabsf(f[k]));
#pragma unroll
            for (int o = 1; o < 16; o <<= 1) m = fmaxf(m, __shfl_xor(m, o, 64));
            float inv = (m > 0.f) ? (127.f / m) : 0.f;
            int q[8];
#pragma unroll
            for (int k = 0; k < 8; ++k) {
                int qi = (int)__builtin_rintf(f[k] * inv);
                q[k] = qi > 127 ? 127 : (qi < -127 ? -127 : qi);
            }
            u32 lo = (q[0]&255) | ((q[1]&255)<<8) | ((q[2]&255)<<16) | ((q[3]&255)<<24);
            u32 hi = (q[4]&255) | ((q[5]&255)<<8) | ((q[6]&255)<<16) | ((q[7]&255)<<24);
            uint2 pk; pk.x = lo; pk.y = hi;
            *(uint2*)(XLq + (size_t)(bm + r) * 512 + head * 128 + lr16 * 8) = pk;
            if (lr16 == 0) scales[(bm + r) * 4 + head] = f2h(m * (1.f / 127.f));
        }
    } else {
        int r  = t >> 4;
        int cb = (t & 15) * 16;
        u16* base = XR + (bn - 512);
#pragma unroll
        for (int p = 0; p < 8; ++p) {
            int row = p * 16 + r;
            uint4 v = *(const uint4*)((const char*)smC +
                        (row * 256 + (cb ^ ((row & 7) << 4))));
            *(uint4*)(base + (size_t)(bm + row) * 512 + (cb >> 1)) = v;
        }
    }
}

// ------------- fused GATv2 attention + head-mean + bias + LN + residual -------------
// ONE wave per node; int8 gather (8 B/lane/edge) + per-node-per-head f16 scale.
// Magic-number decode: h = bits(0x6400 | (q^0x80)) = q+1152 exactly; q = h - 1152.

__global__ __launch_bounds__(256) void k_attn(const u8*  __restrict__ XLq,
                                              const u16* __restrict__ scales,
                                              const u16* __restrict__ XR,
                                              const float* __restrict__ att,
                                              const float* __restrict__ bias,
                                              const float* __restrict__ gamma,
                                              const float* __restrict__ beta,
                                              const int* __restrict__ row,
                                              const int* __restrict__ col,
                                              const float* __restrict__ res,
                                              float* __restrict__ out,
                                              u16* __restrict__ out_h,
                                              int relu_flag) {
    const int wid = __builtin_amdgcn_readfirstlane(threadIdx.x >> 6);
    const int n   = blockIdx.x * 4 + wid;          // grid = NNODES/4 exactly
    const int l   = threadIdx.x & 63;
    const int h   = l >> 4;
    const int e   = l & 15;

    const f16x2 C06 = {(_Float16)0.6f, (_Float16)0.6f};
    const f16x2 C04 = {(_Float16)0.4f, (_Float16)0.4f};
    const f16x2 M1152 = {(_Float16)(-1152.f), (_Float16)(-1152.f)};
    const u32 K64 = 0x64646464u;

    const int lane_off = h * 128 + e * 8;

    uint4 xru = *(const uint4*)(XR + (size_t)n * 512 + lane_off);
    f16x2 xr0 = u2h2(xru.x), xr1 = u2h2(xru.y), xr2 = u2h2(xru.z), xr3 = u2h2(xru.w);

    const float* ap = att + lane_off;
    float4 af0 = *(const float4*)(ap);
    float4 af1 = *(const float4*)(ap + 4);
    f16x2 at0 = {(_Float16)af0.x, (_Float16)af0.y};
    f16x2 at1 = {(_Float16)af0.z, (_Float16)af0.w};
    f16x2 at2 = {(_Float16)af1.x, (_Float16)af1.y};
    f16x2 at3 = {(_Float16)af1.z, (_Float16)af1.w};

    f16x2 acch[4] = {};
    float ssum = 0.f;

    const int beg = row[n], end = row[n + 1];

    for (int i = beg; i < end; i += 2) {
        int s0 = col[i];
        bool has2 = (i + 1 < end);
        int s1 = has2 ? col[i + 1] : s0;

        uint2 a0 = *(const uint2*)(XLq + (size_t)s0 * 512 + lane_off);
        uint2 a1 = *(const uint2*)(XLq + (size_t)s1 * 512 + lane_off);
        _Float16 sh0 = bits2h(scales[s0 * 4 + h]);
        _Float16 sh1 = bits2h(scales[s1 * 4 + h]);
        f16x2 s0h2 = {sh0, sh0};
        f16x2 s1h2 = {sh1, sh1};

        // magic decode int8 -> f16 (exact): 2 xor + 4 perm + 4 pk_add per edge
        u32 w00 = a0.x ^ 0x80808080u, w01 = a0.y ^ 0x80808080u;
        u32 w10 = a1.x ^ 0x80808080u, w11 = a1.y ^ 0x80808080u;
        f16x2 q00 = u2h2(__builtin_amdgcn_perm(K64, w00, 0x04010400u)) + M1152;
        f16x2 q01 = u2h2(__builtin_amdgcn_perm(K64, w00, 0x04030402u)) + M1152;
        f16x2 q02 = u2h2(__builtin_amdgcn_perm(K64, w01, 0x04010400u)) + M1152;
        f16x2 q03 = u2h2(__builtin_amdgcn_perm(K64, w01, 0x04030402u)) + M1152;
        f16x2 q10 = u2h2(__builtin_amdgcn_perm(K64, w10, 0x04010400u)) + M1152;
        f16x2 q11 = u2h2(__builtin_amdgcn_perm(K64, w10, 0x04030402u)) + M1152;
        f16x2 q12 = u2h2(__builtin_amdgcn_perm(K64, w11, 0x04010400u)) + M1152;
        f16x2 q13 = u2h2(__builtin_amdgcn_perm(K64, w11, 0x04030402u)) + M1152;

        float e0, e1;
        {
            f16x2 v0 = q00 * s0h2 + xr0, v1 = q01 * s0h2 + xr1;
            f16x2 v2 = q02 * s0h2 + xr2, v3 = q03 * s0h2 + xr3;
            f16x2 k0 = v0 * C06 + habs2(v0) * C04;
            f16x2 k1 = v1 * C06 + habs2(v1) * C04;
            f16x2 k2 = v2 * C06 + habs2(v2) * C04;
            f16x2 k3 = v3 * C06 + habs2(v3) * C04;
            e0 = __builtin_amdgcn_fdot2(k0, at0, 0.f, false);
            e0 = __builtin_amdgcn_fdot2(k1, at1, e0, false);
            e0 = __builtin_amdgcn_fdot2(k2, at2, e0, false);
            e0 = __builtin_amdgcn_fdot2(k3, at3, e0, false);
        }
        {
            f16x2 v0 = q10 * s1h2 + xr0, v1 = q11 * s1h2 + xr1;
            f16x2 v2 = q12 * s1h2 + xr2, v3 = q13 * s1h2 + xr3;
            f16x2 k0 = v0 * C06 + habs2(v0) * C04;
            f16x2 k1 = v1 * C06 + habs2(v1) * C04;
            f16x2 k2 = v2 * C06 + habs2(v2) * C04;
            f16x2 k3 = v3 * C06 + habs2(v3) * C04;
            e1 = __builtin_amdgcn_fdot2(k0, at0, 0.f, false);
            e1 = __builtin_amdgcn_fdot2(k1, at1, e1, false);
            e1 = __builtin_amdgcn_fdot2(k2, at2, e1, false);
            e1 = __builtin_amdgcn_fdot2(k3, at3, e1, false);
        }

#pragma unroll
        for (int m = 1; m < 16; m <<= 1) {
            e0 += __shfl_xor(e0, m, 64);
            e1 += __shfl_xor(e1, m, 64);
        }

        float p0 = __expf(e0);
        float p1 = has2 ? __expf(e1) : 0.f;
        ssum += p0 + p1;

        _Float16 ph0s = (_Float16)(p0 * (float)sh0);
        _Float16 ph1s = (_Float16)(p1 * (float)sh1);
        f16x2 ph0 = {ph0s, ph0s};
        f16x2 ph1 = {ph1s, ph1s};
        acch[0] = acch[0] + ph0 * q00 + ph1 * q10;
        acch[1] = acch[1] + ph0 * q01 + ph1 * q11;
        acch[2] = acch[2] + ph0 * q02 + ph1 * q12;
        acch[3] = acch[3] + ph0 * q03 + ph1 * q13;
    }

    float acc[8];
    {
        f32x2 c;
        c = __builtin_convertvector(acch[0], f32x2); acc[0] = c[0]; acc[1] = c[1];
        c = __builtin_convertvector(acch[1], f32x2); acc[2] = c[0]; acc[3] = c[1];
        c = __builtin_convertvector(acch[2], f32x2); acc[4] = c[0]; acc[5] = c[1];
        c = __builtin_convertvector(acch[3], f32x2); acc[6] = c[0]; acc[7] = c[1];
    }
    float inv = 1.f / (ssum + 1e-16f);
#pragma unroll
    for (int jj = 0; jj < 8; ++jj) acc[jj] *= inv;
#pragma unroll
    for (int jj = 0; jj < 8; ++jj) acc[jj] += __shfl_xor(acc[jj], 16, 64);
#pragma unroll
    for (int jj = 0; jj < 8; ++jj) acc[jj] += __shfl_xor(acc[jj], 32, 64);

    if (h == 0) {
        const int dd = e * 8;
        float4 b40 = *(const float4*)(bias + dd);
        float4 b41 = *(const float4*)(bias + dd + 4);
        float y[8];
        y[0] = acc[0]*0.25f + b40.x; y[1] = acc[1]*0.25f + b40.y;
        y[2] = acc[2]*0.25f + b40.z; y[3] = acc[3]*0.25f + b40.w;
        y[4] = acc[4]*0.25f + b41.x; y[5] = acc[5]*0.25f + b41.y;
        y[6] = acc[6]*0.25f + b41.z; y[7] = acc[7]*0.25f + b41.w;

        float s1 = 0.f, s2 = 0.f;
#pragma unroll
        for (int jj = 0; jj < 8; ++jj) { s1 += y[jj]; s2 += y[jj]*y[jj]; }
#pragma unroll
        for (int m = 1; m < 16; m <<= 1) {
            s1 += __shfl_xor(s1, m, 64);
            s2 += __shfl_xor(s2, m, 64);
        }
        float mu = s1 * (1.f / 128.f);
        float var = s2 * (1.f / 128.f) - mu * mu;
        float rstd = rsqrtf(var + LN_EPS);

        float4 g40 = *(const float4*)(gamma + dd);
        float4 g41 = *(const float4*)(gamma + dd + 4);
        float4 e40 = *(const float4*)(beta + dd);
        float4 e41 = *(const float4*)(beta + dd + 4);
        float4 r40 = *(const float4*)(res + (size_t)n * 128 + dd);
        float4 r41 = *(const float4*)(res + (size_t)n * 128 + dd + 4);
        float g[8] = {g40.x,g40.y,g40.z,g40.w,g41.x,g41.y,g41.z,g41.w};
        float be[8] = {e40.x,e40.y,e40.z,e40.w,e41.x,e41.y,e41.z,e41.w};
        float r[8] = {r40.x,r40.y,r40.z,r40.w,r41.x,r41.y,r41.z,r41.w};
#pragma unroll
        for (int jj = 0; jj < 8; ++jj) {
            y[jj] = (y[jj] - mu) * rstd * g[jj] + be[jj] + r[jj];
            if (relu_flag) y[jj] = fmaxf(y[jj], 0.f);
        }
        float4 o0 = {y[0],y[1],y[2],y[3]};
        float4 o1 = {y[4],y[5],y[6],y[7]};
        *(float4*)(out + (size_t)n * 128 + dd)     = o0;
        *(float4*)(out + (size_t)n * 128 + dd + 4) = o1;
        if (out_h) {
            ushort4 oh0, oh1;
            oh0.x = f2h(y[0]); oh0.y = f2h(y[1]); oh0.z = f2h(y[2]); oh0.w = f2h(y[3]);
            oh1.x = f2h(y[4]); oh1.y = f2h(y[5]); oh1.z = f2h(y[6]); oh1.w = f2h(y[7]);
            *(ushort4*)(out_h + (size_t)n * 128 + dd)     = oh0;
            *(ushort4*)(out_h + (size_t)n * 128 + dd + 4) = oh1;
        }
    }
}

// ---------------- launch ----------------

extern "C" void kernel_launch(void* const* d_in, const int* in_sizes, int n_in,
                              void* d_out, int out_size, void* d_ws, size_t ws_size,
                              hipStream_t stream) {
    const float* x    = (const float*)d_in[0];
    const int*   src  = (const int*)d_in[1];
    const int*   dst  = (const int*)d_in[2];
    const float* Wl1  = (const float*)d_in[3];
    const float* Wr1  = (const float*)d_in[4];
    const float* att1 = (const float*)d_in[5];
    const float* b1   = (const float*)d_in[6];
    const float* g1   = (const float*)d_in[7];
    const float* be1  = (const float*)d_in[8];
    const float* Wl2  = (const float*)d_in[9];
    const float* Wr2  = (const float*)d_in[10];
    const float* att2 = (const float*)d_in[11];
    const float* b2   = (const float*)d_in[12];
    const float* g2   = (const float*)d_in[13];
    const float* be2  = (const float*)d_in[14];
    float* out = (float*)d_out;

    char* ws = (char*)d_ws;
    size_t off = 0;
    u8*    xlq  = (u8*)(ws + off);    off += (size_t)MPAD * 512;          // int8 XL
    u16*   scl  = (u16*)(ws + off);   off += (size_t)MPAD * 4 * 2;        // f16 scales
    u16*   xrb  = (u16*)(ws + off);   off += (size_t)MPAD * 512 * 2;      // f16 XR
    u16*   xb   = (u16*)(ws + off);   off += (size_t)MPAD * 128 * 2;      // f16 A input
    float* hbuf = (float*)(ws + off); off += (size_t)NNODES * 128 * 4;
    u16*   Bt1  = (u16*)(ws + off);   off += (size_t)1024 * 128 * 2;
    u16*   Bt2  = (u16*)(ws + off);   off += (size_t)1024 * 128 * 2;
    int*   deg  = (int*)(ws + off);   off += (size_t)NNODES * 4;
    int*   rowp = (int*)(ws + off);   off += (size_t)(NNODES + 1) * 4;
    int*   cur  = (int*)(ws + off);   off += (size_t)NNODES * 4;
    int*   col  = (int*)(ws + off);   off += (size_t)ETOT * 4;

    k_prep<<<256, 256, 0, stream>>>(x, xb, Wl1, Wr1, Bt1, Wl2, Wr2, Bt2, deg);
    k_hist<<<(NEDGES + 255) / 256, 256, 0, stream>>>(dst, deg);
    k_scan<<<1, 1024, 0, stream>>>(deg, rowp, cur);
    k_scatter<<<(ETOT + 255) / 256, 256, 0, stream>>>(src, dst, col, cur);

    // layer 1
    k_gemm_f16<<<MPAD / 128 * 8, 256, 0, stream>>>(xb, Bt1, xlq, scl, xrb);
    k_attn<<<NNODES / 4, 256, 0, stream>>>(xlq, scl, xrb, att1, b1, g1, be1, rowp, col,
                                           x, hbuf, xb, 1);
    // layer 2
    k_gemm_f16<<<MPAD / 128 * 8, 256, 0, stream>>>(xb, Bt2, xlq, scl, xrb);
    k_attn<<<NNODES / 4, 256, 0, stream>>>(xlq, scl, xrb, att2, b2, g2, be2, rowp, col,
                                           hbuf, out, (u16*)nullptr, 0);
}

// Round 15
// 174.064 us; speedup vs baseline: 1.6267x; 1.0363x over previous
//
#include <hip/hip_runtime.h>
#include <hip/hip_bf16.h>
#include <hip/hip_fp16.h>

#define NNODES 20000
#define MPAD   20480              // 160 * 128 row-tiles, no M-guards anywhere
#define NEDGES 320000
#define DIM    128
#define NH     4
#define ETOT   (NEDGES + NNODES)
#define LN_EPS 1e-5f

typedef unsigned char  u8;
typedef unsigned short u16;
typedef unsigned int   u32;

typedef _Float16    f16x2 __attribute__((ext_vector_type(2)));
typedef _Float16    f16x8 __attribute__((ext_vector_type(8)));
typedef float       f32x2 __attribute__((ext_vector_type(2)));
typedef float       f32x4 __attribute__((ext_vector_type(4)));

__device__ inline u16 f2h(float f) {
    _Float16 h = (_Float16)f;
    union { _Float16 h; u16 u; } v; v.h = h; return v.u;
}
__device__ inline _Float16 bits2h(u16 b) {
    union { u16 u; _Float16 h; } v; v.u = b; return v.h;
}
__device__ inline f16x2 u2h2(u32 u) { union { u32 u; f16x2 h; } v; v.u = u; return v.h; }
__device__ inline u32 h22u(f16x2 h) { union { f16x2 h; u32 u; } v; v.h = h; return v.u; }
__device__ inline f16x2 habs2(f16x2 h) { return u2h2(h22u(h) & 0x7FFF7FFFu); }

// DPP row_ror rotate (16-lane row), pure-VALU cross-lane
#define DPP_ROR(x, ctrl) ({ union {float f; int i;} _a, _b; _a.f=(x); \
    _b.i = __builtin_amdgcn_update_dpp(0, _a.i, (ctrl), 0xF, 0xF, true); _b.f; })
__device__ inline float rowsum16(float x) {
    x += DPP_ROR(x, 0x121); x += DPP_ROR(x, 0x122);
    x += DPP_ROR(x, 0x124); x += DPP_ROR(x, 0x128);
    return x;
}
__device__ inline float rowmax16(float x) {
    x = fmaxf(x, DPP_ROR(x, 0x121)); x = fmaxf(x, DPP_ROR(x, 0x122));
    x = fmaxf(x, DPP_ROR(x, 0x124)); x = fmaxf(x, DPP_ROR(x, 0x128));
    return x;
}

// async global->LDS, 16B per lane, linear LDS dest
#define GLDS16(g, l) __builtin_amdgcn_global_load_lds(                         \
    (const __attribute__((address_space(1))) void*)(g),                        \
    (__attribute__((address_space(3))) void*)(l), 16, 0, 0)

// ---- fused prep: deg init + x->f16 + W->Bt via LDS transpose ----

__global__ __launch_bounds__(256) void k_prep(const float* __restrict__ x, u16* __restrict__ xb,
                       const float* __restrict__ Wl1, const float* __restrict__ Wr1,
                       u16* __restrict__ Bt1,
                       const float* __restrict__ Wl2, const float* __restrict__ Wr2,
                       u16* __restrict__ Bt2,
                       int* __restrict__ deg) {
    const int b = blockIdx.x, t = threadIdx.x;
    const int gid = b * 256 + t;
    if (gid < NNODES) deg[gid] = 1;   // self-loop

    for (int j = gid; j < NNODES * 32; j += 256 * 256) {
        float4 v = ((const float4*)x)[j];
        ushort4 o;
        o.x = f2h(v.x); o.y = f2h(v.y); o.z = f2h(v.z); o.w = f2h(v.w);
        ((ushort4*)xb)[j] = o;
    }

    {
        const int m    = b >> 6;
        const int tile = b & 63;
        const int kt   = tile >> 4;
        const int nt   = tile & 15;
        const float* W = (m == 0) ? Wl1 : (m == 1) ? Wr1 : (m == 2) ? Wl2 : Wr2;
        u16* Bt        = (m < 2) ? Bt1 : Bt2;
        const int nbase = (m & 1) * 512 + nt * 32;

        __shared__ float lds[32][33];
        const int tx = t & 31, ty = t >> 5;
#pragma unroll
        for (int i = 0; i < 4; ++i) {
            int k = kt * 32 + ty + i * 8;
            lds[ty + i * 8][tx] = W[k * 512 + nt * 32 + tx];
        }
        __syncthreads();
#pragma unroll
        for (int i = 0; i < 4; ++i) {
            int nrow = nbase + ty + i * 8;
            Bt[nrow * 128 + kt * 32 + tx] = f2h(lds[tx][ty + i * 8]);
        }
    }
}

// ---------------- CSR build ----------------

__global__ void k_hist(const int* __restrict__ dst, int* __restrict__ deg) {
    int i = blockIdx.x * blockDim.x + threadIdx.x;
    if (i < NEDGES) atomicAdd(&deg[dst[i]], 1);
}

__global__ __launch_bounds__(1024) void k_scan(const int* __restrict__ deg,
                                               int* __restrict__ row,
                                               int* __restrict__ cur) {
    __shared__ int part[1024];
    const int CH = 20;
    int t = threadIdx.x;
    int base = t * CH;
    int s = 0;
    int d[20];
    if (base < NNODES) {
#pragma unroll
        for (int q = 0; q < 5; ++q) {
            int4 v = ((const int4*)(deg + base))[q];
            d[q*4+0] = v.x; d[q*4+1] = v.y; d[q*4+2] = v.z; d[q*4+3] = v.w;
            s += v.x + v.y + v.z + v.w;
        }
    }
    part[t] = s;
    __syncthreads();
    for (int off = 1; off < 1024; off <<= 1) {
        int v = (t >= off) ? part[t - off] : 0;
        __syncthreads();
        part[t] += v;
        __syncthreads();
    }
    if (base < NNODES) {
        int run = (t == 0) ? 0 : part[t - 1];
#pragma unroll
        for (int i = 0; i < CH; i++) {
            row[base + i] = run; cur[base + i] = run; run += d[i];
        }
    }
    if (t == 1023) row[NNODES] = part[1023];
}

__global__ void k_scatter(const int* __restrict__ src, const int* __restrict__ dst,
                          int* __restrict__ col, int* __restrict__ cur) {
    int i = blockIdx.x * blockDim.x + threadIdx.x;
    if (i < NEDGES) {
        int d = dst[i];
        int pos = atomicAdd(&cur[d], 1);
        col[pos] = src[i];
    } else if (i < ETOT) {
        int n = i - NEDGES;
        int pos = atomicAdd(&cur[n], 1);
        col[pos] = n;
    }
}

// ------------- fp16 MFMA GEMM + fused int8 quant + fused att-dot precompute -------------
// XL blocks (bn<512): per-row absmax -> int8 XLq; sclD = pack(scale_f16, Dl6_f16)
// where Dl6 = 0.6*dot(xl_row, att_head). XR blocks: f16 XR + Dr6 = 0.6*dot(xr_row, att_head).

__global__ __launch_bounds__(256, 2) void k_gemm_f16(const u16* __restrict__ A,
                                                     const u16* __restrict__ Bt,
                                                     const float* __restrict__ att,
                                                     u8*  __restrict__ XLq,
                                                     u32* __restrict__ sclD,
                                                     u16* __restrict__ Dr6,
                                                     u16* __restrict__ XR) {
    __shared__ u16 smA[128 * 128];
    __shared__ u16 smB[128 * 128];
    const int L   = blockIdx.x;
    const int xcd = L & 7;
    const int w9  = L >> 3;
    const int bm  = (xcd * 20 + (w9 >> 3)) * 128;
    const int bn  = (w9 & 7) * 128;
    const int t  = threadIdx.x;
    const int w  = t >> 6;
    const int l  = t & 63;

    {
        char* smAb = (char*)smA;
        char* smBb = (char*)smB;
#pragma unroll
        for (int p = 0; p < 8; ++p) {
            int rbase = w * 32 + p * 4;
            int row   = rbase + (l >> 4);
            int j     = (l & 15) ^ (row & 7);
            const u16* ga = A  + (size_t)(bm + row) * 128 + j * 8;
            const u16* gb = Bt + (size_t)(bn + row) * 128 + j * 8;
            GLDS16(ga, smAb + rbase * 256);
            GLDS16(gb, smBb + rbase * 256);
        }
    }
    __syncthreads();

    const int wr  = (w >> 1) * 64;
    const int wc  = (w & 1) * 64;
    const int lr  = l & 15;
    const int lkb = (l >> 4) * 16;

    f32x4 acc[4][4] = {};

#pragma unroll
    for (int ks = 0; ks < 4; ++ks) {
        f16x8 af[4], bfr[4];
#pragma unroll
        for (int i = 0; i < 4; ++i) {
            int ra = wr + i * 16 + lr;
            af[i]  = *(const f16x8*)((const char*)smA +
                        ((ra * 256 + ks * 64 + lkb) ^ ((ra & 7) << 4)));
            int rb = wc + i * 16 + lr;
            bfr[i] = *(const f16x8*)((const char*)smB +
                        ((rb * 256 + ks * 64 + lkb) ^ ((rb & 7) << 4)));
        }
#pragma unroll
        for (int mi = 0; mi < 4; ++mi)
#pragma unroll
            for (int ni = 0; ni < 4; ++ni)
                acc[mi][ni] = __builtin_amdgcn_mfma_f32_16x16x32_f16(
                    bfr[ni], af[mi], acc[mi][ni], 0, 0, 0);
    }

    __syncthreads();
    u16* smC = smA;
    {
        const int n4 = (l >> 4) * 4;
#pragma unroll
        for (int mi = 0; mi < 4; ++mi) {
            int m = wr + mi * 16 + lr;
#pragma unroll
            for (int ni = 0; ni < 4; ++ni) {
                int n = wc + ni * 16 + n4;
                f32x4 v = acc[mi][ni];
                ushort4 o;
                o.x = f2h(v[0]); o.y = f2h(v[1]); o.z = f2h(v[2]); o.w = f2h(v[3]);
                *(ushort4*)((char*)smC + (m * 256 + ((n * 2) ^ ((m & 7) << 4)))) = o;
            }
        }
    }
    __syncthreads();

    const int lr16 = l & 15;
    const int rg   = l >> 4;
    const int head = (bn < 512) ? (bn >> 7) : ((bn >> 7) - 4);
    // att chunk for this lane's 8 dims (f32)
    const float* ap = att + head * 128 + lr16 * 8;
    float4 aa0 = *(const float4*)(ap);
    float4 aa1 = *(const float4*)(ap + 4);
    const float av[8] = {aa0.x, aa0.y, aa0.z, aa0.w, aa1.x, aa1.y, aa1.z, aa1.w};

    if (bn < 512) {
        // fused quant + Dl6 per row
#pragma unroll
        for (int p = 0; p < 8; ++p) {
            int r = w * 32 + p * 4 + rg;
            uint4 vv = *(const uint4*)((const char*)smC +
                        (r * 256 + ((lr16 * 16) ^ ((r & 7) << 4))));
            f32x2 c0 = __builtin_convertvector(u2h2(vv.x), f32x2);
            f32x2 c1 = __builtin_convertvector(u2h2(vv.y), f32x2);
            f32x2 c2 = __builtin_convertvector(u2h2(vv.z), f32x2);
            f32x2 c3 = __builtin_convertvector(u2h2(vv.w), f32x2);
            float f[8] = {c0[0],c0[1],c1[0],c1[1],c2[0],c2[1],c3[0],c3[1]};
            float m = 0.f, d = 0.f;
#pragma unroll
            for (int k = 0; k < 8; ++k) { m = fmaxf(m, fabsf(f[k])); d += f[k] * av[k]; }
            m = rowmax16(m);
            d = rowsum16(d);
            float inv = (m > 0.f) ? (127.f / m) : 0.f;
            int q[8];
#pragma unroll
            for (int k = 0; k < 8; ++k) {
                int qi = (int)__builtin_rintf(f[k] * inv);
                q[k] = qi > 127 ? 127 : (qi < -127 ? -127 : qi);
            }
            u32 lo = (q[0]&255) | ((q[1]&255)<<8) | ((q[2]&255)<<16) | ((q[3]&255)<<24);
            u32 hi = (q[4]&255) | ((q[5]&255)<<8) | ((q[6]&255)<<16) | ((q[7]&255)<<24);
            uint2 pk; pk.x = lo; pk.y = hi;
            *(uint2*)(XLq + (size_t)(bm + r) * 512 + head * 128 + lr16 * 8) = pk;
            if (lr16 == 0)
                sclD[(bm + r) * 4 + head] =
                    (u32)f2h(m * (1.f / 127.f)) | ((u32)f2h(0.6f * d) << 16);
        }
    } else {
        // Dr6 per row
#pragma unroll
        for (int p = 0; p < 8; ++p) {
            int r = w * 32 + p * 4 + rg;
            uint4 vv = *(const uint4*)((const char*)smC +
                        (r * 256 + ((lr16 * 16) ^ ((r & 7) << 4))));
            f32x2 c0 = __builtin_convertvector(u2h2(vv.x), f32x2);
            f32x2 c1 = __builtin_convertvector(u2h2(vv.y), f32x2);
            f32x2 c2 = __builtin_convertvector(u2h2(vv.z), f32x2);
            f32x2 c3 = __builtin_convertvector(u2h2(vv.w), f32x2);
            float f[8] = {c0[0],c0[1],c1[0],c1[1],c2[0],c2[1],c3[0],c3[1]};
            float d = 0.f;
#pragma unroll
            for (int k = 0; k < 8; ++k) d += f[k] * av[k];
            d = rowsum16(d);
            if (lr16 == 0) Dr6[(bm + r) * 4 + head] = f2h(0.6f * d);
        }
        // coalesced XR writes
        int r  = t >> 4;
        int cb = (t & 15) * 16;
        u16* base = XR + (bn - 512);
#pragma unroll
        for (int p = 0; p < 8; ++p) {
            int row = p * 16 + r;
            uint4 v = *(const uint4*)((const char*)smC +
                        (row * 256 + (cb ^ ((row & 7) << 4))));
            *(uint4*)(base + (size_t)(bm + row) * 512 + (cb >> 1)) = v;
        }
    }
}

// ------------- fused GATv2 attention + head-mean + bias + LN + residual -------------
// score e = 0.6*(Dl+Dr) [precomputed] + dot(|v|, 0.4*att) [per-edge, DPP row-reduce].

__global__ __launch_bounds__(256) void k_attn(const u8*  __restrict__ XLq,
                                              const u32* __restrict__ sclD,
                                              const u16* __restrict__ Dr6,
                                              const u16* __restrict__ XR,
                                              const float* __restrict__ att,
                                              const float* __restrict__ bias,
                                              const float* __restrict__ gamma,
                                              const float* __restrict__ beta,
                                              const int* __restrict__ row,
                                              const int* __restrict__ col,
                                              const float* __restrict__ res,
                                              float* __restrict__ out,
                                              u16* __restrict__ out_h,
                                              int relu_flag) {
    const int wid = __builtin_amdgcn_readfirstlane(threadIdx.x >> 6);
    const int n   = blockIdx.x * 4 + wid;          // grid = NNODES/4 exactly
    const int l   = threadIdx.x & 63;
    const int h   = l >> 4;
    const int e   = l & 15;

    const f16x2 M1152 = {(_Float16)(-1152.f), (_Float16)(-1152.f)};
    const u32 K64 = 0x64646464u;

    const int lane_off = h * 128 + e * 8;

    uint4 xru = *(const uint4*)(XR + (size_t)n * 512 + lane_off);
    f16x2 xr0 = u2h2(xru.x), xr1 = u2h2(xru.y), xr2 = u2h2(xru.z), xr3 = u2h2(xru.w);

    // 0.4*att in f16 pairs
    const float* ap = att + lane_off;
    float4 af0 = *(const float4*)(ap);
    float4 af1 = *(const float4*)(ap + 4);
    f16x2 at0 = {(_Float16)(0.4f*af0.x), (_Float16)(0.4f*af0.y)};
    f16x2 at1 = {(_Float16)(0.4f*af0.z), (_Float16)(0.4f*af0.w)};
    f16x2 at2 = {(_Float16)(0.4f*af1.x), (_Float16)(0.4f*af1.y)};
    f16x2 at3 = {(_Float16)(0.4f*af1.z), (_Float16)(0.4f*af1.w)};

    const float dr6n = (float)bits2h(Dr6[n * 4 + h]);   // 0.6*dot(xr_n, att_h)

    f16x2 acch[4] = {};
    float ssum = 0.f;

    const int beg = row[n], end = row[n + 1];

    for (int i = beg; i < end; i += 2) {
        int s0 = col[i];
        bool has2 = (i + 1 < end);
        int s1 = has2 ? col[i + 1] : s0;

        uint2 a0 = *(const uint2*)(XLq + (size_t)s0 * 512 + lane_off);
        uint2 a1 = *(const uint2*)(XLq + (size_t)s1 * 512 + lane_off);
        u32 sd0 = sclD[s0 * 4 + h];
        u32 sd1 = sclD[s1 * 4 + h];
        _Float16 sh0 = bits2h((u16)sd0);
        _Float16 sh1 = bits2h((u16)sd1);
        float d60 = dr6n + (float)bits2h((u16)(sd0 >> 16));
        float d61 = dr6n + (float)bits2h((u16)(sd1 >> 16));
        f16x2 s0h2 = {sh0, sh0};
        f16x2 s1h2 = {sh1, sh1};

        // magic decode int8 -> f16 (exact)
        u32 w00 = a0.x ^ 0x80808080u, w01 = a0.y ^ 0x80808080u;
        u32 w10 = a1.x ^ 0x80808080u, w11 = a1.y ^ 0x80808080u;
        f16x2 q00 = u2h2(__builtin_amdgcn_perm(K64, w00, 0x04010400u)) + M1152;
        f16x2 q01 = u2h2(__builtin_amdgcn_perm(K64, w00, 0x04030402u)) + M1152;
        f16x2 q02 = u2h2(__builtin_amdgcn_perm(K64, w01, 0x04010400u)) + M1152;
        f16x2 q03 = u2h2(__builtin_amdgcn_perm(K64, w01, 0x04030402u)) + M1152;
        f16x2 q10 = u2h2(__builtin_amdgcn_perm(K64, w10, 0x04010400u)) + M1152;
        f16x2 q11 = u2h2(__builtin_amdgcn_perm(K64, w10, 0x04030402u)) + M1152;
        f16x2 q12 = u2h2(__builtin_amdgcn_perm(K64, w11, 0x04010400u)) + M1152;
        f16x2 q13 = u2h2(__builtin_amdgcn_perm(K64, w11, 0x04030402u)) + M1152;

        float e0, e1;
        {
            f16x2 v0 = q00 * s0h2 + xr0, v1 = q01 * s0h2 + xr1;
            f16x2 v2 = q02 * s0h2 + xr2, v3 = q03 * s0h2 + xr3;
            e0 = __builtin_amdgcn_fdot2(habs2(v0), at0, 0.f, false);
            e0 = __builtin_amdgcn_fdot2(habs2(v1), at1, e0, false);
            e0 = __builtin_amdgcn_fdot2(habs2(v2), at2, e0, false);
            e0 = __builtin_amdgcn_fdot2(habs2(v3), at3, e0, false);
        }
        {
            f16x2 v0 = q10 * s1h2 + xr0, v1 = q11 * s1h2 + xr1;
            f16x2 v2 = q12 * s1h2 + xr2, v3 = q13 * s1h2 + xr3;
            e1 = __builtin_amdgcn_fdot2(habs2(v0), at0, 0.f, false);
            e1 = __builtin_amdgcn_fdot2(habs2(v1), at1, e1, false);
            e1 = __builtin_amdgcn_fdot2(habs2(v2), at2, e1, false);
            e1 = __builtin_amdgcn_fdot2(habs2(v3), at3, e1, false);
        }

        // 16-lane row reduce via DPP (pure VALU), interleaved for ILP
        e0 += DPP_ROR(e0, 0x121); e1 += DPP_ROR(e1, 0x121);
        e0 += DPP_ROR(e0, 0x122); e1 += DPP_ROR(e1, 0x122);
        e0 += DPP_ROR(e0, 0x124); e1 += DPP_ROR(e1, 0x124);
        e0 += DPP_ROR(e0, 0x128); e1 += DPP_ROR(e1, 0x128);

        float p0 = __expf(e0 + d60);
        float p1 = has2 ? __expf(e1 + d61) : 0.f;
        ssum += p0 + p1;

        _Float16 ph0s = (_Float16)(p0 * (float)sh0);
        _Float16 ph1s = (_Float16)(p1 * (float)sh1);
        f16x2 ph0 = {ph0s, ph0s};
        f16x2 ph1 = {ph1s, ph1s};
        acch[0] = acch[0] + ph0 * q00 + ph1 * q10;
        acch[1] = acch[1] + ph0 * q01 + ph1 * q11;
        acch[2] = acch[2] + ph0 * q02 + ph1 * q12;
        acch[3] = acch[3] + ph0 * q03 + ph1 * q13;
    }

    float acc[8];
    {
        f32x2 c;
        c = __builtin_convertvector(acch[0], f32x2); acc[0] = c[0]; acc[1] = c[1];
        c = __builtin_convertvector(acch[1], f32x2); acc[2] = c[0]; acc[3] = c[1];
        c = __builtin_convertvector(acch[2], f32x2); acc[4] = c[0]; acc[5] = c[1];
        c = __builtin_convertvector(acch[3], f32x2); acc[6] = c[0]; acc[7] = c[1];
    }
    float inv = 1.f / (ssum + 1e-16f);
#pragma unroll
    for (int jj = 0; jj < 8; ++jj) acc[jj] *= inv;
#pragma unroll
    for (int jj = 0; jj < 8; ++jj) acc[jj] += __shfl_xor(acc[jj], 16, 64);
#pragma unroll
    for (int jj = 0; jj < 8; ++jj) acc[jj] += __shfl_xor(acc[jj], 32, 64);

    if (h == 0) {
        const int dd = e * 8;
        float4 b40 = *(const float4*)(bias + dd);
        float4 b41 = *(const float4*)(bias + dd + 4);
        float y[8];
        y[0] = acc[0]*0.25f + b40.x; y[1] = acc[1]*0.25f + b40.y;
        y[2] = acc[2]*0.25f + b40.z; y[3] = acc[3]*0.25f + b40.w;
        y[4] = acc[4]*0.25f + b41.x; y[5] = acc[5]*0.25f + b41.y;
        y[6] = acc[6]*0.25f + b41.z; y[7] = acc[7]*0.25f + b41.w;

        float s1 = 0.f, s2 = 0.f;
#pragma unroll
        for (int jj = 0; jj < 8; ++jj) { s1 += y[jj]; s2 += y[jj]*y[jj]; }
#pragma unroll
        for (int m = 1; m < 16; m <<= 1) {
            s1 += __shfl_xor(s1, m, 64);
            s2 += __shfl_xor(s2, m, 64);
        }
        float mu = s1 * (1.f / 128.f);
        float var = s2 * (1.f / 128.f) - mu * mu;
        float rstd = rsqrtf(var + LN_EPS);

        float4 g40 = *(const float4*)(gamma + dd);
        float4 g41 = *(const float4*)(gamma + dd + 4);
        float4 e40 = *(const float4*)(beta + dd);
        float4 e41 = *(const float4*)(beta + dd + 4);
        float4 r40 = *(const float4*)(res + (size_t)n * 128 + dd);
        float4 r41 = *(const float4*)(res + (size_t)n * 128 + dd + 4);
        float g[8] = {g40.x,g40.y,g40.z,g40.w,g41.x,g41.y,g41.z,g41.w};
        float be[8] = {e40.x,e40.y,e40.z,e40.w,e41.x,e41.y,e41.z,e41.w};
        float r[8] = {r40.x,r40.y,r40.z,r40.w,r41.x,r41.y,r41.z,r41.w};
#pragma unroll
        for (int jj = 0; jj < 8; ++jj) {
            y[jj] = (y[jj] - mu) * rstd * g[jj] + be[jj] + r[jj];
            if (relu_flag) y[jj] = fmaxf(y[jj], 0.f);
        }
        float4 o0 = {y[0],y[1],y[2],y[3]};
        float4 o1 = {y[4],y[5],y[6],y[7]};
        *(float4*)(out + (size_t)n * 128 + dd)     = o0;
        *(float4*)(out + (size_t)n * 128 + dd + 4) = o1;
        if (out_h) {
            ushort4 oh0, oh1;
            oh0.x = f2h(y[0]); oh0.y = f2h(y[1]); oh0.z = f2h(y[2]); oh0.w = f2h(y[3]);
            oh1.x = f2h(y[4]); oh1.y = f2h(y[5]); oh1.z = f2h(y[6]); oh1.w = f2h(y[7]);
            *(ushort4*)(out_h + (size_t)n * 128 + dd)     = oh0;
            *(ushort4*)(out_h + (size_t)n * 128 + dd + 4) = oh1;
        }
    }
}

// ---------------- launch ----------------

extern "C" void kernel_launch(void* const* d_in, const int* in_sizes, int n_in,
                              void* d_out, int out_size, void* d_ws, size_t ws_size,
                              hipStream_t stream) {
    const float* x    = (const float*)d_in[0];
    const int*   src  = (const int*)d_in[1];
    const int*   dst  = (const int*)d_in[2];
    const float* Wl1  = (const float*)d_in[3];
    const float* Wr1  = (const float*)d_in[4];
    const float* att1 = (const float*)d_in[5];
    const float* b1   = (const float*)d_in[6];
    const float* g1   = (const float*)d_in[7];
    const float* be1  = (const float*)d_in[8];
    const float* Wl2  = (const float*)d_in[9];
    const float* Wr2  = (const float*)d_in[10];
    const float* att2 = (const float*)d_in[11];
    const float* b2   = (const float*)d_in[12];
    const float* g2   = (const float*)d_in[13];
    const float* be2  = (const float*)d_in[14];
    float* out = (float*)d_out;

    char* ws = (char*)d_ws;
    size_t off = 0;
    u8*    xlq  = (u8*)(ws + off);    off += (size_t)MPAD * 512;          // int8 XL
    u32*   scld = (u32*)(ws + off);   off += (size_t)MPAD * 4 * 4;        // packed scale+Dl6
    u16*   dr6  = (u16*)(ws + off);   off += (size_t)MPAD * 4 * 2;        // Dr6 f16
    u16*   xrb  = (u16*)(ws + off);   off += (size_t)MPAD * 512 * 2;      // f16 XR
    u16*   xb   = (u16*)(ws + off);   off += (size_t)MPAD * 128 * 2;      // f16 A input
    float* hbuf = (float*)(ws + off); off += (size_t)NNODES * 128 * 4;
    u16*   Bt1  = (u16*)(ws + off);   off += (size_t)1024 * 128 * 2;
    u16*   Bt2  = (u16*)(ws + off);   off += (size_t)1024 * 128 * 2;
    int*   deg  = (int*)(ws + off);   off += (size_t)NNODES * 4;
    int*   rowp = (int*)(ws + off);   off += (size_t)(NNODES + 1) * 4;
    int*   cur  = (int*)(ws + off);   off += (size_t)NNODES * 4;
    int*   col  = (int*)(ws + off);   off += (size_t)ETOT * 4;

    k_prep<<<256, 256, 0, stream>>>(x, xb, Wl1, Wr1, Bt1, Wl2, Wr2, Bt2, deg);
    k_hist<<<(NEDGES + 255) / 256, 256, 0, stream>>>(dst, deg);
    k_scan<<<1, 1024, 0, stream>>>(deg, rowp, cur);
    k_scatter<<<(ETOT + 255) / 256, 256, 0, stream>>>(src, dst, col, cur);

    // layer 1
    k_gemm_f16<<<MPAD / 128 * 8, 256, 0, stream>>>(xb, Bt1, att1, xlq, scld, dr6, xrb);
    k_attn<<<NNODES / 4, 256, 0, stream>>>(xlq, scld, dr6, xrb, att1, b1, g1, be1,
                                           rowp, col, x, hbuf, xb, 1);
    // layer 2
    k_gemm_f16<<<MPAD / 128 * 8, 256, 0, stream>>>(xb, Bt2, att2, xlq, scld, dr6, xrb);
    k_attn<<<NNODES / 4, 256, 0, stream>>>(xlq, scld, dr6, xrb, att2, b2, g2, be2,
                                           rowp, col, hbuf, out, (u16*)nullptr, 0);
}